// Round 3
// baseline (2906.707 us; speedup 1.0000x reference)
//
#include <hip/hip_runtime.h>
#include <math.h>

#define BB 256
#define LL 20
#define HH 128
#define NH 8
#define D2C 64
#define NTY 4
#define NRL 4
#define CHILDN 30001
#define PARENTN 500
#define N1SN 50000
#define N1DN 20000
#define E1N 300000
#define N2N 20000
#define E2N 200000
#define TT (BB*LL)
#define N4DN 5000
#define E4N 150000
#define EC2PN 8000
#define GT 32   // nodes per GEMM tile

__device__ __forceinline__ unsigned fenc(float f){ unsigned u=__float_as_uint(f); return (u&0x80000000u)? ~u : (u|0x80000000u); }
__device__ __forceinline__ float fdec(unsigned u){ return (u&0x80000000u)? __uint_as_float(u^0x80000000u) : __uint_as_float(~u); }
__device__ __forceinline__ float sigf(float x){ return 1.f/(1.f+expf(-x)); }

// ---------------- Stage A: feature expansion ----------------
__global__ void k_featx(const int* seq, const int* dur, const int* stime, const int* etime,
                        const float* emb, const float* dia_w, const float* dia_b,
                        const float* t2v_w, const float* t2v_b,
                        const float* exp_W, const float* exp_b, float* xout){
  int bl = blockIdx.x; int o = threadIdx.x;
  __shared__ float feat[272];
  int node = seq[bl];
  float ts = (float)stime[bl], te = (float)etime[bl], td = (float)dur[bl];
  float e0 = emb[node*HH+o];
  float st, et;
  if(o < D2C){ st = e0; et = e0; }
  else {
    float w = dia_w[node*HH+o], b = dia_b[node*HH+o];
    st = e0 * sinf(w*ts + b);
    et = e0 * sinf(w*te + b);
  }
  feat[o] = st; feat[HH+o] = et;
  if(o < 16){
    float w = t2v_w[o], b = t2v_b[o];
    feat[256+o] = (o==0) ? (w*td + b) : sinf(w*td + b);
  }
  __syncthreads();
  float acc = exp_b[o];
  for(int j=0;j<272;j++) acc += feat[j]*exp_W[j*HH+o];
  xout[bl*HH+o] = fmaxf(acc, 0.f);
}

// x (rows of H) @ Wi (H,512) + b -> gpre ; grid = rows, 512 threads
__global__ void k_xwi(const float* x, const float* Wi, const float* bias, float* gpre){
  int row = blockIdx.x; int o = threadIdx.x;
  __shared__ float xs[HH];
  if(o < HH) xs[o] = x[row*HH+o];
  __syncthreads();
  float acc = bias[o];
  for(int h=0;h<HH;h++) acc += xs[h]*Wi[h*512+o];
  gpre[row*512+o] = acc;
}

__global__ void k_zero_state(float* h, float* c){
  int i = blockIdx.x*256 + threadIdx.x;
  if(i < BB*HH){ h[i]=0.f; c[i]=0.f; }
}

// one LSTM time step: grid = BB blocks, 512 threads; in-place h/c state update
__global__ void k_lstm_step(const float* gpre, const float* Wh, float* hstate, float* cstate,
                            float* hout, float* hout2, int l){
  int b = blockIdx.x; int o = threadIdx.x;
  __shared__ float hs[HH];
  __shared__ float gs[512];
  if(o < HH) hs[o] = hstate[b*HH+o];
  __syncthreads();
  float acc = gpre[((size_t)b*LL+l)*512+o];
  #pragma unroll 8
  for(int h=0;h<HH;h++) acc += hs[h]*Wh[h*512+o];
  gs[o] = acc;
  __syncthreads();
  if(o < HH){
    float ig = sigf(gs[o]);
    float fg = sigf(gs[HH+o]);
    float gg = tanhf(gs[2*HH+o]);
    float og = sigf(gs[3*HH+o]);
    float c = fg*cstate[b*HH+o] + ig*gg;
    float h = og*tanhf(c);
    cstate[b*HH+o] = c; hstate[b*HH+o] = h;
    hout[((size_t)b*LL+l)*HH+o] = h;
    if(hout2) hout2[((size_t)b*LL+l)*HH+o] = h;
  }
}

__global__ void k_tok(const int* seq, const int* seq_nt, int* tokid, int* toknt){
  int t = blockIdx.x*blockDim.x + threadIdx.x;
  if(t >= TT) return;
  int b = t % BB, l = t / BB;
  tokid[t] = seq[b*LL+l];
  toknt[t] = seq_nt[b*LL+l];
}

// ---------------- conv prep ----------------
__global__ void k_gather_emb(const int* nid, const float* emb, float* dst){
  int i = blockIdx.x; int o = threadIdx.x;
  dst[i*HH+o] = emb[nid[i]*HH+o];
}

__global__ void k_prep2(const int* sel, const float* xg, const int* g1_nid, const int* g1_nt,
                        float* srcbuf, int* gnid2, int* tsrc2){
  int i = blockIdx.x; int o = threadIdx.x;
  int s = sel[i];
  srcbuf[i*HH+o] = xg[s*HH+o];
  if(o==0){ gnid2[i] = g1_nid[s]; tsrc2[i] = g1_nt[s]; }
}

__global__ void k_dst2(const int* tok_sel, const float* xg, const float* h1, float* dst2){
  int t = blockIdx.x; int o = threadIdx.x;
  int b = t % BB, l = t / BB;
  dst2[t*HH+o] = xg[tok_sel[t]*HH+o] + h1[(b*LL+l)*HH+o];
}

__global__ void k_x0(const int* nid, const int* ntype, const float* emb, const float* hist2,
                     const float* skip, float* srcbuf){
  int i = blockIdx.x; int o = threadIdx.x;
  float a = sigf(skip[ntype[i]]);
  int nd = nid[i];
  srcbuf[i*HH+o] = emb[nd*HH+o]*a + hist2[nd*HH+o]*(1.f-a);
}

// LN + time-mod -> hsbuf; grid = nsrc, 128 threads
__global__ void k_ln_mod(const float* src_h, const int* src_nid,
                         const float* dia_w, const float* dia_b, float* hsbuf){
  int i = blockIdx.x; int o = threadIdx.x;
  __shared__ float red[HH];
  float v = src_h[i*HH+o];
  red[o] = v; __syncthreads();
  for(int s=64;s>0;s>>=1){ if(o<s) red[o]+=red[o+s]; __syncthreads(); }
  float mean = red[0]/(float)HH;
  __syncthreads();
  red[o] = v*v; __syncthreads();
  for(int s=64;s>0;s>>=1){ if(o<s) red[o]+=red[o+s]; __syncthreads(); }
  float var = red[0]/(float)HH - mean*mean;
  float h = (v-mean)*(1.f/sqrtf(fmaxf(var,0.f)+1e-5f));
  if(o >= D2C){
    int nd = src_nid[i];
    h *= sinf(dia_w[nd*HH+o] + dia_b[nd*HH+o]);
  }
  hsbuf[(size_t)i*HH+o] = h;
}

__global__ void k_zero_cnt(int* cnts){ if(threadIdx.x < NTY) cnts[threadIdx.x] = 0; }

__global__ void k_scatter_type(const int* types, int n, int* cnts, int* idxb, int stride){
  int i = blockIdx.x*256 + threadIdx.x;
  if(i >= n) return;
  int t = types[i];
  int pos = atomicAdd(&cnts[t], 1);
  idxb[t*stride + pos] = i;
}

// type-grouped K,V GEMM: grid (tiles, NTY), 256 threads.
// tile = GT nodes x 128 cols; X staged transposed in LDS, weights streamed.
__global__ void k_gemm_kv(const float* hsbuf, const int* idxb, const int* cnts, int stride,
                          const float* KW, const float* VW, float* Kbuf, float* Vbuf){
  int t = blockIdx.y;
  int cnt = cnts[t];
  int base = blockIdx.x * GT;
  if(base >= cnt) return;
  int nn = min(GT, cnt - base);
  const int* ids = idxb + t*stride + base;
  __shared__ float xs[128][GT+4];   // stride 36 floats (144B, 16B-aligned rows)
  __shared__ int sid[GT];
  int tid = threadIdx.x;
  if(tid < GT) sid[tid] = (tid < nn) ? ids[tid] : ids[0];
  __syncthreads();
  for(int s=0;s<16;s++){
    int elem = tid + 256*s;
    int j = elem >> 7, k = elem & 127;
    xs[k][j] = hsbuf[(size_t)sid[j]*HH + k];
  }
  __syncthreads();
  const float* kw = KW + (size_t)t*HH*HH;
  const float* vw = VW + (size_t)t*HH*HH;
  int o  = (tid & 63) * 2;   // column pair
  int ng = tid >> 6;         // node group 0..3 (8 nodes each)
  float ak0[8] = {0,0,0,0,0,0,0,0}, ak1[8] = {0,0,0,0,0,0,0,0};
  float av0[8] = {0,0,0,0,0,0,0,0}, av1[8] = {0,0,0,0,0,0,0,0};
  for(int k=0;k<HH;k++){
    float wk0 = kw[k*HH+o], wk1 = kw[k*HH+o+1];
    float wv0 = vw[k*HH+o], wv1 = vw[k*HH+o+1];
    #pragma unroll
    for(int j=0;j<8;j++){
      float x = xs[k][ng*8+j];
      ak0[j] += x*wk0; ak1[j] += x*wk1;
      av0[j] += x*wv0; av1[j] += x*wv1;
    }
  }
  for(int j=0;j<8;j++){
    int n = ng*8+j;
    if(n < nn){
      size_t r = (size_t)sid[n]*HH;
      Kbuf[r+o] = ak0[j]; Kbuf[r+o+1] = ak1[j];
      Vbuf[r+o] = av0[j]; Vbuf[r+o+1] = av1[j];
    }
  }
}

// LN + Q projection; grid = ndst, 128 threads
__global__ void k_conv_q(const float* dst_h, const int* dst_t, const float* QW, float* Qbuf){
  int i = blockIdx.x; int o = threadIdx.x;
  __shared__ float hs[HH];
  __shared__ float red[HH];
  float v = dst_h[i*HH+o];
  red[o] = v; __syncthreads();
  for(int s=64;s>0;s>>=1){ if(o<s) red[o]+=red[o+s]; __syncthreads(); }
  float mean = red[0]/(float)HH;
  __syncthreads();
  red[o] = v*v; __syncthreads();
  for(int s=64;s>0;s>>=1){ if(o<s) red[o]+=red[o+s]; __syncthreads(); }
  float var = red[0]/(float)HH - mean*mean;
  float h = (v-mean)*(1.f/sqrtf(fmaxf(var,0.f)+1e-5f));
  __syncthreads();
  hs[o] = h; __syncthreads();
  const float* qw = QW + (size_t)dst_t[i]*HH*HH;
  float qa = 0.f;
  for(int j=0;j<HH;j++) qa += hs[j]*qw[j*HH+o];
  Qbuf[i*HH+o] = qa;
}

__global__ void k_conv_init(float* Abuf, float* Dbuf, unsigned* Mbuf, int nd){
  int i = blockIdx.x*blockDim.x + threadIdx.x;
  if(i < nd*HH) Abuf[i] = 0.f;
  if(i < nd*NH){ Dbuf[i] = 0.f; Mbuf[i] = 0x007FFFFFu; }
}

// EW2[50][128] = edge_emb @ EW (per conv layer); grid 50, 128 threads
__global__ void k_edge_tab(const float* edge_emb, const float* EWp, float* EW2){
  int r = blockIdx.x; int o = threadIdx.x;
  float acc = 0.f;
  for(int j=0;j<32;j++) acc += edge_emb[r*32+j]*EWp[j*HH+o];
  EW2[r*HH+o] = acc;
}

// one wave per edge (4 edges / 256-thread block); lane handles dims 2l,2l+1
__global__ void k_conv_score(const int* esrc, const int* edst, const int* etype, const int* ew,
                             const float* EW2, const float* mu,
                             const float* Kbuf, const float* Qbuf,
                             float* Sbuf, unsigned* Mbuf, int E){
  int e = blockIdx.x*4 + (threadIdx.x>>6);
  if(e >= E) return;
  int lane = threadIdx.x & 63;
  int src = esrc[e], dst = edst[e], w = ew[e];
  float2 qa = ((const float2*)(Qbuf + (size_t)dst*HH))[lane];
  float2 kb = ((const float2*)(Kbuf + (size_t)src*HH))[lane];
  float2 eb = ((const float2*)(EW2  + (size_t)w  *HH))[lane];
  float p = qa.x*(kb.x+eb.x) + qa.y*(kb.y+eb.y);
  p += __shfl_xor(p, 1, 64);
  p += __shfl_xor(p, 2, 64);
  p += __shfl_xor(p, 4, 64);
  if((lane & 7) == 0){
    int h = lane >> 3;
    float s = p * mu[etype[e]*NH+h] * 0.25f;
    Sbuf[e*8+h] = s;
    atomicMax(&Mbuf[dst*8+h], fenc(s));
  }
}

__global__ void k_conv_expsum(const int* edst, float* Sbuf, const unsigned* Mbuf, float* Dbuf, int E){
  int i = blockIdx.x*blockDim.x + threadIdx.x;
  if(i >= E*8) return;
  int e = i>>3, h = i&7;
  int dst = edst[e];
  float m = fdec(Mbuf[dst*8+h]);
  float ex = expf(Sbuf[i]-m);
  Sbuf[i] = ex;
  atomicAdd(&Dbuf[dst*8+h], ex);
}

__global__ void k_conv_agg(const int* esrc, const int* edst, const float* Sbuf, const float* Dbuf,
                           const float* Vbuf, float* Abuf, int E){
  int e = blockIdx.x*4 + (threadIdx.x>>6);
  if(e >= E) return;
  int lane = threadIdx.x & 63;
  int src = esrc[e], dst = edst[e];
  int h1 = lane>>4, h2 = 4 + (lane>>4);
  float a1 = Sbuf[e*8+h1]/fmaxf(Dbuf[dst*8+h1],1e-9f);
  float a2 = Sbuf[e*8+h2]/fmaxf(Dbuf[dst*8+h2],1e-9f);
  atomicAdd(&Abuf[dst*HH+lane],    a1*Vbuf[(size_t)src*HH+lane]);
  atomicAdd(&Abuf[dst*HH+lane+64], a2*Vbuf[(size_t)src*HH+lane+64]);
}

__global__ void k_conv_out(const float* Abuf, const int* dst_t, const float* OW,
                           const float* dst_h, float* out, float* out2, int relu){
  int i = blockIdx.x; int o = threadIdx.x;
  __shared__ float as[HH];
  as[o] = Abuf[i*HH+o]; __syncthreads();
  const float* w = OW + (size_t)dst_t[i]*HH*HH;
  float acc = dst_h[i*HH+o];
  for(int j=0;j<HH;j++) acc += as[j]*w[j*HH+o];
  if(relu) acc = fmaxf(acc, 0.f);
  out[i*HH+o] = acc;
  if(out2) out2[i*HH+o] = acc;
}

// ---------------- stage D: token pooling ----------------
__global__ void k_seq2(const float* x2, float* xout){
  int bl = blockIdx.x; int o = threadIdx.x;
  int b = bl / LL, l = bl % LL;
  xout[bl*HH+o] = x2[(l*BB+b)*HH+o];
}

__global__ void k_zero_hist(float* hist2, float* cnt, unsigned* amax, float* aden){
  int i = blockIdx.x*blockDim.x + threadIdx.x;
  if(i < CHILDN*HH) hist2[i] = 0.f;
  if(i < CHILDN){ cnt[i] = 0.f; aden[i] = 0.f; amax[i] = 0x007FFFFFu; }
}

__global__ void k_tokatt(const float* h2f, const int* toknt, const float* ipW, const float* iaW,
                         float* abuf, unsigned* amax, const int* tokid){
  int t = blockIdx.x; int o = threadIdx.x;
  __shared__ float es[HH];
  __shared__ float red[HH];
  int b = t % BB, l = t / BB;
  es[o] = h2f[(b*LL+l)*HH+o];
  __syncthreads();
  int nt = toknt[t];
  const float* w = ipW + (size_t)nt*HH*HH;
  float acc = 0.f;
  for(int j=0;j<HH;j++) acc += es[j]*w[j*HH+o];
  float u = tanhf(acc);
  red[o] = u * iaW[nt*HH+o];
  __syncthreads();
  for(int s=64;s>0;s>>=1){ if(o<s) red[o]+=red[o+s]; __syncthreads(); }
  if(o==0){
    float a = red[0];
    abuf[t] = a;
    atomicMax(&amax[tokid[t]], fenc(a));
  }
}

__global__ void k_tokexp(const int* tokid, float* abuf, const unsigned* amax, float* aden, float* cnt){
  int t = blockIdx.x*blockDim.x + threadIdx.x;
  if(t >= TT) return;
  int c = tokid[t];
  float ex = expf(abuf[t]-fdec(amax[c]));
  abuf[t] = ex;
  atomicAdd(&aden[c], ex);
  atomicAdd(&cnt[c], 1.f);
}

__global__ void k_tokagg(const int* tokid, const float* abuf, const float* aden,
                         const float* h2f, float* hist2){
  int t = blockIdx.x; int o = threadIdx.x;
  int c = tokid[t];
  float w = abuf[t]/fmaxf(aden[c],1e-9f);
  int b = t % BB, l = t / BB;
  atomicAdd(&hist2[c*HH+o], w*h2f[(b*LL+l)*HH+o]);
}

__global__ void k_histfix(const float* cnt, const float* hist_emb, float* hist2){
  int c = blockIdx.x; int o = threadIdx.x;
  if(cnt[c] == 0.f) hist2[c*HH+o] = hist_emb[c*HH+o];
}

// ---------------- parent pooling ----------------
__global__ void k_zero_parent(float* psum, float* pcnt){
  int i = blockIdx.x*blockDim.x + threadIdx.x;
  if(i < PARENTN*HH) psum[i] = 0.f;
  if(i < PARENTN) pcnt[i] = 0.f;
}

__global__ void k_peagg(const int* pe_p, const int* pe_c, const float* cef, float* psum, float* pcnt){
  int i = blockIdx.x; int o = threadIdx.x;
  int p = pe_p[i], c = pe_c[i];
  atomicAdd(&psum[p*HH+o], cef[c*HH+o]);
  if(o==0) atomicAdd(&pcnt[p], 1.f);
}

__global__ void k_parent(const float* psum, const float* pcnt, float* out){
  int i = blockIdx.x; int o = threadIdx.x;
  out[i*HH+o] = psum[i*HH+o]/fmaxf(pcnt[i],1.f);
}

extern "C" void kernel_launch(void* const* d_in, const int* in_sizes, int n_in,
                              void* d_out, int out_size, void* d_ws, size_t ws_size,
                              hipStream_t stream){
  const int* seq     = (const int*)d_in[0];
  const int* seq_nt  = (const int*)d_in[1];
  const int* dur     = (const int*)d_in[2];
  const int* stime   = (const int*)d_in[3];
  const int* etime   = (const int*)d_in[4];
  const int* g1_nid  = (const int*)d_in[5];
  const int* g1_nt   = (const int*)d_in[6];
  const int* g1_esrc = (const int*)d_in[7];
  const int* g1_edst = (const int*)d_in[8];
  const int* g1_ety  = (const int*)d_in[9];
  const int* g1_ew   = (const int*)d_in[10];
  const int* g2_sel  = (const int*)d_in[11];
  const int* g2_esrc = (const int*)d_in[12];
  const int* g2_edst = (const int*)d_in[13];
  const int* g2_ety  = (const int*)d_in[14];
  const int* g2_ew   = (const int*)d_in[15];
  const int* tok_sel = (const int*)d_in[16];
  const int* g4_esrc = (const int*)d_in[17];
  const int* g4_edst = (const int*)d_in[18];
  const int* g4_ety  = (const int*)d_in[19];
  const int* g4_ew   = (const int*)d_in[20];
  const int* pe_p    = (const int*)d_in[21];
  const int* pe_c    = (const int*)d_in[22];
  const float* emb     = (const float*)d_in[23];
  const float* hist_emb= (const float*)d_in[24];
  const float* edge_emb= (const float*)d_in[25];
  const float* dia_w   = (const float*)d_in[26];
  const float* dia_b   = (const float*)d_in[27];
  const float* t2v_w   = (const float*)d_in[28];
  const float* t2v_b   = (const float*)d_in[29];
  const float* exp_W   = (const float*)d_in[30];
  const float* exp_b   = (const float*)d_in[31];
  const float* l1Wi    = (const float*)d_in[32];
  const float* l1Wh    = (const float*)d_in[33];
  const float* l1b     = (const float*)d_in[34];
  const float* l2Wi    = (const float*)d_in[35];
  const float* l2Wh    = (const float*)d_in[36];
  const float* l2b     = (const float*)d_in[37];
  const float* convK   = (const float*)d_in[38];
  const float* convQ   = (const float*)d_in[39];
  const float* convV   = (const float*)d_in[40];
  const float* convO   = (const float*)d_in[41];
  const float* convE   = (const float*)d_in[42];
  const float* convMu  = (const float*)d_in[43];
  const float* ipW     = (const float*)d_in[44];
  const float* iaW     = (const float*)d_in[45];
  const float* skip    = (const float*)d_in[46];
  float* outp = (float*)d_out;

  // workspace arena
  char* wsp = (char*)d_ws;
  size_t off = 0;
  auto A = [&](size_t nbytes)->char*{ char* p = wsp+off; off += (nbytes+255)&~(size_t)255; return p; };
  float*    srcbuf = (float*)   A((size_t)N1SN*HH*4);
  float*    Kbuf   = (float*)   A((size_t)N1SN*HH*4);
  float*    Vbuf   = (float*)   A((size_t)N1SN*HH*4);
  float*    Qbuf   = (float*)   A((size_t)N1DN*HH*4);
  float*    Sbuf   = (float*)   A((size_t)E1N*8*4);
  unsigned* Mbuf   = (unsigned*)A((size_t)N1DN*8*4);
  float*    Dbuf   = (float*)   A((size_t)N1DN*8*4);
  float*    Abuf   = (float*)   A((size_t)N1DN*HH*4);
  float*    xbuf   = (float*)   A((size_t)TT*HH*4);
  float*    gpre   = (float*)   A((size_t)TT*512*4);
  float*    h1     = (float*)   A((size_t)TT*HH*4);
  float*    dst2   = (float*)   A((size_t)TT*HH*4);
  float*    xg     = (float*)   A((size_t)N1DN*HH*4);
  float*    x2     = (float*)   A((size_t)TT*HH*4);
  float*    h2f    = (float*)   A((size_t)TT*HH*4);
  // hsbuf (LN'd src rows, live only inside each conv) aliases hist2 (live only
  // between stage D and k_x0) — lifetimes are disjoint on the serial stream.
  float*    hsbuf  = (float*)   A((size_t)N1SN*HH*4);
  float*    hist2  = hsbuf;
  float*    cnt    = (float*)   A((size_t)CHILDN*4);
  float*    abuf   = (float*)   A((size_t)TT*4);
  unsigned* amax   = (unsigned*)A((size_t)CHILDN*4);
  float*    aden   = (float*)   A((size_t)CHILDN*4);
  float*    x3     = (float*)   A((size_t)N1DN*HH*4);
  float*    cef    = (float*)   A((size_t)N4DN*HH*4);
  float*    psum   = (float*)   A((size_t)PARENTN*HH*4);
  float*    pcnt   = (float*)   A((size_t)PARENTN*4);
  int*      tokid  = (int*)     A((size_t)TT*4);
  int*      toknt  = (int*)     A((size_t)TT*4);
  int*      gnid2  = (int*)     A((size_t)N2N*4);
  int*      tsrc2  = (int*)     A((size_t)N2N*4);
  int*      idxb   = (int*)     A((size_t)NTY*N1SN*4);
  int*      cnts   = (int*)     A((size_t)NTY*4);
  float*    EW2    = (float*)   A((size_t)50*HH*4);
  float*    hstate = (float*)   A((size_t)BB*HH*4);
  float*    cstate = (float*)   A((size_t)BB*HH*4);
  if(off > ws_size) return;  // insufficient scratch: output stays zero

  auto run_conv = [&](const float* src_h, const int* src_nid, const int* src_t, int nsrc,
                      const float* dst_h, const int* dst_t, int ndst,
                      const int* esrc, const int* edst, const int* ety, const int* ew, int E,
                      int layer, float* outbuf, float* out2, int relu){
    const float* KW  = convK  + (size_t)layer*NTY*HH*HH;
    const float* QW  = convQ  + (size_t)layer*NTY*HH*HH;
    const float* VW  = convV  + (size_t)layer*NTY*HH*HH;
    const float* OW  = convO  + (size_t)layer*NTY*HH*HH;
    const float* EWp = convE  + (size_t)layer*32*HH;
    const float* MU  = convMu + (size_t)layer*NRL*NH;
    // K,V via type-grouped GEMM
    k_ln_mod<<<nsrc, HH, 0, stream>>>(src_h, src_nid, dia_w, dia_b, hsbuf);
    k_zero_cnt<<<1, 64, 0, stream>>>(cnts);
    k_scatter_type<<<(nsrc+255)/256, 256, 0, stream>>>(src_t, nsrc, cnts, idxb, N1SN);
    dim3 gg((nsrc+GT-1)/GT, NTY);
    k_gemm_kv<<<gg, 256, 0, stream>>>(hsbuf, idxb, cnts, N1SN, KW, VW, Kbuf, Vbuf);
    // Q
    k_conv_q<<<ndst, HH, 0, stream>>>(dst_h, dst_t, QW, Qbuf);
    // attention
    k_conv_init<<<(ndst*HH+255)/256, 256, 0, stream>>>(Abuf, Dbuf, Mbuf, ndst);
    k_edge_tab<<<50, HH, 0, stream>>>(edge_emb, EWp, EW2);
    k_conv_score<<<(E+3)/4, 256, 0, stream>>>(esrc, edst, ety, ew, EW2, MU, Kbuf, Qbuf, Sbuf, Mbuf, E);
    k_conv_expsum<<<(E*8+255)/256, 256, 0, stream>>>(edst, Sbuf, Mbuf, Dbuf, E);
    k_conv_agg<<<(E+3)/4, 256, 0, stream>>>(esrc, edst, Sbuf, Dbuf, Vbuf, Abuf, E);
    k_conv_out<<<ndst, HH, 0, stream>>>(Abuf, dst_t, OW, dst_h, outbuf, out2, relu);
  };

  // ---- stage A: features + LSTM1 ----
  k_featx<<<TT, HH, 0, stream>>>(seq, dur, stime, etime, emb, dia_w, dia_b, t2v_w, t2v_b, exp_W, exp_b, xbuf);
  k_xwi<<<TT, 512, 0, stream>>>(xbuf, l1Wi, l1b, gpre);
  k_zero_state<<<(BB*HH+255)/256, 256, 0, stream>>>(hstate, cstate);
  for(int l=0;l<LL;l++)
    k_lstm_step<<<BB, 512, 0, stream>>>(gpre, l1Wh, hstate, cstate, h1, (float*)nullptr, l);
  k_tok<<<(TT+255)/256, 256, 0, stream>>>(seq, seq_nt, tokid, toknt);

  // ---- conv1 on g1 ----
  k_gather_emb<<<N1SN, HH, 0, stream>>>(g1_nid, emb, srcbuf);
  run_conv(srcbuf, g1_nid, g1_nt, N1SN, srcbuf, g1_nt, N1DN,
           g1_esrc, g1_edst, g1_ety, g1_ew, E1N, 0, xg, (float*)nullptr, 1);

  // ---- conv2 on g2 ----
  k_prep2<<<N2N, HH, 0, stream>>>(g2_sel, xg, g1_nid, g1_nt, srcbuf, gnid2, tsrc2);
  k_dst2<<<TT, HH, 0, stream>>>(tok_sel, xg, h1, dst2);
  run_conv(srcbuf, gnid2, tsrc2, N2N, dst2, toknt, TT,
           g2_esrc, g2_edst, g2_ety, g2_ew, E2N, 1, x2, (float*)nullptr, 1);

  // ---- LSTM2 (h2 is output 0) ----
  k_seq2<<<TT, HH, 0, stream>>>(x2, xbuf);
  k_xwi<<<TT, 512, 0, stream>>>(xbuf, l2Wi, l2b, gpre);
  k_zero_state<<<(BB*HH+255)/256, 256, 0, stream>>>(hstate, cstate);
  for(int l=0;l<LL;l++)
    k_lstm_step<<<BB, 512, 0, stream>>>(gpre, l2Wh, hstate, cstate, h2f, outp, l);

  // ---- stage D: token attention pooling -> hist2 ----
  k_zero_hist<<<(CHILDN*HH+255)/256, 256, 0, stream>>>(hist2, cnt, amax, aden);
  k_tokatt<<<TT, HH, 0, stream>>>(h2f, toknt, ipW, iaW, abuf, amax, tokid);
  k_tokexp<<<(TT+255)/256, 256, 0, stream>>>(tokid, abuf, amax, aden, cnt);
  k_tokagg<<<TT, HH, 0, stream>>>(tokid, abuf, aden, h2f, hist2);
  k_histfix<<<CHILDN, HH, 0, stream>>>(cnt, hist_emb, hist2);

  // ---- conv3 on g1 with skip-mixed input ----
  k_x0<<<N1SN, HH, 0, stream>>>(g1_nid, g1_nt, emb, hist2, skip, srcbuf);
  run_conv(srcbuf, g1_nid, g1_nt, N1SN, srcbuf, g1_nt, N1DN,
           g1_esrc, g1_edst, g1_ety, g1_ew, E1N, 2, x3, (float*)nullptr, 1);

  // ---- conv4 on g4 (child_embed = output 1, no relu) ----
  run_conv(x3, g1_nid, g1_nt, N1DN, x3, g1_nt, N4DN,
           g4_esrc, g4_edst, g4_ety, g4_ew, E4N, 3, cef, outp + (size_t)TT*HH, 0);

  // ---- parent pooling (output 2) ----
  k_zero_parent<<<(PARENTN*HH+255)/256, 256, 0, stream>>>(psum, pcnt);
  k_peagg<<<EC2PN, HH, 0, stream>>>(pe_p, pe_c, cef, psum, pcnt);
  k_parent<<<PARENTN, HH, 0, stream>>>(psum, pcnt, outp + (size_t)TT*HH + (size_t)N4DN*HH);
}

// Round 4
// 2157.645 us; speedup vs baseline: 1.3472x; 1.3472x over previous
//
#include <hip/hip_runtime.h>
#include <math.h>

#define BB 256
#define LL 20
#define HH 128
#define NH 8
#define D2C 64
#define NTY 4
#define NRL 4
#define CHILDN 30001
#define PARENTN 500
#define N1SN 50000
#define N1DN 20000
#define E1N 300000
#define N2N 20000
#define E2N 200000
#define TT (BB*LL)
#define N4DN 5000
#define E4N 150000
#define EC2PN 8000
#define GT 32   // nodes per GEMM tile

__device__ __forceinline__ unsigned fenc(float f){ unsigned u=__float_as_uint(f); return (u&0x80000000u)? ~u : (u|0x80000000u); }
__device__ __forceinline__ float fdec(unsigned u){ return (u&0x80000000u)? __uint_as_float(u^0x80000000u) : __uint_as_float(~u); }
__device__ __forceinline__ float sigf(float x){ return 1.f/(1.f+expf(-x)); }

// ---------------- Stage A: feature expansion ----------------
__global__ void k_featx(const int* seq, const int* dur, const int* stime, const int* etime,
                        const float* emb, const float* dia_w, const float* dia_b,
                        const float* t2v_w, const float* t2v_b,
                        const float* exp_W, const float* exp_b, float* xout){
  int bl = blockIdx.x; int o = threadIdx.x;
  __shared__ float feat[272];
  int node = seq[bl];
  float ts = (float)stime[bl], te = (float)etime[bl], td = (float)dur[bl];
  float e0 = emb[node*HH+o];
  float st, et;
  if(o < D2C){ st = e0; et = e0; }
  else {
    float w = dia_w[node*HH+o], b = dia_b[node*HH+o];
    st = e0 * sinf(w*ts + b);
    et = e0 * sinf(w*te + b);
  }
  feat[o] = st; feat[HH+o] = et;
  if(o < 16){
    float w = t2v_w[o], b = t2v_b[o];
    feat[256+o] = (o==0) ? (w*td + b) : sinf(w*td + b);
  }
  __syncthreads();
  float acc = exp_b[o];
  for(int j=0;j<272;j++) acc += feat[j]*exp_W[j*HH+o];
  xout[bl*HH+o] = fmaxf(acc, 0.f);
}

// x (rows of H) @ Wi (H,512) + b -> gpre ; grid = rows, 512 threads
__global__ void k_xwi(const float* x, const float* Wi, const float* bias, float* gpre){
  int row = blockIdx.x; int o = threadIdx.x;
  __shared__ float xs[HH];
  if(o < HH) xs[o] = x[row*HH+o];
  __syncthreads();
  float acc = bias[o];
  for(int h=0;h<HH;h++) acc += xs[h]*Wi[h*512+o];
  gpre[row*512+o] = acc;
}

__global__ void k_zero_state(float* h, float* c){
  int i = blockIdx.x*256 + threadIdx.x;
  if(i < BB*HH){ h[i]=0.f; c[i]=0.f; }
}

// one LSTM time step: grid = BB blocks, 512 threads; in-place h/c state update
__global__ void k_lstm_step(const float* gpre, const float* Wh, float* hstate, float* cstate,
                            float* hout, float* hout2, int l){
  int b = blockIdx.x; int o = threadIdx.x;
  __shared__ float hs[HH];
  __shared__ float gs[512];
  if(o < HH) hs[o] = hstate[b*HH+o];
  __syncthreads();
  float acc = gpre[((size_t)b*LL+l)*512+o];
  #pragma unroll 8
  for(int h=0;h<HH;h++) acc += hs[h]*Wh[h*512+o];
  gs[o] = acc;
  __syncthreads();
  if(o < HH){
    float ig = sigf(gs[o]);
    float fg = sigf(gs[HH+o]);
    float gg = tanhf(gs[2*HH+o]);
    float og = sigf(gs[3*HH+o]);
    float c = fg*cstate[b*HH+o] + ig*gg;
    float h = og*tanhf(c);
    cstate[b*HH+o] = c; hstate[b*HH+o] = h;
    hout[((size_t)b*LL+l)*HH+o] = h;
    if(hout2) hout2[((size_t)b*LL+l)*HH+o] = h;
  }
}

__global__ void k_tok(const int* seq, const int* seq_nt, int* tokid, int* toknt){
  int t = blockIdx.x*blockDim.x + threadIdx.x;
  if(t >= TT) return;
  int b = t % BB, l = t / BB;
  tokid[t] = seq[b*LL+l];
  toknt[t] = seq_nt[b*LL+l];
}

// ---------------- conv prep ----------------
__global__ void k_gather_emb(const int* nid, const float* emb, float* dst){
  int i = blockIdx.x; int o = threadIdx.x;
  dst[i*HH+o] = emb[nid[i]*HH+o];
}

__global__ void k_prep2(const int* sel, const float* xg, const int* g1_nid, const int* g1_nt,
                        float* srcbuf, int* gnid2, int* tsrc2){
  int i = blockIdx.x; int o = threadIdx.x;
  int s = sel[i];
  srcbuf[i*HH+o] = xg[s*HH+o];
  if(o==0){ gnid2[i] = g1_nid[s]; tsrc2[i] = g1_nt[s]; }
}

__global__ void k_dst2(const int* tok_sel, const float* xg, const float* h1, float* dst2){
  int t = blockIdx.x; int o = threadIdx.x;
  int b = t % BB, l = t / BB;
  dst2[t*HH+o] = xg[tok_sel[t]*HH+o] + h1[(b*LL+l)*HH+o];
}

__global__ void k_x0(const int* nid, const int* ntype, const float* emb, const float* hist2,
                     const float* skip, float* srcbuf){
  int i = blockIdx.x; int o = threadIdx.x;
  float a = sigf(skip[ntype[i]]);
  int nd = nid[i];
  srcbuf[i*HH+o] = emb[nd*HH+o]*a + hist2[nd*HH+o]*(1.f-a);
}

// LN + time-mod -> hsbuf; grid = nsrc, 128 threads
__global__ void k_ln_mod(const float* src_h, const int* src_nid,
                         const float* dia_w, const float* dia_b, float* hsbuf){
  int i = blockIdx.x; int o = threadIdx.x;
  __shared__ float red[HH];
  float v = src_h[i*HH+o];
  red[o] = v; __syncthreads();
  for(int s=64;s>0;s>>=1){ if(o<s) red[o]+=red[o+s]; __syncthreads(); }
  float mean = red[0]/(float)HH;
  __syncthreads();
  red[o] = v*v; __syncthreads();
  for(int s=64;s>0;s>>=1){ if(o<s) red[o]+=red[o+s]; __syncthreads(); }
  float var = red[0]/(float)HH - mean*mean;
  float h = (v-mean)*(1.f/sqrtf(fmaxf(var,0.f)+1e-5f));
  if(o >= D2C){
    int nd = src_nid[i];
    h *= sinf(dia_w[nd*HH+o] + dia_b[nd*HH+o]);
  }
  hsbuf[(size_t)i*HH+o] = h;
}

__global__ void k_zero_cnt(int* cnts){ if(threadIdx.x < NTY) cnts[threadIdx.x] = 0; }

// block-aggregated type scatter: LDS histogram + ONE global atomic per (block,type).
// Round-3 version did 50k global atomics on 4 addresses -> 270 us of pure
// serialization; this does ~784 global atomics total.
__global__ void k_scatter_type(const int* types, int n, int* cnts, int* idxb, int stride){
  __shared__ int hist[NTY];
  __shared__ int base[NTY];
  int i = blockIdx.x*256 + threadIdx.x;
  if(threadIdx.x < NTY) hist[threadIdx.x] = 0;
  __syncthreads();
  int t = 0, r = 0;
  bool act = (i < n);
  if(act){ t = types[i]; r = atomicAdd(&hist[t], 1); }   // LDS atomic: fast
  __syncthreads();
  if(threadIdx.x < NTY && hist[threadIdx.x] > 0)
    base[threadIdx.x] = atomicAdd(&cnts[threadIdx.x], hist[threadIdx.x]);
  __syncthreads();
  if(act) idxb[t*stride + base[t] + r] = i;
}

// type-grouped K,V GEMM: grid (tiles, NTY), 256 threads.
// tile = GT nodes x 128 cols; X staged transposed in LDS, weights streamed.
__global__ void k_gemm_kv(const float* hsbuf, const int* idxb, const int* cnts, int stride,
                          const float* KW, const float* VW, float* Kbuf, float* Vbuf){
  int t = blockIdx.y;
  int cnt = cnts[t];
  int base = blockIdx.x * GT;
  if(base >= cnt) return;
  int nn = min(GT, cnt - base);
  const int* ids = idxb + t*stride + base;
  __shared__ float xs[128][GT+4];
  __shared__ int sid[GT];
  int tid = threadIdx.x;
  if(tid < GT) sid[tid] = (tid < nn) ? ids[tid] : ids[0];
  __syncthreads();
  for(int s=0;s<16;s++){
    int elem = tid + 256*s;
    int j = elem >> 7, k = elem & 127;
    xs[k][j] = hsbuf[(size_t)sid[j]*HH + k];
  }
  __syncthreads();
  const float* kw = KW + (size_t)t*HH*HH;
  const float* vw = VW + (size_t)t*HH*HH;
  int o  = (tid & 63) * 2;
  int ng = tid >> 6;
  float ak0[8] = {0,0,0,0,0,0,0,0}, ak1[8] = {0,0,0,0,0,0,0,0};
  float av0[8] = {0,0,0,0,0,0,0,0}, av1[8] = {0,0,0,0,0,0,0,0};
  for(int k=0;k<HH;k++){
    float wk0 = kw[k*HH+o], wk1 = kw[k*HH+o+1];
    float wv0 = vw[k*HH+o], wv1 = vw[k*HH+o+1];
    #pragma unroll
    for(int j=0;j<8;j++){
      float x = xs[k][ng*8+j];
      ak0[j] += x*wk0; ak1[j] += x*wk1;
      av0[j] += x*wv0; av1[j] += x*wv1;
    }
  }
  for(int j=0;j<8;j++){
    int n = ng*8+j;
    if(n < nn){
      size_t r = (size_t)sid[n]*HH;
      Kbuf[r+o] = ak0[j]; Kbuf[r+o+1] = ak1[j];
      Vbuf[r+o] = av0[j]; Vbuf[r+o+1] = av1[j];
    }
  }
}

// LN + Q projection; grid = ndst, 128 threads
__global__ void k_conv_q(const float* dst_h, const int* dst_t, const float* QW, float* Qbuf){
  int i = blockIdx.x; int o = threadIdx.x;
  __shared__ float hs[HH];
  __shared__ float red[HH];
  float v = dst_h[i*HH+o];
  red[o] = v; __syncthreads();
  for(int s=64;s>0;s>>=1){ if(o<s) red[o]+=red[o+s]; __syncthreads(); }
  float mean = red[0]/(float)HH;
  __syncthreads();
  red[o] = v*v; __syncthreads();
  for(int s=64;s>0;s>>=1){ if(o<s) red[o]+=red[o+s]; __syncthreads(); }
  float var = red[0]/(float)HH - mean*mean;
  float h = (v-mean)*(1.f/sqrtf(fmaxf(var,0.f)+1e-5f));
  __syncthreads();
  hs[o] = h; __syncthreads();
  const float* qw = QW + (size_t)dst_t[i]*HH*HH;
  float qa = 0.f;
  for(int j=0;j<HH;j++) qa += hs[j]*qw[j*HH+o];
  Qbuf[i*HH+o] = qa;
}

__global__ void k_conv_init(float* Abuf, float* Dbuf, unsigned* Mbuf, int nd){
  int i = blockIdx.x*blockDim.x + threadIdx.x;
  if(i < nd*HH) Abuf[i] = 0.f;
  if(i < nd*NH){ Dbuf[i] = 0.f; Mbuf[i] = 0x007FFFFFu; }
}

// EW2[50][128] = edge_emb @ EW (per conv layer); grid 50, 128 threads
__global__ void k_edge_tab(const float* edge_emb, const float* EWp, float* EW2){
  int r = blockIdx.x; int o = threadIdx.x;
  float acc = 0.f;
  for(int j=0;j<32;j++) acc += edge_emb[r*32+j]*EWp[j*HH+o];
  EW2[r*HH+o] = acc;
}

// one wave per edge (4 edges / 256-thread block); lane handles dims 2l,2l+1
__global__ void k_conv_score(const int* esrc, const int* edst, const int* etype, const int* ew,
                             const float* EW2, const float* mu,
                             const float* Kbuf, const float* Qbuf,
                             float* Sbuf, unsigned* Mbuf, int E){
  int e = blockIdx.x*4 + (threadIdx.x>>6);
  if(e >= E) return;
  int lane = threadIdx.x & 63;
  int src = esrc[e], dst = edst[e], w = ew[e];
  float2 qa = ((const float2*)(Qbuf + (size_t)dst*HH))[lane];
  float2 kb = ((const float2*)(Kbuf + (size_t)src*HH))[lane];
  float2 eb = ((const float2*)(EW2  + (size_t)w  *HH))[lane];
  float p = qa.x*(kb.x+eb.x) + qa.y*(kb.y+eb.y);
  p += __shfl_xor(p, 1, 64);
  p += __shfl_xor(p, 2, 64);
  p += __shfl_xor(p, 4, 64);
  if((lane & 7) == 0){
    int h = lane >> 3;
    float s = p * mu[etype[e]*NH+h] * 0.25f;
    Sbuf[e*8+h] = s;
    atomicMax(&Mbuf[dst*8+h], fenc(s));
  }
}

__global__ void k_conv_expsum(const int* edst, float* Sbuf, const unsigned* Mbuf, float* Dbuf, int E){
  int i = blockIdx.x*blockDim.x + threadIdx.x;
  if(i >= E*8) return;
  int e = i>>3, h = i&7;
  int dst = edst[e];
  float m = fdec(Mbuf[dst*8+h]);
  float ex = expf(Sbuf[i]-m);
  Sbuf[i] = ex;
  atomicAdd(&Dbuf[dst*8+h], ex);
}

__global__ void k_conv_agg(const int* esrc, const int* edst, const float* Sbuf, const float* Dbuf,
                           const float* Vbuf, float* Abuf, int E){
  int e = blockIdx.x*4 + (threadIdx.x>>6);
  if(e >= E) return;
  int lane = threadIdx.x & 63;
  int src = esrc[e], dst = edst[e];
  int h1 = lane>>4, h2 = 4 + (lane>>4);
  float a1 = Sbuf[e*8+h1]/fmaxf(Dbuf[dst*8+h1],1e-9f);
  float a2 = Sbuf[e*8+h2]/fmaxf(Dbuf[dst*8+h2],1e-9f);
  atomicAdd(&Abuf[dst*HH+lane],    a1*Vbuf[(size_t)src*HH+lane]);
  atomicAdd(&Abuf[dst*HH+lane+64], a2*Vbuf[(size_t)src*HH+lane+64]);
}

__global__ void k_conv_out(const float* Abuf, const int* dst_t, const float* OW,
                           const float* dst_h, float* out, float* out2, int relu){
  int i = blockIdx.x; int o = threadIdx.x;
  __shared__ float as[HH];
  as[o] = Abuf[i*HH+o]; __syncthreads();
  const float* w = OW + (size_t)dst_t[i]*HH*HH;
  float acc = dst_h[i*HH+o];
  for(int j=0;j<HH;j++) acc += as[j]*w[j*HH+o];
  if(relu) acc = fmaxf(acc, 0.f);
  out[i*HH+o] = acc;
  if(out2) out2[i*HH+o] = acc;
}

// ---------------- stage D: token pooling ----------------
__global__ void k_seq2(const float* x2, float* xout){
  int bl = blockIdx.x; int o = threadIdx.x;
  int b = bl / LL, l = bl % LL;
  xout[bl*HH+o] = x2[(l*BB+b)*HH+o];
}

__global__ void k_zero_hist(float* hist2, float* cnt, unsigned* amax, float* aden){
  int i = blockIdx.x*blockDim.x + threadIdx.x;
  if(i < CHILDN*HH) hist2[i] = 0.f;
  if(i < CHILDN){ cnt[i] = 0.f; aden[i] = 0.f; amax[i] = 0x007FFFFFu; }
}

__global__ void k_tokatt(const float* h2f, const int* toknt, const float* ipW, const float* iaW,
                         float* abuf, unsigned* amax, const int* tokid){
  int t = blockIdx.x; int o = threadIdx.x;
  __shared__ float es[HH];
  __shared__ float red[HH];
  int b = t % BB, l = t / BB;
  es[o] = h2f[(b*LL+l)*HH+o];
  __syncthreads();
  int nt = toknt[t];
  const float* w = ipW + (size_t)nt*HH*HH;
  float acc = 0.f;
  for(int j=0;j<HH;j++) acc += es[j]*w[j*HH+o];
  float u = tanhf(acc);
  red[o] = u * iaW[nt*HH+o];
  __syncthreads();
  for(int s=64;s>0;s>>=1){ if(o<s) red[o]+=red[o+s]; __syncthreads(); }
  if(o==0){
    float a = red[0];
    abuf[t] = a;
    atomicMax(&amax[tokid[t]], fenc(a));
  }
}

__global__ void k_tokexp(const int* tokid, float* abuf, const unsigned* amax, float* aden, float* cnt){
  int t = blockIdx.x*blockDim.x + threadIdx.x;
  if(t >= TT) return;
  int c = tokid[t];
  float ex = expf(abuf[t]-fdec(amax[c]));
  abuf[t] = ex;
  atomicAdd(&aden[c], ex);
  atomicAdd(&cnt[c], 1.f);
}

__global__ void k_tokagg(const int* tokid, const float* abuf, const float* aden,
                         const float* h2f, float* hist2){
  int t = blockIdx.x; int o = threadIdx.x;
  int c = tokid[t];
  float w = abuf[t]/fmaxf(aden[c],1e-9f);
  int b = t % BB, l = t / BB;
  atomicAdd(&hist2[c*HH+o], w*h2f[(b*LL+l)*HH+o]);
}

__global__ void k_histfix(const float* cnt, const float* hist_emb, float* hist2){
  int c = blockIdx.x; int o = threadIdx.x;
  if(cnt[c] == 0.f) hist2[c*HH+o] = hist_emb[c*HH+o];
}

// ---------------- parent pooling ----------------
__global__ void k_zero_parent(float* psum, float* pcnt){
  int i = blockIdx.x*blockDim.x + threadIdx.x;
  if(i < PARENTN*HH) psum[i] = 0.f;
  if(i < PARENTN) pcnt[i] = 0.f;
}

__global__ void k_peagg(const int* pe_p, const int* pe_c, const float* cef, float* psum, float* pcnt){
  int i = blockIdx.x; int o = threadIdx.x;
  int p = pe_p[i], c = pe_c[i];
  atomicAdd(&psum[p*HH+o], cef[c*HH+o]);
  if(o==0) atomicAdd(&pcnt[p], 1.f);
}

__global__ void k_parent(const float* psum, const float* pcnt, float* out){
  int i = blockIdx.x; int o = threadIdx.x;
  out[i*HH+o] = psum[i*HH+o]/fmaxf(pcnt[i],1.f);
}

extern "C" void kernel_launch(void* const* d_in, const int* in_sizes, int n_in,
                              void* d_out, int out_size, void* d_ws, size_t ws_size,
                              hipStream_t stream){
  const int* seq     = (const int*)d_in[0];
  const int* seq_nt  = (const int*)d_in[1];
  const int* dur     = (const int*)d_in[2];
  const int* stime   = (const int*)d_in[3];
  const int* etime   = (const int*)d_in[4];
  const int* g1_nid  = (const int*)d_in[5];
  const int* g1_nt   = (const int*)d_in[6];
  const int* g1_esrc = (const int*)d_in[7];
  const int* g1_edst = (const int*)d_in[8];
  const int* g1_ety  = (const int*)d_in[9];
  const int* g1_ew   = (const int*)d_in[10];
  const int* g2_sel  = (const int*)d_in[11];
  const int* g2_esrc = (const int*)d_in[12];
  const int* g2_edst = (const int*)d_in[13];
  const int* g2_ety  = (const int*)d_in[14];
  const int* g2_ew   = (const int*)d_in[15];
  const int* tok_sel = (const int*)d_in[16];
  const int* g4_esrc = (const int*)d_in[17];
  const int* g4_edst = (const int*)d_in[18];
  const int* g4_ety  = (const int*)d_in[19];
  const int* g4_ew   = (const int*)d_in[20];
  const int* pe_p    = (const int*)d_in[21];
  const int* pe_c    = (const int*)d_in[22];
  const float* emb     = (const float*)d_in[23];
  const float* hist_emb= (const float*)d_in[24];
  const float* edge_emb= (const float*)d_in[25];
  const float* dia_w   = (const float*)d_in[26];
  const float* dia_b   = (const float*)d_in[27];
  const float* t2v_w   = (const float*)d_in[28];
  const float* t2v_b   = (const float*)d_in[29];
  const float* exp_W   = (const float*)d_in[30];
  const float* exp_b   = (const float*)d_in[31];
  const float* l1Wi    = (const float*)d_in[32];
  const float* l1Wh    = (const float*)d_in[33];
  const float* l1b     = (const float*)d_in[34];
  const float* l2Wi    = (const float*)d_in[35];
  const float* l2Wh    = (const float*)d_in[36];
  const float* l2b     = (const float*)d_in[37];
  const float* convK   = (const float*)d_in[38];
  const float* convQ   = (const float*)d_in[39];
  const float* convV   = (const float*)d_in[40];
  const float* convO   = (const float*)d_in[41];
  const float* convE   = (const float*)d_in[42];
  const float* convMu  = (const float*)d_in[43];
  const float* ipW     = (const float*)d_in[44];
  const float* iaW     = (const float*)d_in[45];
  const float* skip    = (const float*)d_in[46];
  float* outp = (float*)d_out;

  // workspace arena
  char* wsp = (char*)d_ws;
  size_t off = 0;
  auto A = [&](size_t nbytes)->char*{ char* p = wsp+off; off += (nbytes+255)&~(size_t)255; return p; };
  float*    srcbuf = (float*)   A((size_t)N1SN*HH*4);
  float*    Kbuf   = (float*)   A((size_t)N1SN*HH*4);
  float*    Vbuf   = (float*)   A((size_t)N1SN*HH*4);
  float*    Qbuf   = (float*)   A((size_t)N1DN*HH*4);
  float*    Sbuf   = (float*)   A((size_t)E1N*8*4);
  unsigned* Mbuf   = (unsigned*)A((size_t)N1DN*8*4);
  float*    Dbuf   = (float*)   A((size_t)N1DN*8*4);
  float*    Abuf   = (float*)   A((size_t)N1DN*HH*4);
  float*    xbuf   = (float*)   A((size_t)TT*HH*4);
  float*    gpre   = (float*)   A((size_t)TT*512*4);
  float*    h1     = (float*)   A((size_t)TT*HH*4);
  float*    dst2   = (float*)   A((size_t)TT*HH*4);
  float*    xg     = (float*)   A((size_t)N1DN*HH*4);
  float*    x2     = (float*)   A((size_t)TT*HH*4);
  float*    h2f    = (float*)   A((size_t)TT*HH*4);
  // hsbuf aliases hist2 (disjoint lifetimes on the serial stream)
  float*    hsbuf  = (float*)   A((size_t)N1SN*HH*4);
  float*    hist2  = hsbuf;
  float*    cnt    = (float*)   A((size_t)CHILDN*4);
  float*    abuf   = (float*)   A((size_t)TT*4);
  unsigned* amax   = (unsigned*)A((size_t)CHILDN*4);
  float*    aden   = (float*)   A((size_t)CHILDN*4);
  float*    x3     = (float*)   A((size_t)N1DN*HH*4);
  float*    cef    = (float*)   A((size_t)N4DN*HH*4);
  float*    psum   = (float*)   A((size_t)PARENTN*HH*4);
  float*    pcnt   = (float*)   A((size_t)PARENTN*4);
  int*      tokid  = (int*)     A((size_t)TT*4);
  int*      toknt  = (int*)     A((size_t)TT*4);
  int*      gnid2  = (int*)     A((size_t)N2N*4);
  int*      tsrc2  = (int*)     A((size_t)N2N*4);
  int*      idxb   = (int*)     A((size_t)NTY*N1SN*4);
  int*      cnts   = (int*)     A((size_t)NTY*4);
  float*    EW2    = (float*)   A((size_t)50*HH*4);
  float*    hstate = (float*)   A((size_t)BB*HH*4);
  float*    cstate = (float*)   A((size_t)BB*HH*4);
  if(off > ws_size) return;  // insufficient scratch: output stays zero

  auto run_conv = [&](const float* src_h, const int* src_nid, const int* src_t, int nsrc,
                      const float* dst_h, const int* dst_t, int ndst,
                      const int* esrc, const int* edst, const int* ety, const int* ew, int E,
                      int layer, float* outbuf, float* out2, int relu){
    const float* KW  = convK  + (size_t)layer*NTY*HH*HH;
    const float* QW  = convQ  + (size_t)layer*NTY*HH*HH;
    const float* VW  = convV  + (size_t)layer*NTY*HH*HH;
    const float* OW  = convO  + (size_t)layer*NTY*HH*HH;
    const float* EWp = convE  + (size_t)layer*32*HH;
    const float* MU  = convMu + (size_t)layer*NRL*NH;
    // K,V via type-grouped GEMM
    k_ln_mod<<<nsrc, HH, 0, stream>>>(src_h, src_nid, dia_w, dia_b, hsbuf);
    k_zero_cnt<<<1, 64, 0, stream>>>(cnts);
    k_scatter_type<<<(nsrc+255)/256, 256, 0, stream>>>(src_t, nsrc, cnts, idxb, N1SN);
    dim3 gg((nsrc+GT-1)/GT, NTY);
    k_gemm_kv<<<gg, 256, 0, stream>>>(hsbuf, idxb, cnts, N1SN, KW, VW, Kbuf, Vbuf);
    // Q
    k_conv_q<<<ndst, HH, 0, stream>>>(dst_h, dst_t, QW, Qbuf);
    // attention
    k_conv_init<<<(ndst*HH+255)/256, 256, 0, stream>>>(Abuf, Dbuf, Mbuf, ndst);
    k_edge_tab<<<50, HH, 0, stream>>>(edge_emb, EWp, EW2);
    k_conv_score<<<(E+3)/4, 256, 0, stream>>>(esrc, edst, ety, ew, EW2, MU, Kbuf, Qbuf, Sbuf, Mbuf, E);
    k_conv_expsum<<<(E*8+255)/256, 256, 0, stream>>>(edst, Sbuf, Mbuf, Dbuf, E);
    k_conv_agg<<<(E+3)/4, 256, 0, stream>>>(esrc, edst, Sbuf, Dbuf, Vbuf, Abuf, E);
    k_conv_out<<<ndst, HH, 0, stream>>>(Abuf, dst_t, OW, dst_h, outbuf, out2, relu);
  };

  // ---- stage A: features + LSTM1 ----
  k_featx<<<TT, HH, 0, stream>>>(seq, dur, stime, etime, emb, dia_w, dia_b, t2v_w, t2v_b, exp_W, exp_b, xbuf);
  k_xwi<<<TT, 512, 0, stream>>>(xbuf, l1Wi, l1b, gpre);
  k_zero_state<<<(BB*HH+255)/256, 256, 0, stream>>>(hstate, cstate);
  for(int l=0;l<LL;l++)
    k_lstm_step<<<BB, 512, 0, stream>>>(gpre, l1Wh, hstate, cstate, h1, (float*)nullptr, l);
  k_tok<<<(TT+255)/256, 256, 0, stream>>>(seq, seq_nt, tokid, toknt);

  // ---- conv1 on g1 ----
  k_gather_emb<<<N1SN, HH, 0, stream>>>(g1_nid, emb, srcbuf);
  run_conv(srcbuf, g1_nid, g1_nt, N1SN, srcbuf, g1_nt, N1DN,
           g1_esrc, g1_edst, g1_ety, g1_ew, E1N, 0, xg, (float*)nullptr, 1);

  // ---- conv2 on g2 ----
  k_prep2<<<N2N, HH, 0, stream>>>(g2_sel, xg, g1_nid, g1_nt, srcbuf, gnid2, tsrc2);
  k_dst2<<<TT, HH, 0, stream>>>(tok_sel, xg, h1, dst2);
  run_conv(srcbuf, gnid2, tsrc2, N2N, dst2, toknt, TT,
           g2_esrc, g2_edst, g2_ety, g2_ew, E2N, 1, x2, (float*)nullptr, 1);

  // ---- LSTM2 (h2 is output 0) ----
  k_seq2<<<TT, HH, 0, stream>>>(x2, xbuf);
  k_xwi<<<TT, 512, 0, stream>>>(xbuf, l2Wi, l2b, gpre);
  k_zero_state<<<(BB*HH+255)/256, 256, 0, stream>>>(hstate, cstate);
  for(int l=0;l<LL;l++)
    k_lstm_step<<<BB, 512, 0, stream>>>(gpre, l2Wh, hstate, cstate, h2f, outp, l);

  // ---- stage D: token attention pooling -> hist2 ----
  k_zero_hist<<<(CHILDN*HH+255)/256, 256, 0, stream>>>(hist2, cnt, amax, aden);
  k_tokatt<<<TT, HH, 0, stream>>>(h2f, toknt, ipW, iaW, abuf, amax, tokid);
  k_tokexp<<<(TT+255)/256, 256, 0, stream>>>(tokid, abuf, amax, aden, cnt);
  k_tokagg<<<TT, HH, 0, stream>>>(tokid, abuf, aden, h2f, hist2);
  k_histfix<<<CHILDN, HH, 0, stream>>>(cnt, hist_emb, hist2);

  // ---- conv3 on g1 with skip-mixed input ----
  k_x0<<<N1SN, HH, 0, stream>>>(g1_nid, g1_nt, emb, hist2, skip, srcbuf);
  run_conv(srcbuf, g1_nid, g1_nt, N1SN, srcbuf, g1_nt, N1DN,
           g1_esrc, g1_edst, g1_ety, g1_ew, E1N, 2, x3, (float*)nullptr, 1);

  // ---- conv4 on g4 (child_embed = output 1, no relu) ----
  run_conv(x3, g1_nid, g1_nt, N1DN, x3, g1_nt, N4DN,
           g4_esrc, g4_edst, g4_ety, g4_ew, E4N, 3, cef, outp + (size_t)TT*HH, 0);

  // ---- parent pooling (output 2) ----
  k_zero_parent<<<(PARENTN*HH+255)/256, 256, 0, stream>>>(psum, pcnt);
  k_peagg<<<EC2PN, HH, 0, stream>>>(pe_p, pe_c, cef, psum, pcnt);
  k_parent<<<PARENTN, HH, 0, stream>>>(psum, pcnt, outp + (size_t)TT*HH + (size_t)N4DN*HH);
}

// Round 5
// 2018.819 us; speedup vs baseline: 1.4398x; 1.0688x over previous
//
#include <hip/hip_runtime.h>
#include <math.h>

#define BB 256
#define LL 20
#define HH 128
#define NH 8
#define D2C 64
#define NTY 4
#define NRL 4
#define CHILDN 30001
#define PARENTN 500
#define N1SN 50000
#define N1DN 20000
#define E1N 300000
#define N2N 20000
#define E2N 200000
#define TT (BB*LL)
#define N4DN 5000
#define E4N 150000
#define EC2PN 8000
#define GT 32   // nodes per GEMM tile

__device__ __forceinline__ unsigned fenc(float f){ unsigned u=__float_as_uint(f); return (u&0x80000000u)? ~u : (u|0x80000000u); }
__device__ __forceinline__ float fdec(unsigned u){ return (u&0x80000000u)? __uint_as_float(u^0x80000000u) : __uint_as_float(~u); }
__device__ __forceinline__ float sigf(float x){ return 1.f/(1.f+expf(-x)); }

// ---------------- Stage A: feature expansion ----------------
__global__ void k_featx(const int* seq, const int* dur, const int* stime, const int* etime,
                        const float* emb, const float* dia_w, const float* dia_b,
                        const float* t2v_w, const float* t2v_b,
                        const float* exp_W, const float* exp_b, float* xout){
  int bl = blockIdx.x; int o = threadIdx.x;
  __shared__ float feat[272];
  int node = seq[bl];
  float ts = (float)stime[bl], te = (float)etime[bl], td = (float)dur[bl];
  float e0 = emb[node*HH+o];
  float st, et;
  if(o < D2C){ st = e0; et = e0; }
  else {
    float w = dia_w[node*HH+o], b = dia_b[node*HH+o];
    st = e0 * sinf(w*ts + b);
    et = e0 * sinf(w*te + b);
  }
  feat[o] = st; feat[HH+o] = et;
  if(o < 16){
    float w = t2v_w[o], b = t2v_b[o];
    feat[256+o] = (o==0) ? (w*td + b) : sinf(w*td + b);
  }
  __syncthreads();
  float acc = exp_b[o];
  for(int j=0;j<272;j++) acc += feat[j]*exp_W[j*HH+o];
  xout[bl*HH+o] = fmaxf(acc, 0.f);
}

// x (rows of H) @ Wi (H,512) + b -> gpre ; grid = rows, 512 threads
__global__ void k_xwi(const float* x, const float* Wi, const float* bias, float* gpre){
  int row = blockIdx.x; int o = threadIdx.x;
  __shared__ float xs[HH];
  if(o < HH) xs[o] = x[row*HH+o];
  __syncthreads();
  float acc = bias[o];
  for(int h=0;h<HH;h++) acc += xs[h]*Wi[h*512+o];
  gpre[row*512+o] = acc;
}

__global__ void k_zero_state(float* h, float* c){
  int i = blockIdx.x*256 + threadIdx.x;
  if(i < BB*HH){ h[i]=0.f; c[i]=0.f; }
}

// one LSTM time step: grid = BB blocks, 512 threads; in-place h/c state update
__global__ void k_lstm_step(const float* gpre, const float* Wh, float* hstate, float* cstate,
                            float* hout, float* hout2, int l){
  int b = blockIdx.x; int o = threadIdx.x;
  __shared__ float hs[HH];
  __shared__ float gs[512];
  if(o < HH) hs[o] = hstate[b*HH+o];
  __syncthreads();
  float acc = gpre[((size_t)b*LL+l)*512+o];
  #pragma unroll 8
  for(int h=0;h<HH;h++) acc += hs[h]*Wh[h*512+o];
  gs[o] = acc;
  __syncthreads();
  if(o < HH){
    float ig = sigf(gs[o]);
    float fg = sigf(gs[HH+o]);
    float gg = tanhf(gs[2*HH+o]);
    float og = sigf(gs[3*HH+o]);
    float c = fg*cstate[b*HH+o] + ig*gg;
    float h = og*tanhf(c);
    cstate[b*HH+o] = c; hstate[b*HH+o] = h;
    hout[((size_t)b*LL+l)*HH+o] = h;
    if(hout2) hout2[((size_t)b*LL+l)*HH+o] = h;
  }
}

__global__ void k_tok(const int* seq, const int* seq_nt, int* tokid, int* toknt){
  int t = blockIdx.x*blockDim.x + threadIdx.x;
  if(t >= TT) return;
  int b = t % BB, l = t / BB;
  tokid[t] = seq[b*LL+l];
  toknt[t] = seq_nt[b*LL+l];
}

// ---------------- conv prep ----------------
__global__ void k_gather_emb(const int* nid, const float* emb, float* dst){
  int i = blockIdx.x; int o = threadIdx.x;
  dst[i*HH+o] = emb[nid[i]*HH+o];
}

__global__ void k_prep2(const int* sel, const float* xg, const int* g1_nid, const int* g1_nt,
                        float* srcbuf, int* gnid2, int* tsrc2){
  int i = blockIdx.x; int o = threadIdx.x;
  int s = sel[i];
  srcbuf[i*HH+o] = xg[s*HH+o];
  if(o==0){ gnid2[i] = g1_nid[s]; tsrc2[i] = g1_nt[s]; }
}

__global__ void k_dst2(const int* tok_sel, const float* xg, const float* h1, float* dst2){
  int t = blockIdx.x; int o = threadIdx.x;
  int b = t % BB, l = t / BB;
  dst2[t*HH+o] = xg[tok_sel[t]*HH+o] + h1[(b*LL+l)*HH+o];
}

__global__ void k_x0(const int* nid, const int* ntype, const float* emb, const float* hist2,
                     const float* skip, float* srcbuf){
  int i = blockIdx.x; int o = threadIdx.x;
  float a = sigf(skip[ntype[i]]);
  int nd = nid[i];
  srcbuf[i*HH+o] = emb[nd*HH+o]*a + hist2[nd*HH+o]*(1.f-a);
}

// LN + time-mod -> hsbuf; grid = nsrc, 128 threads
__global__ void k_ln_mod(const float* src_h, const int* src_nid,
                         const float* dia_w, const float* dia_b, float* hsbuf){
  int i = blockIdx.x; int o = threadIdx.x;
  __shared__ float red[HH];
  float v = src_h[i*HH+o];
  red[o] = v; __syncthreads();
  for(int s=64;s>0;s>>=1){ if(o<s) red[o]+=red[o+s]; __syncthreads(); }
  float mean = red[0]/(float)HH;
  __syncthreads();
  red[o] = v*v; __syncthreads();
  for(int s=64;s>0;s>>=1){ if(o<s) red[o]+=red[o+s]; __syncthreads(); }
  float var = red[0]/(float)HH - mean*mean;
  float h = (v-mean)*(1.f/sqrtf(fmaxf(var,0.f)+1e-5f));
  if(o >= D2C){
    int nd = src_nid[i];
    h *= sinf(dia_w[nd*HH+o] + dia_b[nd*HH+o]);
  }
  hsbuf[(size_t)i*HH+o] = h;
}

__global__ void k_zero_cnt(int* cnts){ if(threadIdx.x < NTY) cnts[threadIdx.x] = 0; }

// block-aggregated type scatter: LDS histogram + one global atomic per (block,type)
__global__ void k_scatter_type(const int* types, int n, int* cnts, int* idxb, int stride){
  __shared__ int hist[NTY];
  __shared__ int base[NTY];
  int i = blockIdx.x*256 + threadIdx.x;
  if(threadIdx.x < NTY) hist[threadIdx.x] = 0;
  __syncthreads();
  int t = 0, r = 0;
  bool act = (i < n);
  if(act){ t = types[i]; r = atomicAdd(&hist[t], 1); }
  __syncthreads();
  if(threadIdx.x < NTY && hist[threadIdx.x] > 0)
    base[threadIdx.x] = atomicAdd(&cnts[threadIdx.x], hist[threadIdx.x]);
  __syncthreads();
  if(act) idxb[t*stride + base[t] + r] = i;
}

// type-grouped K,V GEMM: grid (tiles, NTY), 256 threads.
__global__ void k_gemm_kv(const float* hsbuf, const int* idxb, const int* cnts, int stride,
                          const float* KW, const float* VW, float* Kbuf, float* Vbuf){
  int t = blockIdx.y;
  int cnt = cnts[t];
  int base = blockIdx.x * GT;
  if(base >= cnt) return;
  int nn = min(GT, cnt - base);
  const int* ids = idxb + t*stride + base;
  __shared__ float xs[128][GT+4];
  __shared__ int sid[GT];
  int tid = threadIdx.x;
  if(tid < GT) sid[tid] = (tid < nn) ? ids[tid] : ids[0];
  __syncthreads();
  for(int s=0;s<16;s++){
    int elem = tid + 256*s;
    int j = elem >> 7, k = elem & 127;
    xs[k][j] = hsbuf[(size_t)sid[j]*HH + k];
  }
  __syncthreads();
  const float* kw = KW + (size_t)t*HH*HH;
  const float* vw = VW + (size_t)t*HH*HH;
  int o  = (tid & 63) * 2;
  int ng = tid >> 6;
  float ak0[8] = {0,0,0,0,0,0,0,0}, ak1[8] = {0,0,0,0,0,0,0,0};
  float av0[8] = {0,0,0,0,0,0,0,0}, av1[8] = {0,0,0,0,0,0,0,0};
  for(int k=0;k<HH;k++){
    float wk0 = kw[k*HH+o], wk1 = kw[k*HH+o+1];
    float wv0 = vw[k*HH+o], wv1 = vw[k*HH+o+1];
    #pragma unroll
    for(int j=0;j<8;j++){
      float x = xs[k][ng*8+j];
      ak0[j] += x*wk0; ak1[j] += x*wk1;
      av0[j] += x*wv0; av1[j] += x*wv1;
    }
  }
  for(int j=0;j<8;j++){
    int n = ng*8+j;
    if(n < nn){
      size_t r = (size_t)sid[n]*HH;
      Kbuf[r+o] = ak0[j]; Kbuf[r+o+1] = ak1[j];
      Vbuf[r+o] = av0[j]; Vbuf[r+o+1] = av1[j];
    }
  }
}

// LN + Q projection; grid = ndst, 128 threads
__global__ void k_conv_q(const float* dst_h, const int* dst_t, const float* QW, float* Qbuf){
  int i = blockIdx.x; int o = threadIdx.x;
  __shared__ float hs[HH];
  __shared__ float red[HH];
  float v = dst_h[i*HH+o];
  red[o] = v; __syncthreads();
  for(int s=64;s>0;s>>=1){ if(o<s) red[o]+=red[o+s]; __syncthreads(); }
  float mean = red[0]/(float)HH;
  __syncthreads();
  red[o] = v*v; __syncthreads();
  for(int s=64;s>0;s>>=1){ if(o<s) red[o]+=red[o+s]; __syncthreads(); }
  float var = red[0]/(float)HH - mean*mean;
  float h = (v-mean)*(1.f/sqrtf(fmaxf(var,0.f)+1e-5f));
  __syncthreads();
  hs[o] = h; __syncthreads();
  const float* qw = QW + (size_t)dst_t[i]*HH*HH;
  float qa = 0.f;
  for(int j=0;j<HH;j++) qa += hs[j]*qw[j*HH+o];
  Qbuf[i*HH+o] = qa;
}

// EW2[50][128] = edge_emb @ EW (per conv layer); grid 50, 128 threads
__global__ void k_edge_tab(const float* edge_emb, const float* EWp, float* EW2){
  int r = blockIdx.x; int o = threadIdx.x;
  float acc = 0.f;
  for(int j=0;j<32;j++) acc += edge_emb[r*32+j]*EWp[j*HH+o];
  EW2[r*HH+o] = acc;
}

// one wave per edge (4 edges / 256-thread block); no atomics — just score to Sbuf
__global__ void k_conv_score(const int* esrc, const int* edst, const int* etype, const int* ew,
                             const float* EW2, const float* mu,
                             const float* Kbuf, const float* Qbuf,
                             float* Sbuf, int E){
  int e = blockIdx.x*4 + (threadIdx.x>>6);
  if(e >= E) return;
  int lane = threadIdx.x & 63;
  int src = esrc[e], dst = edst[e], w = ew[e];
  float2 qa = ((const float2*)(Qbuf + (size_t)dst*HH))[lane];
  float2 kb = ((const float2*)(Kbuf + (size_t)src*HH))[lane];
  float2 eb = ((const float2*)(EW2  + (size_t)w  *HH))[lane];
  float p = qa.x*(kb.x+eb.x) + qa.y*(kb.y+eb.y);
  p += __shfl_xor(p, 1, 64);
  p += __shfl_xor(p, 2, 64);
  p += __shfl_xor(p, 4, 64);
  if((lane & 7) == 0){
    int h = lane >> 3;
    Sbuf[(size_t)e*8+h] = p * mu[etype[e]*NH+h] * 0.25f;
  }
}

// ---------------- CSR build (per graph) ----------------
__global__ void k_zero_int(int* p, int n){
  int i = blockIdx.x*256 + threadIdx.x;
  if(i < n) p[i] = 0;
}
__global__ void k_hist_dst(const int* edst, int E, int* cnt){
  int e = blockIdx.x*256 + threadIdx.x;
  if(e < E) atomicAdd(&cnt[edst[e]], 1);
}
// single-block exclusive scan over n bins (n <= 20480); writes row_ptr[0..n] and cursor copy
__global__ void k_scan(const int* cnt, int n, int* row_ptr, int* cursor){
  __shared__ int tsum[1024];
  int tid = threadIdx.x;
  int per = (n + 1023) / 1024;
  int start = tid*per; int end = min(start+per, n);
  int s = 0;
  for(int i=start;i<end;i++) s += cnt[i];
  tsum[tid] = s; __syncthreads();
  for(int off=1;off<1024;off<<=1){
    int v = (tid>=off) ? tsum[tid-off] : 0;
    __syncthreads();
    tsum[tid] += v;
    __syncthreads();
  }
  int run = (tid==0) ? 0 : tsum[tid-1];
  for(int i=start;i<end;i++){ row_ptr[i]=run; cursor[i]=run; run += cnt[i]; }
  if(end == n) row_ptr[n] = run;
}
__global__ void k_fill_csr(const int* edst, int E, int* cursor, int* eid){
  int e = blockIdx.x*256 + threadIdx.x;
  if(e >= E) return;
  int pos = atomicAdd(&cursor[edst[e]], 1);
  eid[pos] = e;
}

// fused segment-softmax + V aggregation: one block (128 thr) per dst node; NO atomics.
__global__ void k_conv_soft_agg(const int* row_ptr, const int* eidx, const int* esrc,
                                const float* Sbuf, const float* Vbuf, float* Abuf){
  int d = blockIdx.x; int o = threadIdx.x;
  int r0 = row_ptr[d], r1 = row_ptr[d+1];
  __shared__ float red[HH];
  __shared__ float msh[NH], ish[NH];
  int h8 = o & 7, j16 = o >> 3;          // 16 threads stride edges per head
  float mm = -3.0e38f;
  for(int r=r0+j16; r<r1; r+=16) mm = fmaxf(mm, Sbuf[(size_t)eidx[r]*8 + h8]);
  red[o] = mm; __syncthreads();
  for(int s=64;s>=8;s>>=1){ if(o<s) red[o]=fmaxf(red[o],red[o+s]); __syncthreads(); }
  if(o < NH) msh[o] = (r1>r0) ? red[o] : 0.f;
  __syncthreads();
  float dd = 0.f;
  float mh = msh[h8];
  for(int r=r0+j16; r<r1; r+=16) dd += expf(Sbuf[(size_t)eidx[r]*8 + h8] - mh);
  red[o] = dd; __syncthreads();
  for(int s=64;s>=8;s>>=1){ if(o<s) red[o]+=red[o+s]; __syncthreads(); }
  if(o < NH) ish[o] = 1.f / fmaxf(red[o], 1e-9f);
  __syncthreads();
  int h = o >> 4;
  float m = msh[h], inv = ish[h];
  float acc = 0.f;
  for(int r=r0; r<r1; r++){
    int e = eidx[r]; int src = esrc[e];
    float a = expf(Sbuf[(size_t)e*8+h] - m) * inv;
    acc += a * Vbuf[(size_t)src*HH + o];
  }
  Abuf[(size_t)d*HH + o] = acc;
}

__global__ void k_conv_out(const float* Abuf, const int* dst_t, const float* OW,
                           const float* dst_h, float* out, float* out2, int relu){
  int i = blockIdx.x; int o = threadIdx.x;
  __shared__ float as[HH];
  as[o] = Abuf[i*HH+o]; __syncthreads();
  const float* w = OW + (size_t)dst_t[i]*HH*HH;
  float acc = dst_h[i*HH+o];
  for(int j=0;j<HH;j++) acc += as[j]*w[j*HH+o];
  if(relu) acc = fmaxf(acc, 0.f);
  out[i*HH+o] = acc;
  if(out2) out2[i*HH+o] = acc;
}

// ---------------- stage D: token pooling ----------------
__global__ void k_seq2(const float* x2, float* xout){
  int bl = blockIdx.x; int o = threadIdx.x;
  int b = bl / LL, l = bl % LL;
  xout[bl*HH+o] = x2[(l*BB+b)*HH+o];
}

__global__ void k_zero_hist(float* hist2, float* cnt, unsigned* amax, float* aden){
  int i = blockIdx.x*blockDim.x + threadIdx.x;
  if(i < CHILDN*HH) hist2[i] = 0.f;
  if(i < CHILDN){ cnt[i] = 0.f; aden[i] = 0.f; amax[i] = 0x007FFFFFu; }
}

__global__ void k_tokatt(const float* h2f, const int* toknt, const float* ipW, const float* iaW,
                         float* abuf, unsigned* amax, const int* tokid){
  int t = blockIdx.x; int o = threadIdx.x;
  __shared__ float es[HH];
  __shared__ float red[HH];
  int b = t % BB, l = t / BB;
  es[o] = h2f[(b*LL+l)*HH+o];
  __syncthreads();
  int nt = toknt[t];
  const float* w = ipW + (size_t)nt*HH*HH;
  float acc = 0.f;
  for(int j=0;j<HH;j++) acc += es[j]*w[j*HH+o];
  float u = tanhf(acc);
  red[o] = u * iaW[nt*HH+o];
  __syncthreads();
  for(int s=64;s>0;s>>=1){ if(o<s) red[o]+=red[o+s]; __syncthreads(); }
  if(o==0){
    float a = red[0];
    abuf[t] = a;
    atomicMax(&amax[tokid[t]], fenc(a));
  }
}

__global__ void k_tokexp(const int* tokid, float* abuf, const unsigned* amax, float* aden, float* cnt){
  int t = blockIdx.x*blockDim.x + threadIdx.x;
  if(t >= TT) return;
  int c = tokid[t];
  float ex = expf(abuf[t]-fdec(amax[c]));
  abuf[t] = ex;
  atomicAdd(&aden[c], ex);
  atomicAdd(&cnt[c], 1.f);
}

__global__ void k_tokagg(const int* tokid, const float* abuf, const float* aden,
                         const float* h2f, float* hist2){
  int t = blockIdx.x; int o = threadIdx.x;
  int c = tokid[t];
  float w = abuf[t]/fmaxf(aden[c],1e-9f);
  int b = t % BB, l = t / BB;
  atomicAdd(&hist2[c*HH+o], w*h2f[(b*LL+l)*HH+o]);
}

__global__ void k_histfix(const float* cnt, const float* hist_emb, float* hist2){
  int c = blockIdx.x; int o = threadIdx.x;
  if(cnt[c] == 0.f) hist2[c*HH+o] = hist_emb[c*HH+o];
}

// ---------------- parent pooling ----------------
__global__ void k_zero_parent(float* psum, float* pcnt){
  int i = blockIdx.x*blockDim.x + threadIdx.x;
  if(i < PARENTN*HH) psum[i] = 0.f;
  if(i < PARENTN) pcnt[i] = 0.f;
}

__global__ void k_peagg(const int* pe_p, const int* pe_c, const float* cef, float* psum, float* pcnt){
  int i = blockIdx.x; int o = threadIdx.x;
  int p = pe_p[i], c = pe_c[i];
  atomicAdd(&psum[p*HH+o], cef[c*HH+o]);
  if(o==0) atomicAdd(&pcnt[p], 1.f);
}

__global__ void k_parent(const float* psum, const float* pcnt, float* out){
  int i = blockIdx.x; int o = threadIdx.x;
  out[i*HH+o] = psum[i*HH+o]/fmaxf(pcnt[i],1.f);
}

extern "C" void kernel_launch(void* const* d_in, const int* in_sizes, int n_in,
                              void* d_out, int out_size, void* d_ws, size_t ws_size,
                              hipStream_t stream){
  const int* seq     = (const int*)d_in[0];
  const int* seq_nt  = (const int*)d_in[1];
  const int* dur     = (const int*)d_in[2];
  const int* stime   = (const int*)d_in[3];
  const int* etime   = (const int*)d_in[4];
  const int* g1_nid  = (const int*)d_in[5];
  const int* g1_nt   = (const int*)d_in[6];
  const int* g1_esrc = (const int*)d_in[7];
  const int* g1_edst = (const int*)d_in[8];
  const int* g1_ety  = (const int*)d_in[9];
  const int* g1_ew   = (const int*)d_in[10];
  const int* g2_sel  = (const int*)d_in[11];
  const int* g2_esrc = (const int*)d_in[12];
  const int* g2_edst = (const int*)d_in[13];
  const int* g2_ety  = (const int*)d_in[14];
  const int* g2_ew   = (const int*)d_in[15];
  const int* tok_sel = (const int*)d_in[16];
  const int* g4_esrc = (const int*)d_in[17];
  const int* g4_edst = (const int*)d_in[18];
  const int* g4_ety  = (const int*)d_in[19];
  const int* g4_ew   = (const int*)d_in[20];
  const int* pe_p    = (const int*)d_in[21];
  const int* pe_c    = (const int*)d_in[22];
  const float* emb     = (const float*)d_in[23];
  const float* hist_emb= (const float*)d_in[24];
  const float* edge_emb= (const float*)d_in[25];
  const float* dia_w   = (const float*)d_in[26];
  const float* dia_b   = (const float*)d_in[27];
  const float* t2v_w   = (const float*)d_in[28];
  const float* t2v_b   = (const float*)d_in[29];
  const float* exp_W   = (const float*)d_in[30];
  const float* exp_b   = (const float*)d_in[31];
  const float* l1Wi    = (const float*)d_in[32];
  const float* l1Wh    = (const float*)d_in[33];
  const float* l1b     = (const float*)d_in[34];
  const float* l2Wi    = (const float*)d_in[35];
  const float* l2Wh    = (const float*)d_in[36];
  const float* l2b     = (const float*)d_in[37];
  const float* convK   = (const float*)d_in[38];
  const float* convQ   = (const float*)d_in[39];
  const float* convV   = (const float*)d_in[40];
  const float* convO   = (const float*)d_in[41];
  const float* convE   = (const float*)d_in[42];
  const float* convMu  = (const float*)d_in[43];
  const float* ipW     = (const float*)d_in[44];
  const float* iaW     = (const float*)d_in[45];
  const float* skip    = (const float*)d_in[46];
  float* outp = (float*)d_out;

  // workspace arena
  char* wsp = (char*)d_ws;
  size_t off = 0;
  auto A = [&](size_t nbytes)->char*{ char* p = wsp+off; off += (nbytes+255)&~(size_t)255; return p; };
  float*    srcbuf = (float*)   A((size_t)N1SN*HH*4);
  float*    Kbuf   = (float*)   A((size_t)N1SN*HH*4);
  float*    Vbuf   = (float*)   A((size_t)N1SN*HH*4);
  float*    Qbuf   = (float*)   A((size_t)N1DN*HH*4);
  float*    Sbuf   = (float*)   A((size_t)E1N*8*4);
  float*    Abuf   = (float*)   A((size_t)N1DN*HH*4);
  float*    xbuf   = (float*)   A((size_t)TT*HH*4);
  float*    gpre   = (float*)   A((size_t)TT*512*4);
  float*    h1     = (float*)   A((size_t)TT*HH*4);
  float*    dst2   = (float*)   A((size_t)TT*HH*4);
  float*    xg     = (float*)   A((size_t)N1DN*HH*4);
  float*    x2     = (float*)   A((size_t)TT*HH*4);
  float*    h2f    = (float*)   A((size_t)TT*HH*4);
  // hsbuf aliases hist2 (disjoint lifetimes on the serial stream)
  float*    hsbuf  = (float*)   A((size_t)N1SN*HH*4);
  float*    hist2  = hsbuf;
  float*    cnt    = (float*)   A((size_t)CHILDN*4);
  float*    abuf   = (float*)   A((size_t)TT*4);
  unsigned* amax   = (unsigned*)A((size_t)CHILDN*4);
  float*    aden   = (float*)   A((size_t)CHILDN*4);
  float*    x3     = (float*)   A((size_t)N1DN*HH*4);
  float*    cef    = (float*)   A((size_t)N4DN*HH*4);
  float*    psum   = (float*)   A((size_t)PARENTN*HH*4);
  float*    pcnt   = (float*)   A((size_t)PARENTN*4);
  int*      tokid  = (int*)     A((size_t)TT*4);
  int*      toknt  = (int*)     A((size_t)TT*4);
  int*      gnid2  = (int*)     A((size_t)N2N*4);
  int*      tsrc2  = (int*)     A((size_t)N2N*4);
  int*      idxb   = (int*)     A((size_t)NTY*N1SN*4);
  int*      cnts   = (int*)     A((size_t)NTY*4);
  float*    EW2    = (float*)   A((size_t)50*HH*4);
  float*    hstate = (float*)   A((size_t)BB*HH*4);
  float*    cstate = (float*)   A((size_t)BB*HH*4);
  // CSR structures
  int*      g1row  = (int*)     A((size_t)(N1DN+1)*4);
  int*      g1eid  = (int*)     A((size_t)E1N*4);
  int*      g2row  = (int*)     A((size_t)(TT+1)*4);
  int*      g2eid  = (int*)     A((size_t)E2N*4);
  int*      g4row  = (int*)     A((size_t)(N4DN+1)*4);
  int*      g4eid  = (int*)     A((size_t)E4N*4);
  int*      icnt   = (int*)     A((size_t)(N1DN+1)*4);   // shared hist scratch
  int*      icur   = (int*)     A((size_t)(N1DN+1)*4);   // shared cursor scratch
  if(off > ws_size) return;  // insufficient scratch: output stays zero

  auto build_csr = [&](const int* edst, int E, int ndst, int* rowp, int* eid){
    k_zero_int<<<(ndst+255)/256, 256, 0, stream>>>(icnt, ndst);
    k_hist_dst<<<(E+255)/256, 256, 0, stream>>>(edst, E, icnt);
    k_scan<<<1, 1024, 0, stream>>>(icnt, ndst, rowp, icur);
    k_fill_csr<<<(E+255)/256, 256, 0, stream>>>(edst, E, icur, eid);
  };

  auto run_conv = [&](const float* src_h, const int* src_nid, const int* src_t, int nsrc,
                      const float* dst_h, const int* dst_t, int ndst,
                      const int* esrc, const int* edst, const int* ety, const int* ew, int E,
                      const int* rowp, const int* eid,
                      int layer, float* outbuf, float* out2, int relu){
    const float* KW  = convK  + (size_t)layer*NTY*HH*HH;
    const float* QW  = convQ  + (size_t)layer*NTY*HH*HH;
    const float* VW  = convV  + (size_t)layer*NTY*HH*HH;
    const float* OW  = convO  + (size_t)layer*NTY*HH*HH;
    const float* EWp = convE  + (size_t)layer*32*HH;
    const float* MU  = convMu + (size_t)layer*NRL*NH;
    // K,V via type-grouped GEMM
    k_ln_mod<<<nsrc, HH, 0, stream>>>(src_h, src_nid, dia_w, dia_b, hsbuf);
    k_zero_cnt<<<1, 64, 0, stream>>>(cnts);
    k_scatter_type<<<(nsrc+255)/256, 256, 0, stream>>>(src_t, nsrc, cnts, idxb, N1SN);
    dim3 gg((nsrc+GT-1)/GT, NTY);
    k_gemm_kv<<<gg, 256, 0, stream>>>(hsbuf, idxb, cnts, N1SN, KW, VW, Kbuf, Vbuf);
    // Q
    k_conv_q<<<ndst, HH, 0, stream>>>(dst_h, dst_t, QW, Qbuf);
    // attention: per-edge score, then per-dst fused softmax+aggregate (no atomics)
    k_edge_tab<<<50, HH, 0, stream>>>(edge_emb, EWp, EW2);
    k_conv_score<<<(E+3)/4, 256, 0, stream>>>(esrc, edst, ety, ew, EW2, MU, Kbuf, Qbuf, Sbuf, E);
    k_conv_soft_agg<<<ndst, HH, 0, stream>>>(rowp, eid, esrc, Sbuf, Vbuf, Abuf);
    k_conv_out<<<ndst, HH, 0, stream>>>(Abuf, dst_t, OW, dst_h, outbuf, out2, relu);
  };

  // ---- stage A: features + LSTM1 ----
  k_featx<<<TT, HH, 0, stream>>>(seq, dur, stime, etime, emb, dia_w, dia_b, t2v_w, t2v_b, exp_W, exp_b, xbuf);
  k_xwi<<<TT, 512, 0, stream>>>(xbuf, l1Wi, l1b, gpre);
  k_zero_state<<<(BB*HH+255)/256, 256, 0, stream>>>(hstate, cstate);
  for(int l=0;l<LL;l++)
    k_lstm_step<<<BB, 512, 0, stream>>>(gpre, l1Wh, hstate, cstate, h1, (float*)nullptr, l);
  k_tok<<<(TT+255)/256, 256, 0, stream>>>(seq, seq_nt, tokid, toknt);

  // ---- CSR for g1 (reused by conv1 and conv3) ----
  build_csr(g1_edst, E1N, N1DN, g1row, g1eid);

  // ---- conv1 on g1 ----
  k_gather_emb<<<N1SN, HH, 0, stream>>>(g1_nid, emb, srcbuf);
  run_conv(srcbuf, g1_nid, g1_nt, N1SN, srcbuf, g1_nt, N1DN,
           g1_esrc, g1_edst, g1_ety, g1_ew, E1N, g1row, g1eid, 0, xg, (float*)nullptr, 1);

  // ---- conv2 on g2 ----
  build_csr(g2_edst, E2N, TT, g2row, g2eid);
  k_prep2<<<N2N, HH, 0, stream>>>(g2_sel, xg, g1_nid, g1_nt, srcbuf, gnid2, tsrc2);
  k_dst2<<<TT, HH, 0, stream>>>(tok_sel, xg, h1, dst2);
  run_conv(srcbuf, gnid2, tsrc2, N2N, dst2, toknt, TT,
           g2_esrc, g2_edst, g2_ety, g2_ew, E2N, g2row, g2eid, 1, x2, (float*)nullptr, 1);

  // ---- LSTM2 (h2 is output 0) ----
  k_seq2<<<TT, HH, 0, stream>>>(x2, xbuf);
  k_xwi<<<TT, 512, 0, stream>>>(xbuf, l2Wi, l2b, gpre);
  k_zero_state<<<(BB*HH+255)/256, 256, 0, stream>>>(hstate, cstate);
  for(int l=0;l<LL;l++)
    k_lstm_step<<<BB, 512, 0, stream>>>(gpre, l2Wh, hstate, cstate, h2f, outp, l);

  // ---- stage D: token attention pooling -> hist2 ----
  k_zero_hist<<<(CHILDN*HH+255)/256, 256, 0, stream>>>(hist2, cnt, amax, aden);
  k_tokatt<<<TT, HH, 0, stream>>>(h2f, toknt, ipW, iaW, abuf, amax, tokid);
  k_tokexp<<<(TT+255)/256, 256, 0, stream>>>(tokid, abuf, amax, aden, cnt);
  k_tokagg<<<TT, HH, 0, stream>>>(tokid, abuf, aden, h2f, hist2);
  k_histfix<<<CHILDN, HH, 0, stream>>>(cnt, hist_emb, hist2);

  // ---- conv3 on g1 with skip-mixed input (g1 CSR reused) ----
  k_x0<<<N1SN, HH, 0, stream>>>(g1_nid, g1_nt, emb, hist2, skip, srcbuf);
  run_conv(srcbuf, g1_nid, g1_nt, N1SN, srcbuf, g1_nt, N1DN,
           g1_esrc, g1_edst, g1_ety, g1_ew, E1N, g1row, g1eid, 2, x3, (float*)nullptr, 1);

  // ---- conv4 on g4 (child_embed = output 1, no relu) ----
  build_csr(g4_edst, E4N, N4DN, g4row, g4eid);
  run_conv(x3, g1_nid, g1_nt, N1DN, x3, g1_nt, N4DN,
           g4_esrc, g4_edst, g4_ety, g4_ew, E4N, g4row, g4eid, 3, cef, outp + (size_t)TT*HH, 0);

  // ---- parent pooling (output 2) ----
  k_zero_parent<<<(PARENTN*HH+255)/256, 256, 0, stream>>>(psum, pcnt);
  k_peagg<<<EC2PN, HH, 0, stream>>>(pe_p, pe_c, cef, psum, pcnt);
  k_parent<<<PARENTN, HH, 0, stream>>>(psum, pcnt, outp + (size_t)TT*HH + (size_t)N4DN*HH);
}

// Round 6
// 1877.716 us; speedup vs baseline: 1.5480x; 1.0751x over previous
//
#include <hip/hip_runtime.h>
#include <math.h>

#define BB 256
#define LL 20
#define HH 128
#define NH 8
#define D2C 64
#define NTY 4
#define NRL 4
#define CHILDN 30001
#define PARENTN 500
#define N1SN 50000
#define N1DN 20000
#define E1N 300000
#define N2N 20000
#define E2N 200000
#define TT (BB*LL)
#define N4DN 5000
#define E4N 150000
#define EC2PN 8000
#define GT2 64   // nodes per GEMM tile

__device__ __forceinline__ unsigned fenc(float f){ unsigned u=__float_as_uint(f); return (u&0x80000000u)? ~u : (u|0x80000000u); }
__device__ __forceinline__ float fdec(unsigned u){ return (u&0x80000000u)? __uint_as_float(u^0x80000000u) : __uint_as_float(~u); }
__device__ __forceinline__ float sigf(float x){ return 1.f/(1.f+expf(-x)); }

// ---------------- Stage A: feature expansion ----------------
__global__ void k_featx(const int* seq, const int* dur, const int* stime, const int* etime,
                        const float* emb, const float* dia_w, const float* dia_b,
                        const float* t2v_w, const float* t2v_b,
                        const float* exp_W, const float* exp_b, float* xout){
  int bl = blockIdx.x; int o = threadIdx.x;
  __shared__ float feat[272];
  int node = seq[bl];
  float ts = (float)stime[bl], te = (float)etime[bl], td = (float)dur[bl];
  float e0 = emb[node*HH+o];
  float st, et;
  if(o < D2C){ st = e0; et = e0; }
  else {
    float w = dia_w[node*HH+o], b = dia_b[node*HH+o];
    st = e0 * sinf(w*ts + b);
    et = e0 * sinf(w*te + b);
  }
  feat[o] = st; feat[HH+o] = et;
  if(o < 16){
    float w = t2v_w[o], b = t2v_b[o];
    feat[256+o] = (o==0) ? (w*td + b) : sinf(w*td + b);
  }
  __syncthreads();
  float acc = exp_b[o];
  for(int j=0;j<272;j++) acc += feat[j]*exp_W[j*HH+o];
  xout[bl*HH+o] = fmaxf(acc, 0.f);
}

// x (rows of H) @ Wi (H,512) + b -> gpre ; grid = rows, 512 threads
__global__ void k_xwi(const float* x, const float* Wi, const float* bias, float* gpre){
  int row = blockIdx.x; int o = threadIdx.x;
  __shared__ float xs[HH];
  if(o < HH) xs[o] = x[row*HH+o];
  __syncthreads();
  float acc = bias[o];
  for(int h=0;h<HH;h++) acc += xs[h]*Wi[h*512+o];
  gpre[row*512+o] = acc;
}

__global__ void k_zero_state(float* h, float* c){
  int i = blockIdx.x*256 + threadIdx.x;
  if(i < BB*HH){ h[i]=0.f; c[i]=0.f; }
}

// one LSTM time step: grid = BB blocks, 512 threads; in-place h/c state update
__global__ void k_lstm_step(const float* gpre, const float* Wh, float* hstate, float* cstate,
                            float* hout, float* hout2, int l){
  int b = blockIdx.x; int o = threadIdx.x;
  __shared__ float hs[HH];
  __shared__ float gs[512];
  if(o < HH) hs[o] = hstate[b*HH+o];
  __syncthreads();
  float acc = gpre[((size_t)b*LL+l)*512+o];
  #pragma unroll 8
  for(int h=0;h<HH;h++) acc += hs[h]*Wh[h*512+o];
  gs[o] = acc;
  __syncthreads();
  if(o < HH){
    float ig = sigf(gs[o]);
    float fg = sigf(gs[HH+o]);
    float gg = tanhf(gs[2*HH+o]);
    float og = sigf(gs[3*HH+o]);
    float c = fg*cstate[b*HH+o] + ig*gg;
    float h = og*tanhf(c);
    cstate[b*HH+o] = c; hstate[b*HH+o] = h;
    hout[((size_t)b*LL+l)*HH+o] = h;
    if(hout2) hout2[((size_t)b*LL+l)*HH+o] = h;
  }
}

__global__ void k_tok(const int* seq, const int* seq_nt, int* tokid, int* toknt){
  int t = blockIdx.x*blockDim.x + threadIdx.x;
  if(t >= TT) return;
  int b = t % BB, l = t / BB;
  tokid[t] = seq[b*LL+l];
  toknt[t] = seq_nt[b*LL+l];
}

// ---------------- conv prep ----------------
__global__ void k_gather_emb(const int* nid, const float* emb, float* dst){
  int i = blockIdx.x; int o = threadIdx.x;
  dst[i*HH+o] = emb[nid[i]*HH+o];
}

__global__ void k_prep2(const int* sel, const float* xg, const int* g1_nid, const int* g1_nt,
                        float* srcbuf, int* gnid2, int* tsrc2){
  int i = blockIdx.x; int o = threadIdx.x;
  int s = sel[i];
  srcbuf[i*HH+o] = xg[s*HH+o];
  if(o==0){ gnid2[i] = g1_nid[s]; tsrc2[i] = g1_nt[s]; }
}

__global__ void k_dst2(const int* tok_sel, const float* xg, const float* h1, float* dst2){
  int t = blockIdx.x; int o = threadIdx.x;
  int b = t % BB, l = t / BB;
  dst2[t*HH+o] = xg[tok_sel[t]*HH+o] + h1[(b*LL+l)*HH+o];
}

__global__ void k_x0(const int* nid, const int* ntype, const float* emb, const float* hist2,
                     const float* skip, float* srcbuf){
  int i = blockIdx.x; int o = threadIdx.x;
  float a = sigf(skip[ntype[i]]);
  int nd = nid[i];
  srcbuf[i*HH+o] = emb[nd*HH+o]*a + hist2[nd*HH+o]*(1.f-a);
}

// LN + time-mod -> hsbuf; grid = nsrc, 128 threads
__global__ void k_ln_mod(const float* src_h, const int* src_nid,
                         const float* dia_w, const float* dia_b, float* hsbuf){
  int i = blockIdx.x; int o = threadIdx.x;
  __shared__ float red[HH];
  float v = src_h[i*HH+o];
  red[o] = v; __syncthreads();
  for(int s=64;s>0;s>>=1){ if(o<s) red[o]+=red[o+s]; __syncthreads(); }
  float mean = red[0]/(float)HH;
  __syncthreads();
  red[o] = v*v; __syncthreads();
  for(int s=64;s>0;s>>=1){ if(o<s) red[o]+=red[o+s]; __syncthreads(); }
  float var = red[0]/(float)HH - mean*mean;
  float h = (v-mean)*(1.f/sqrtf(fmaxf(var,0.f)+1e-5f));
  if(o >= D2C){
    int nd = src_nid[i];
    h *= sinf(dia_w[nd*HH+o] + dia_b[nd*HH+o]);
  }
  hsbuf[(size_t)i*HH+o] = h;
}

// plain LN (no time-mod) -> out; grid = n, 128 threads
__global__ void k_ln(const float* src_h, float* out){
  int i = blockIdx.x; int o = threadIdx.x;
  __shared__ float red[HH];
  float v = src_h[i*HH+o];
  red[o] = v; __syncthreads();
  for(int s=64;s>0;s>>=1){ if(o<s) red[o]+=red[o+s]; __syncthreads(); }
  float mean = red[0]/(float)HH;
  __syncthreads();
  red[o] = v*v; __syncthreads();
  for(int s=64;s>0;s>>=1){ if(o<s) red[o]+=red[o+s]; __syncthreads(); }
  float var = red[0]/(float)HH - mean*mean;
  out[(size_t)i*HH+o] = (v-mean)*(1.f/sqrtf(fmaxf(var,0.f)+1e-5f));
}

__global__ void k_zero_cnt2(int* a, int* b){
  if(threadIdx.x < NTY){ a[threadIdx.x] = 0; b[threadIdx.x] = 0; }
}

// block-aggregated type scatter: LDS histogram + one global atomic per (block,type)
__global__ void k_scatter_type(const int* types, int n, int* cnts, int* idxb, int stride){
  __shared__ int hist[NTY];
  __shared__ int base[NTY];
  int i = blockIdx.x*256 + threadIdx.x;
  if(threadIdx.x < NTY) hist[threadIdx.x] = 0;
  __syncthreads();
  int t = 0, r = 0;
  bool act = (i < n);
  if(act){ t = types[i]; r = atomicAdd(&hist[t], 1); }
  __syncthreads();
  if(threadIdx.x < NTY && hist[threadIdx.x] > 0)
    base[threadIdx.x] = atomicAdd(&cnts[threadIdx.x], hist[threadIdx.x]);
  __syncthreads();
  if(act) idxb[t*stride + base[t] + r] = i;
}

// ---- tiled type-grouped GEMM core ----
// LDS layout xs[k][j], stride 65: staging writes addr=k*65+j with consecutive
// lanes on consecutive k -> bank stride 1 -> conflict-free (old stride-36 was
// 8-way conflicted: 600k SQ_LDS_BANK_CONFLICT in r5).
// Compute: tid -> o4=(tid&31)*4 column quad (float4 weight loads), ng=tid>>5
// node-group of 8; weights streamed once per 64-node tile.

// dual-output (K,V) version
__global__ void k_gemm_kv2(const float* X, const int* idxb, const int* cnts, int stride,
                           const float* KW, const float* VW, float* Kbuf, float* Vbuf){
  int t = blockIdx.y;
  int cnt = cnts[t];
  int base = blockIdx.x * GT2;
  if(base >= cnt || cnt == 0) return;
  int nn = min(GT2, cnt - base);
  const int* ids = idxb + t*stride + base;
  __shared__ float xs[128*65];
  __shared__ int sid[GT2];
  int tid = threadIdx.x;
  if(tid < GT2) sid[tid] = (tid < nn) ? ids[tid] : ids[0];
  __syncthreads();
  #pragma unroll
  for(int s=0;s<32;s++){
    int elem = tid + 256*s;
    int k = elem & 127, j = elem >> 7;
    xs[k*65 + j] = X[(size_t)sid[j]*HH + k];
  }
  __syncthreads();
  const float* kw = KW + (size_t)t*HH*HH;
  const float* vw = VW + (size_t)t*HH*HH;
  int o4 = (tid & 31)*4;
  int ng = tid >> 5;
  float4 ak[8], av[8];
  #pragma unroll
  for(int j=0;j<8;j++){ ak[j]=make_float4(0,0,0,0); av[j]=make_float4(0,0,0,0); }
  for(int k=0;k<HH;k++){
    float4 wk = *(const float4*)(kw + k*HH + o4);
    float4 wv = *(const float4*)(vw + k*HH + o4);
    const float* xr = xs + k*65 + ng*8;
    #pragma unroll
    for(int j=0;j<8;j++){
      float x = xr[j];
      ak[j].x += x*wk.x; ak[j].y += x*wk.y; ak[j].z += x*wk.z; ak[j].w += x*wk.w;
      av[j].x += x*wv.x; av[j].y += x*wv.y; av[j].z += x*wv.z; av[j].w += x*wv.w;
    }
  }
  #pragma unroll
  for(int j=0;j<8;j++){
    int n = ng*8+j;
    if(n < nn){
      size_t r = (size_t)sid[n]*HH + o4;
      *(float4*)(Kbuf + r) = ak[j];
      *(float4*)(Vbuf + r) = av[j];
    }
  }
}

// single-output version; resid!=null -> Y = acc + resid (+relu); Y2 optional copy
__global__ void k_gemm_t1(const float* X, const int* idxb, const int* cnts, int stride,
                          const float* W, const float* resid, float* Y, float* Y2, int relu){
  int t = blockIdx.y;
  int cnt = cnts[t];
  int base = blockIdx.x * GT2;
  if(base >= cnt || cnt == 0) return;
  int nn = min(GT2, cnt - base);
  const int* ids = idxb + t*stride + base;
  __shared__ float xs[128*65];
  __shared__ int sid[GT2];
  int tid = threadIdx.x;
  if(tid < GT2) sid[tid] = (tid < nn) ? ids[tid] : ids[0];
  __syncthreads();
  #pragma unroll
  for(int s=0;s<32;s++){
    int elem = tid + 256*s;
    int k = elem & 127, j = elem >> 7;
    xs[k*65 + j] = X[(size_t)sid[j]*HH + k];
  }
  __syncthreads();
  const float* w = W + (size_t)t*HH*HH;
  int o4 = (tid & 31)*4;
  int ng = tid >> 5;
  float4 a[8];
  #pragma unroll
  for(int j=0;j<8;j++) a[j]=make_float4(0,0,0,0);
  for(int k=0;k<HH;k++){
    float4 wk = *(const float4*)(w + k*HH + o4);
    const float* xr = xs + k*65 + ng*8;
    #pragma unroll
    for(int j=0;j<8;j++){
      float x = xr[j];
      a[j].x += x*wk.x; a[j].y += x*wk.y; a[j].z += x*wk.z; a[j].w += x*wk.w;
    }
  }
  #pragma unroll
  for(int j=0;j<8;j++){
    int n = ng*8+j;
    if(n < nn){
      size_t r = (size_t)sid[n]*HH + o4;
      float4 v = a[j];
      if(resid){
        float4 rs = *(const float4*)(resid + r);
        v.x += rs.x; v.y += rs.y; v.z += rs.z; v.w += rs.w;
        if(relu){ v.x=fmaxf(v.x,0.f); v.y=fmaxf(v.y,0.f); v.z=fmaxf(v.z,0.f); v.w=fmaxf(v.w,0.f); }
      }
      *(float4*)(Y + r) = v;
      if(Y2) *(float4*)(Y2 + r) = v;
    }
  }
}

// EW2[50][128] = edge_emb @ EW (per conv layer); grid 50, 128 threads
__global__ void k_edge_tab(const float* edge_emb, const float* EWp, float* EW2){
  int r = blockIdx.x; int o = threadIdx.x;
  float acc = 0.f;
  for(int j=0;j<32;j++) acc += edge_emb[r*32+j]*EWp[j*HH+o];
  EW2[r*HH+o] = acc;
}

// one wave per edge (4 edges / 256-thread block); no atomics — just score to Sbuf
__global__ void k_conv_score(const int* esrc, const int* edst, const int* etype, const int* ew,
                             const float* EW2, const float* mu,
                             const float* Kbuf, const float* Qbuf,
                             float* Sbuf, int E){
  int e = blockIdx.x*4 + (threadIdx.x>>6);
  if(e >= E) return;
  int lane = threadIdx.x & 63;
  int src = esrc[e], dst = edst[e], w = ew[e];
  float2 qa = ((const float2*)(Qbuf + (size_t)dst*HH))[lane];
  float2 kb = ((const float2*)(Kbuf + (size_t)src*HH))[lane];
  float2 eb = ((const float2*)(EW2  + (size_t)w  *HH))[lane];
  float p = qa.x*(kb.x+eb.x) + qa.y*(kb.y+eb.y);
  p += __shfl_xor(p, 1, 64);
  p += __shfl_xor(p, 2, 64);
  p += __shfl_xor(p, 4, 64);
  if((lane & 7) == 0){
    int h = lane >> 3;
    Sbuf[(size_t)e*8+h] = p * mu[etype[e]*NH+h] * 0.25f;
  }
}

// ---------------- CSR build (per graph) ----------------
__global__ void k_zero_int(int* p, int n){
  int i = blockIdx.x*256 + threadIdx.x;
  if(i < n) p[i] = 0;
}
__global__ void k_hist_dst(const int* edst, int E, int* cnt){
  int e = blockIdx.x*256 + threadIdx.x;
  if(e < E) atomicAdd(&cnt[edst[e]], 1);
}
// single-block exclusive scan over n bins; writes row_ptr[0..n] and cursor copy
__global__ void k_scan(const int* cnt, int n, int* row_ptr, int* cursor){
  __shared__ int tsum[1024];
  int tid = threadIdx.x;
  int per = (n + 1023) / 1024;
  int start = tid*per; int end = min(start+per, n);
  int s = 0;
  for(int i=start;i<end;i++) s += cnt[i];
  tsum[tid] = s; __syncthreads();
  for(int off=1;off<1024;off<<=1){
    int v = (tid>=off) ? tsum[tid-off] : 0;
    __syncthreads();
    tsum[tid] += v;
    __syncthreads();
  }
  int run = (tid==0) ? 0 : tsum[tid-1];
  for(int i=start;i<end;i++){ row_ptr[i]=run; cursor[i]=run; run += cnt[i]; }
  if(end == n) row_ptr[n] = run;
}
__global__ void k_fill_csr(const int* edst, int E, int* cursor, int* eid){
  int e = blockIdx.x*256 + threadIdx.x;
  if(e >= E) return;
  int pos = atomicAdd(&cursor[edst[e]], 1);
  eid[pos] = e;
}

// fused segment-softmax + V aggregation: one block (128 thr) per dst node; NO atomics.
__global__ void k_conv_soft_agg(const int* row_ptr, const int* eidx, const int* esrc,
                                const float* Sbuf, const float* Vbuf, float* Abuf){
  int d = blockIdx.x; int o = threadIdx.x;
  int r0 = row_ptr[d], r1 = row_ptr[d+1];
  __shared__ float red[HH];
  __shared__ float msh[NH], ish[NH];
  int h8 = o & 7, j16 = o >> 3;
  float mm = -3.0e38f;
  for(int r=r0+j16; r<r1; r+=16) mm = fmaxf(mm, Sbuf[(size_t)eidx[r]*8 + h8]);
  red[o] = mm; __syncthreads();
  for(int s=64;s>=8;s>>=1){ if(o<s) red[o]=fmaxf(red[o],red[o+s]); __syncthreads(); }
  if(o < NH) msh[o] = (r1>r0) ? red[o] : 0.f;
  __syncthreads();
  float dd = 0.f;
  float mh = msh[h8];
  for(int r=r0+j16; r<r1; r+=16) dd += expf(Sbuf[(size_t)eidx[r]*8 + h8] - mh);
  red[o] = dd; __syncthreads();
  for(int s=64;s>=8;s>>=1){ if(o<s) red[o]+=red[o+s]; __syncthreads(); }
  if(o < NH) ish[o] = 1.f / fmaxf(red[o], 1e-9f);
  __syncthreads();
  int h = o >> 4;
  float m = msh[h], inv = ish[h];
  float acc = 0.f;
  for(int r=r0; r<r1; r++){
    int e = eidx[r]; int src = esrc[e];
    float a = expf(Sbuf[(size_t)e*8+h] - m) * inv;
    acc += a * Vbuf[(size_t)src*HH + o];
  }
  Abuf[(size_t)d*HH + o] = acc;
}

// ---------------- stage D: token pooling ----------------
__global__ void k_seq2(const float* x2, float* xout){
  int bl = blockIdx.x; int o = threadIdx.x;
  int b = bl / LL, l = bl % LL;
  xout[bl*HH+o] = x2[(l*BB+b)*HH+o];
}

__global__ void k_zero_hist(float* hist2, float* cnt, unsigned* amax, float* aden){
  int i = blockIdx.x*blockDim.x + threadIdx.x;
  if(i < CHILDN*HH) hist2[i] = 0.f;
  if(i < CHILDN){ cnt[i] = 0.f; aden[i] = 0.f; amax[i] = 0x007FFFFFu; }
}

__global__ void k_tokatt(const float* h2f, const int* toknt, const float* ipW, const float* iaW,
                         float* abuf, unsigned* amax, const int* tokid){
  int t = blockIdx.x; int o = threadIdx.x;
  __shared__ float es[HH];
  __shared__ float red[HH];
  int b = t % BB, l = t / BB;
  es[o] = h2f[(b*LL+l)*HH+o];
  __syncthreads();
  int nt = toknt[t];
  const float* w = ipW + (size_t)nt*HH*HH;
  float acc = 0.f;
  for(int j=0;j<HH;j++) acc += es[j]*w[j*HH+o];
  float u = tanhf(acc);
  red[o] = u * iaW[nt*HH+o];
  __syncthreads();
  for(int s=64;s>0;s>>=1){ if(o<s) red[o]+=red[o+s]; __syncthreads(); }
  if(o==0){
    float a = red[0];
    abuf[t] = a;
    atomicMax(&amax[tokid[t]], fenc(a));
  }
}

__global__ void k_tokexp(const int* tokid, float* abuf, const unsigned* amax, float* aden, float* cnt){
  int t = blockIdx.x*blockDim.x + threadIdx.x;
  if(t >= TT) return;
  int c = tokid[t];
  float ex = expf(abuf[t]-fdec(amax[c]));
  abuf[t] = ex;
  atomicAdd(&aden[c], ex);
  atomicAdd(&cnt[c], 1.f);
}

__global__ void k_tokagg(const int* tokid, const float* abuf, const float* aden,
                         const float* h2f, float* hist2){
  int t = blockIdx.x; int o = threadIdx.x;
  int c = tokid[t];
  float w = abuf[t]/fmaxf(aden[c],1e-9f);
  int b = t % BB, l = t / BB;
  atomicAdd(&hist2[c*HH+o], w*h2f[(b*LL+l)*HH+o]);
}

__global__ void k_histfix(const float* cnt, const float* hist_emb, float* hist2){
  int c = blockIdx.x; int o = threadIdx.x;
  if(cnt[c] == 0.f) hist2[c*HH+o] = hist_emb[c*HH+o];
}

// ---------------- parent pooling ----------------
__global__ void k_zero_parent(float* psum, float* pcnt){
  int i = blockIdx.x*blockDim.x + threadIdx.x;
  if(i < PARENTN*HH) psum[i] = 0.f;
  if(i < PARENTN) pcnt[i] = 0.f;
}

__global__ void k_peagg(const int* pe_p, const int* pe_c, const float* cef, float* psum, float* pcnt){
  int i = blockIdx.x; int o = threadIdx.x;
  int p = pe_p[i], c = pe_c[i];
  atomicAdd(&psum[p*HH+o], cef[c*HH+o]);
  if(o==0) atomicAdd(&pcnt[p], 1.f);
}

__global__ void k_parent(const float* psum, const float* pcnt, float* out){
  int i = blockIdx.x; int o = threadIdx.x;
  out[i*HH+o] = psum[i*HH+o]/fmaxf(pcnt[i],1.f);
}

extern "C" void kernel_launch(void* const* d_in, const int* in_sizes, int n_in,
                              void* d_out, int out_size, void* d_ws, size_t ws_size,
                              hipStream_t stream){
  const int* seq     = (const int*)d_in[0];
  const int* seq_nt  = (const int*)d_in[1];
  const int* dur     = (const int*)d_in[2];
  const int* stime   = (const int*)d_in[3];
  const int* etime   = (const int*)d_in[4];
  const int* g1_nid  = (const int*)d_in[5];
  const int* g1_nt   = (const int*)d_in[6];
  const int* g1_esrc = (const int*)d_in[7];
  const int* g1_edst = (const int*)d_in[8];
  const int* g1_ety  = (const int*)d_in[9];
  const int* g1_ew   = (const int*)d_in[10];
  const int* g2_sel  = (const int*)d_in[11];
  const int* g2_esrc = (const int*)d_in[12];
  const int* g2_edst = (const int*)d_in[13];
  const int* g2_ety  = (const int*)d_in[14];
  const int* g2_ew   = (const int*)d_in[15];
  const int* tok_sel = (const int*)d_in[16];
  const int* g4_esrc = (const int*)d_in[17];
  const int* g4_edst = (const int*)d_in[18];
  const int* g4_ety  = (const int*)d_in[19];
  const int* g4_ew   = (const int*)d_in[20];
  const int* pe_p    = (const int*)d_in[21];
  const int* pe_c    = (const int*)d_in[22];
  const float* emb     = (const float*)d_in[23];
  const float* hist_emb= (const float*)d_in[24];
  const float* edge_emb= (const float*)d_in[25];
  const float* dia_w   = (const float*)d_in[26];
  const float* dia_b   = (const float*)d_in[27];
  const float* t2v_w   = (const float*)d_in[28];
  const float* t2v_b   = (const float*)d_in[29];
  const float* exp_W   = (const float*)d_in[30];
  const float* exp_b   = (const float*)d_in[31];
  const float* l1Wi    = (const float*)d_in[32];
  const float* l1Wh    = (const float*)d_in[33];
  const float* l1b     = (const float*)d_in[34];
  const float* l2Wi    = (const float*)d_in[35];
  const float* l2Wh    = (const float*)d_in[36];
  const float* l2b     = (const float*)d_in[37];
  const float* convK   = (const float*)d_in[38];
  const float* convQ   = (const float*)d_in[39];
  const float* convV   = (const float*)d_in[40];
  const float* convO   = (const float*)d_in[41];
  const float* convE   = (const float*)d_in[42];
  const float* convMu  = (const float*)d_in[43];
  const float* ipW     = (const float*)d_in[44];
  const float* iaW     = (const float*)d_in[45];
  const float* skip    = (const float*)d_in[46];
  float* outp = (float*)d_out;

  // workspace arena
  char* wsp = (char*)d_ws;
  size_t off = 0;
  auto A = [&](size_t nbytes)->char*{ char* p = wsp+off; off += (nbytes+255)&~(size_t)255; return p; };
  float*    srcbuf = (float*)   A((size_t)N1SN*HH*4);
  float*    Kbuf   = (float*)   A((size_t)N1SN*HH*4);
  float*    Vbuf   = (float*)   A((size_t)N1SN*HH*4);
  float*    Qbuf   = (float*)   A((size_t)N1DN*HH*4);
  float*    Sbuf   = (float*)   A((size_t)E1N*8*4);
  float*    Abuf   = (float*)   A((size_t)N1DN*HH*4);
  float*    lnq    = (float*)   A((size_t)N1DN*HH*4);
  float*    xbuf   = (float*)   A((size_t)TT*HH*4);
  float*    gpre   = (float*)   A((size_t)TT*512*4);
  float*    h1     = (float*)   A((size_t)TT*HH*4);
  float*    dst2   = (float*)   A((size_t)TT*HH*4);
  float*    xg     = (float*)   A((size_t)N1DN*HH*4);
  float*    x2     = (float*)   A((size_t)TT*HH*4);
  float*    h2f    = (float*)   A((size_t)TT*HH*4);
  // hsbuf aliases hist2 (disjoint lifetimes on the serial stream)
  float*    hsbuf  = (float*)   A((size_t)N1SN*HH*4);
  float*    hist2  = hsbuf;
  float*    cnt    = (float*)   A((size_t)CHILDN*4);
  float*    abuf   = (float*)   A((size_t)TT*4);
  unsigned* amax   = (unsigned*)A((size_t)CHILDN*4);
  float*    aden   = (float*)   A((size_t)CHILDN*4);
  float*    x3     = (float*)   A((size_t)N1DN*HH*4);
  float*    cef    = (float*)   A((size_t)N4DN*HH*4);
  float*    psum   = (float*)   A((size_t)PARENTN*HH*4);
  float*    pcnt   = (float*)   A((size_t)PARENTN*4);
  int*      tokid  = (int*)     A((size_t)TT*4);
  int*      toknt  = (int*)     A((size_t)TT*4);
  int*      gnid2  = (int*)     A((size_t)N2N*4);
  int*      tsrc2  = (int*)     A((size_t)N2N*4);
  int*      idxb   = (int*)     A((size_t)NTY*N1SN*4);
  int*      idxb2  = (int*)     A((size_t)NTY*N1DN*4);
  int*      cnts   = (int*)     A((size_t)NTY*4);
  int*      cnts2  = (int*)     A((size_t)NTY*4);
  float*    EW2    = (float*)   A((size_t)50*HH*4);
  float*    hstate = (float*)   A((size_t)BB*HH*4);
  float*    cstate = (float*)   A((size_t)BB*HH*4);
  // CSR structures
  int*      g1row  = (int*)     A((size_t)(N1DN+1)*4);
  int*      g1eid  = (int*)     A((size_t)E1N*4);
  int*      g2row  = (int*)     A((size_t)(TT+1)*4);
  int*      g2eid  = (int*)     A((size_t)E2N*4);
  int*      g4row  = (int*)     A((size_t)(N4DN+1)*4);
  int*      g4eid  = (int*)     A((size_t)E4N*4);
  int*      icnt   = (int*)     A((size_t)(N1DN+1)*4);
  int*      icur   = (int*)     A((size_t)(N1DN+1)*4);
  if(off > ws_size) return;  // insufficient scratch: output stays zero

  auto build_csr = [&](const int* edst, int E, int ndst, int* rowp, int* eid){
    k_zero_int<<<(ndst+255)/256, 256, 0, stream>>>(icnt, ndst);
    k_hist_dst<<<(E+255)/256, 256, 0, stream>>>(edst, E, icnt);
    k_scan<<<1, 1024, 0, stream>>>(icnt, ndst, rowp, icur);
    k_fill_csr<<<(E+255)/256, 256, 0, stream>>>(edst, E, icur, eid);
  };

  auto run_conv = [&](const float* src_h, const int* src_nid, const int* src_t, int nsrc,
                      const float* dst_h, const int* dst_t, int ndst,
                      const int* esrc, const int* edst, const int* ety, const int* ew, int E,
                      const int* rowp, const int* eid,
                      int layer, float* outbuf, float* out2, int relu){
    const float* KW  = convK  + (size_t)layer*NTY*HH*HH;
    const float* QW  = convQ  + (size_t)layer*NTY*HH*HH;
    const float* VW  = convV  + (size_t)layer*NTY*HH*HH;
    const float* OW  = convO  + (size_t)layer*NTY*HH*HH;
    const float* EWp = convE  + (size_t)layer*32*HH;
    const float* MU  = convMu + (size_t)layer*NRL*NH;
    // LN/mod inputs + type scatters (src and dst)
    k_ln_mod<<<nsrc, HH, 0, stream>>>(src_h, src_nid, dia_w, dia_b, hsbuf);
    k_ln<<<ndst, HH, 0, stream>>>(dst_h, lnq);
    k_zero_cnt2<<<1, 64, 0, stream>>>(cnts, cnts2);
    k_scatter_type<<<(nsrc+255)/256, 256, 0, stream>>>(src_t, nsrc, cnts, idxb, N1SN);
    k_scatter_type<<<(ndst+255)/256, 256, 0, stream>>>(dst_t, ndst, cnts2, idxb2, N1DN);
    // projections via tiled type-grouped GEMMs
    dim3 gkv((nsrc+GT2-1)/GT2, NTY);
    k_gemm_kv2<<<gkv, 256, 0, stream>>>(hsbuf, idxb, cnts, N1SN, KW, VW, Kbuf, Vbuf);
    dim3 gq((ndst+GT2-1)/GT2, NTY);
    k_gemm_t1<<<gq, 256, 0, stream>>>(lnq, idxb2, cnts2, N1DN, QW, (const float*)nullptr, Qbuf, (float*)nullptr, 0);
    // attention: per-edge score, then per-dst fused softmax+aggregate (no atomics)
    k_edge_tab<<<50, HH, 0, stream>>>(edge_emb, EWp, EW2);
    k_conv_score<<<(E+3)/4, 256, 0, stream>>>(esrc, edst, ety, ew, EW2, MU, Kbuf, Qbuf, Sbuf, E);
    k_conv_soft_agg<<<ndst, HH, 0, stream>>>(rowp, eid, esrc, Sbuf, Vbuf, Abuf);
    // output projection + residual (+relu) via GEMM
    k_gemm_t1<<<gq, 256, 0, stream>>>(Abuf, idxb2, cnts2, N1DN, OW, dst_h, outbuf, out2, relu);
  };

  // ---- stage A: features + LSTM1 ----
  k_featx<<<TT, HH, 0, stream>>>(seq, dur, stime, etime, emb, dia_w, dia_b, t2v_w, t2v_b, exp_W, exp_b, xbuf);
  k_xwi<<<TT, 512, 0, stream>>>(xbuf, l1Wi, l1b, gpre);
  k_zero_state<<<(BB*HH+255)/256, 256, 0, stream>>>(hstate, cstate);
  for(int l=0;l<LL;l++)
    k_lstm_step<<<BB, 512, 0, stream>>>(gpre, l1Wh, hstate, cstate, h1, (float*)nullptr, l);
  k_tok<<<(TT+255)/256, 256, 0, stream>>>(seq, seq_nt, tokid, toknt);

  // ---- CSR for g1 (reused by conv1 and conv3) ----
  build_csr(g1_edst, E1N, N1DN, g1row, g1eid);

  // ---- conv1 on g1 ----
  k_gather_emb<<<N1SN, HH, 0, stream>>>(g1_nid, emb, srcbuf);
  run_conv(srcbuf, g1_nid, g1_nt, N1SN, srcbuf, g1_nt, N1DN,
           g1_esrc, g1_edst, g1_ety, g1_ew, E1N, g1row, g1eid, 0, xg, (float*)nullptr, 1);

  // ---- conv2 on g2 ----
  build_csr(g2_edst, E2N, TT, g2row, g2eid);
  k_prep2<<<N2N, HH, 0, stream>>>(g2_sel, xg, g1_nid, g1_nt, srcbuf, gnid2, tsrc2);
  k_dst2<<<TT, HH, 0, stream>>>(tok_sel, xg, h1, dst2);
  run_conv(srcbuf, gnid2, tsrc2, N2N, dst2, toknt, TT,
           g2_esrc, g2_edst, g2_ety, g2_ew, E2N, g2row, g2eid, 1, x2, (float*)nullptr, 1);

  // ---- LSTM2 (h2 is output 0) ----
  k_seq2<<<TT, HH, 0, stream>>>(x2, xbuf);
  k_xwi<<<TT, 512, 0, stream>>>(xbuf, l2Wi, l2b, gpre);
  k_zero_state<<<(BB*HH+255)/256, 256, 0, stream>>>(hstate, cstate);
  for(int l=0;l<LL;l++)
    k_lstm_step<<<BB, 512, 0, stream>>>(gpre, l2Wh, hstate, cstate, h2f, outp, l);

  // ---- stage D: token attention pooling -> hist2 ----
  k_zero_hist<<<(CHILDN*HH+255)/256, 256, 0, stream>>>(hist2, cnt, amax, aden);
  k_tokatt<<<TT, HH, 0, stream>>>(h2f, toknt, ipW, iaW, abuf, amax, tokid);
  k_tokexp<<<(TT+255)/256, 256, 0, stream>>>(tokid, abuf, amax, aden, cnt);
  k_tokagg<<<TT, HH, 0, stream>>>(tokid, abuf, aden, h2f, hist2);
  k_histfix<<<CHILDN, HH, 0, stream>>>(cnt, hist_emb, hist2);

  // ---- conv3 on g1 with skip-mixed input (g1 CSR reused) ----
  k_x0<<<N1SN, HH, 0, stream>>>(g1_nid, g1_nt, emb, hist2, skip, srcbuf);
  run_conv(srcbuf, g1_nid, g1_nt, N1SN, srcbuf, g1_nt, N1DN,
           g1_esrc, g1_edst, g1_ety, g1_ew, E1N, g1row, g1eid, 2, x3, (float*)nullptr, 1);

  // ---- conv4 on g4 (child_embed = output 1, no relu) ----
  build_csr(g4_edst, E4N, N4DN, g4row, g4eid);
  run_conv(x3, g1_nid, g1_nt, N1DN, x3, g1_nt, N4DN,
           g4_esrc, g4_edst, g4_ety, g4_ew, E4N, g4row, g4eid, 3, cef, outp + (size_t)TT*HH, 0);

  // ---- parent pooling (output 2) ----
  k_zero_parent<<<(PARENTN*HH+255)/256, 256, 0, stream>>>(psum, pcnt);
  k_peagg<<<EC2PN, HH, 0, stream>>>(pe_p, pe_c, cef, psum, pcnt);
  k_parent<<<PARENTN, HH, 0, stream>>>(psum, pcnt, outp + (size_t)TT*HH + (size_t)N4DN*HH);
}

// Round 7
// 1709.087 us; speedup vs baseline: 1.7007x; 1.0987x over previous
//
#include <hip/hip_runtime.h>
#include <math.h>

#define BB 256
#define LL 20
#define HH 128
#define NH 8
#define D2C 64
#define NTY 4
#define NRL 4
#define CHILDN 30001
#define PARENTN 500
#define N1SN 50000
#define N1DN 20000
#define E1N 300000
#define N2N 20000
#define E2N 200000
#define TT (BB*LL)
#define N4DN 5000
#define E4N 150000
#define EC2PN 8000
#define GT2 64   // nodes per GEMM tile

__device__ __forceinline__ unsigned fenc(float f){ unsigned u=__float_as_uint(f); return (u&0x80000000u)? ~u : (u|0x80000000u); }
__device__ __forceinline__ float fdec(unsigned u){ return (u&0x80000000u)? __uint_as_float(u^0x80000000u) : __uint_as_float(~u); }
__device__ __forceinline__ float sigf(float x){ return 1.f/(1.f+expf(-x)); }

// ---------------- Stage A: feature expansion ----------------
__global__ void k_featx(const int* seq, const int* dur, const int* stime, const int* etime,
                        const float* emb, const float* dia_w, const float* dia_b,
                        const float* t2v_w, const float* t2v_b,
                        const float* exp_W, const float* exp_b, float* xout){
  int bl = blockIdx.x; int o = threadIdx.x;
  __shared__ float feat[272];
  int node = seq[bl];
  float ts = (float)stime[bl], te = (float)etime[bl], td = (float)dur[bl];
  float e0 = emb[node*HH+o];
  float st, et;
  if(o < D2C){ st = e0; et = e0; }
  else {
    float w = dia_w[node*HH+o], b = dia_b[node*HH+o];
    st = e0 * sinf(w*ts + b);
    et = e0 * sinf(w*te + b);
  }
  feat[o] = st; feat[HH+o] = et;
  if(o < 16){
    float w = t2v_w[o], b = t2v_b[o];
    feat[256+o] = (o==0) ? (w*td + b) : sinf(w*td + b);
  }
  __syncthreads();
  float acc = exp_b[o];
  for(int j=0;j<272;j++) acc += feat[j]*exp_W[j*HH+o];
  xout[bl*HH+o] = fmaxf(acc, 0.f);
}

// tiled x @ Wi + b -> gpre: 16 rows x 512 cols per block, grid = rows/16.
// replaces per-row matvec that streamed 256KB Wi per row (1.3 GB L2 -> ~40us).
__global__ void k_xwi2(const float* x, const float* Wi, const float* bias, float* gpre, int rows){
  int base = blockIdx.x*16;
  __shared__ float xs[128*17];
  int tid = threadIdx.x;
  #pragma unroll
  for(int s=0;s<8;s++){
    int elem = tid + 256*s;
    int k = elem & 127, j = elem >> 7;
    int r = base + j;
    xs[k*17 + j] = (r < rows) ? x[(size_t)r*HH + k] : 0.f;
  }
  __syncthreads();
  int o4 = (tid & 127)*4;
  int ng = tid >> 7;      // 0/1 -> rows 0-7 / 8-15
  float4 a[8];
  #pragma unroll
  for(int j=0;j<8;j++) a[j]=make_float4(0,0,0,0);
  for(int k=0;k<HH;k++){
    float4 w = *(const float4*)(Wi + (size_t)k*512 + o4);
    const float* xr = xs + k*17 + ng*8;
    #pragma unroll
    for(int j=0;j<8;j++){
      float xv = xr[j];
      a[j].x += xv*w.x; a[j].y += xv*w.y; a[j].z += xv*w.z; a[j].w += xv*w.w;
    }
  }
  float4 bv = *(const float4*)(bias + o4);
  #pragma unroll
  for(int j=0;j<8;j++){
    int r = base + ng*8 + j;
    if(r < rows){
      float4 v = a[j];
      v.x += bv.x; v.y += bv.y; v.z += bv.z; v.w += bv.w;
      *(float4*)(gpre + (size_t)r*512 + o4) = v;
    }
  }
}

__global__ void k_zero_state(float* h, float* c){
  int i = blockIdx.x*256 + threadIdx.x;
  if(i < BB*HH){ h[i]=0.f; c[i]=0.f; }
}

// one LSTM time step: grid = BB blocks, 512 threads; in-place h/c state update
__global__ void k_lstm_step(const float* gpre, const float* Wh, float* hstate, float* cstate,
                            float* hout, float* hout2, int l){
  int b = blockIdx.x; int o = threadIdx.x;
  __shared__ float hs[HH];
  __shared__ float gs[512];
  if(o < HH) hs[o] = hstate[b*HH+o];
  __syncthreads();
  float acc = gpre[((size_t)b*LL+l)*512+o];
  #pragma unroll 8
  for(int h=0;h<HH;h++) acc += hs[h]*Wh[h*512+o];
  gs[o] = acc;
  __syncthreads();
  if(o < HH){
    float ig = sigf(gs[o]);
    float fg = sigf(gs[HH+o]);
    float gg = tanhf(gs[2*HH+o]);
    float og = sigf(gs[3*HH+o]);
    float c = fg*cstate[b*HH+o] + ig*gg;
    float h = og*tanhf(c);
    cstate[b*HH+o] = c; hstate[b*HH+o] = h;
    hout[((size_t)b*LL+l)*HH+o] = h;
    if(hout2) hout2[((size_t)b*LL+l)*HH+o] = h;
  }
}

__global__ void k_tok(const int* seq, const int* seq_nt, int* tokid, int* toknt){
  int t = blockIdx.x*blockDim.x + threadIdx.x;
  if(t >= TT) return;
  int b = t % BB, l = t / BB;
  tokid[t] = seq[b*LL+l];
  toknt[t] = seq_nt[b*LL+l];
}

// ---------------- conv prep ----------------
__global__ void k_gather_emb(const int* nid, const float* emb, float* dst){
  int i = blockIdx.x; int o = threadIdx.x;
  dst[i*HH+o] = emb[nid[i]*HH+o];
}

__global__ void k_prep2(const int* sel, const float* xg, const int* g1_nid, const int* g1_nt,
                        float* srcbuf, int* gnid2, int* tsrc2){
  int i = blockIdx.x; int o = threadIdx.x;
  int s = sel[i];
  srcbuf[i*HH+o] = xg[s*HH+o];
  if(o==0){ gnid2[i] = g1_nid[s]; tsrc2[i] = g1_nt[s]; }
}

__global__ void k_dst2(const int* tok_sel, const float* xg, const float* h1, float* dst2){
  int t = blockIdx.x; int o = threadIdx.x;
  int b = t % BB, l = t / BB;
  dst2[t*HH+o] = xg[tok_sel[t]*HH+o] + h1[(b*LL+l)*HH+o];
}

__global__ void k_x0(const int* nid, const int* ntype, const float* emb, const float* hist2,
                     const float* skip, float* srcbuf){
  int i = blockIdx.x; int o = threadIdx.x;
  float a = sigf(skip[ntype[i]]);
  int nd = nid[i];
  srcbuf[i*HH+o] = emb[nd*HH+o]*a + hist2[nd*HH+o]*(1.f-a);
}

// LN + time-mod -> hsbuf; grid = nsrc, 128 threads
__global__ void k_ln_mod(const float* src_h, const int* src_nid,
                         const float* dia_w, const float* dia_b, float* hsbuf){
  int i = blockIdx.x; int o = threadIdx.x;
  __shared__ float red[HH];
  float v = src_h[i*HH+o];
  red[o] = v; __syncthreads();
  for(int s=64;s>0;s>>=1){ if(o<s) red[o]+=red[o+s]; __syncthreads(); }
  float mean = red[0]/(float)HH;
  __syncthreads();
  red[o] = v*v; __syncthreads();
  for(int s=64;s>0;s>>=1){ if(o<s) red[o]+=red[o+s]; __syncthreads(); }
  float var = red[0]/(float)HH - mean*mean;
  float h = (v-mean)*(1.f/sqrtf(fmaxf(var,0.f)+1e-5f));
  if(o >= D2C){
    int nd = src_nid[i];
    h *= sinf(dia_w[nd*HH+o] + dia_b[nd*HH+o]);
  }
  hsbuf[(size_t)i*HH+o] = h;
}

// plain LN (no time-mod) -> out; grid = n, 128 threads
__global__ void k_ln(const float* src_h, float* out){
  int i = blockIdx.x; int o = threadIdx.x;
  __shared__ float red[HH];
  float v = src_h[i*HH+o];
  red[o] = v; __syncthreads();
  for(int s=64;s>0;s>>=1){ if(o<s) red[o]+=red[o+s]; __syncthreads(); }
  float mean = red[0]/(float)HH;
  __syncthreads();
  red[o] = v*v; __syncthreads();
  for(int s=64;s>0;s>>=1){ if(o<s) red[o]+=red[o+s]; __syncthreads(); }
  float var = red[0]/(float)HH - mean*mean;
  out[(size_t)i*HH+o] = (v-mean)*(1.f/sqrtf(fmaxf(var,0.f)+1e-5f));
}

__global__ void k_zero_cnt2(int* a, int* b){
  if(threadIdx.x < NTY){ a[threadIdx.x] = 0; b[threadIdx.x] = 0; }
}

// block-aggregated type scatter: LDS histogram + one global atomic per (block,type)
__global__ void k_scatter_type(const int* types, int n, int* cnts, int* idxb, int stride){
  __shared__ int hist[NTY];
  __shared__ int base[NTY];
  int i = blockIdx.x*256 + threadIdx.x;
  if(threadIdx.x < NTY) hist[threadIdx.x] = 0;
  __syncthreads();
  int t = 0, r = 0;
  bool act = (i < n);
  if(act){ t = types[i]; r = atomicAdd(&hist[t], 1); }
  __syncthreads();
  if(threadIdx.x < NTY && hist[threadIdx.x] > 0)
    base[threadIdx.x] = atomicAdd(&cnts[threadIdx.x], hist[threadIdx.x]);
  __syncthreads();
  if(act) idxb[t*stride + base[t] + r] = i;
}

// ---- tiled type-grouped GEMM core (conflict-free stride-65 LDS) ----
__global__ void k_gemm_kv2(const float* X, const int* idxb, const int* cnts, int stride,
                           const float* KW, const float* VW, float* Kbuf, float* Vbuf){
  int t = blockIdx.y;
  int cnt = cnts[t];
  int base = blockIdx.x * GT2;
  if(base >= cnt || cnt == 0) return;
  int nn = min(GT2, cnt - base);
  const int* ids = idxb + t*stride + base;
  __shared__ float xs[128*65];
  __shared__ int sid[GT2];
  int tid = threadIdx.x;
  if(tid < GT2) sid[tid] = (tid < nn) ? ids[tid] : ids[0];
  __syncthreads();
  #pragma unroll
  for(int s=0;s<32;s++){
    int elem = tid + 256*s;
    int k = elem & 127, j = elem >> 7;
    xs[k*65 + j] = X[(size_t)sid[j]*HH + k];
  }
  __syncthreads();
  const float* kw = KW + (size_t)t*HH*HH;
  const float* vw = VW + (size_t)t*HH*HH;
  int o4 = (tid & 31)*4;
  int ng = tid >> 5;
  float4 ak[8], av[8];
  #pragma unroll
  for(int j=0;j<8;j++){ ak[j]=make_float4(0,0,0,0); av[j]=make_float4(0,0,0,0); }
  for(int k=0;k<HH;k++){
    float4 wk = *(const float4*)(kw + k*HH + o4);
    float4 wv = *(const float4*)(vw + k*HH + o4);
    const float* xr = xs + k*65 + ng*8;
    #pragma unroll
    for(int j=0;j<8;j++){
      float x = xr[j];
      ak[j].x += x*wk.x; ak[j].y += x*wk.y; ak[j].z += x*wk.z; ak[j].w += x*wk.w;
      av[j].x += x*wv.x; av[j].y += x*wv.y; av[j].z += x*wv.z; av[j].w += x*wv.w;
    }
  }
  #pragma unroll
  for(int j=0;j<8;j++){
    int n = ng*8+j;
    if(n < nn){
      size_t r = (size_t)sid[n]*HH + o4;
      *(float4*)(Kbuf + r) = ak[j];
      *(float4*)(Vbuf + r) = av[j];
    }
  }
}

// single-output version; resid!=null -> Y = acc + resid (+relu); Y2 optional copy
__global__ void k_gemm_t1(const float* X, const int* idxb, const int* cnts, int stride,
                          const float* W, const float* resid, float* Y, float* Y2, int relu){
  int t = blockIdx.y;
  int cnt = cnts[t];
  int base = blockIdx.x * GT2;
  if(base >= cnt || cnt == 0) return;
  int nn = min(GT2, cnt - base);
  const int* ids = idxb + t*stride + base;
  __shared__ float xs[128*65];
  __shared__ int sid[GT2];
  int tid = threadIdx.x;
  if(tid < GT2) sid[tid] = (tid < nn) ? ids[tid] : ids[0];
  __syncthreads();
  #pragma unroll
  for(int s=0;s<32;s++){
    int elem = tid + 256*s;
    int k = elem & 127, j = elem >> 7;
    xs[k*65 + j] = X[(size_t)sid[j]*HH + k];
  }
  __syncthreads();
  const float* w = W + (size_t)t*HH*HH;
  int o4 = (tid & 31)*4;
  int ng = tid >> 5;
  float4 a[8];
  #pragma unroll
  for(int j=0;j<8;j++) a[j]=make_float4(0,0,0,0);
  for(int k=0;k<HH;k++){
    float4 wk = *(const float4*)(w + k*HH + o4);
    const float* xr = xs + k*65 + ng*8;
    #pragma unroll
    for(int j=0;j<8;j++){
      float x = xr[j];
      a[j].x += x*wk.x; a[j].y += x*wk.y; a[j].z += x*wk.z; a[j].w += x*wk.w;
    }
  }
  #pragma unroll
  for(int j=0;j<8;j++){
    int n = ng*8+j;
    if(n < nn){
      size_t r = (size_t)sid[n]*HH + o4;
      float4 v = a[j];
      if(resid){
        float4 rs = *(const float4*)(resid + r);
        v.x += rs.x; v.y += rs.y; v.z += rs.z; v.w += rs.w;
        if(relu){ v.x=fmaxf(v.x,0.f); v.y=fmaxf(v.y,0.f); v.z=fmaxf(v.z,0.f); v.w=fmaxf(v.w,0.f); }
      }
      *(float4*)(Y + r) = v;
      if(Y2) *(float4*)(Y2 + r) = v;
    }
  }
}

// EW2[50][128] = edge_emb @ EW (per conv layer); grid 50, 128 threads
__global__ void k_edge_tab(const float* edge_emb, const float* EWp, float* EW2){
  int r = blockIdx.x; int o = threadIdx.x;
  float acc = 0.f;
  for(int j=0;j<32;j++) acc += edge_emb[r*32+j]*EWp[j*HH+o];
  EW2[r*HH+o] = acc;
}

// ---------------- CSR build (per graph) ----------------
__global__ void k_zero_int(int* p, int n){
  int i = blockIdx.x*256 + threadIdx.x;
  if(i < n) p[i] = 0;
}
__global__ void k_hist_dst(const int* edst, int E, int* cnt){
  int e = blockIdx.x*256 + threadIdx.x;
  if(e < E) atomicAdd(&cnt[edst[e]], 1);
}
__global__ void k_scan(const int* cnt, int n, int* row_ptr, int* cursor){
  __shared__ int tsum[1024];
  int tid = threadIdx.x;
  int per = (n + 1023) / 1024;
  int start = tid*per; int end = min(start+per, n);
  int s = 0;
  for(int i=start;i<end;i++) s += cnt[i];
  tsum[tid] = s; __syncthreads();
  for(int off=1;off<1024;off<<=1){
    int v = (tid>=off) ? tsum[tid-off] : 0;
    __syncthreads();
    tsum[tid] += v;
    __syncthreads();
  }
  int run = (tid==0) ? 0 : tsum[tid-1];
  for(int i=start;i<end;i++){ row_ptr[i]=run; cursor[i]=run; run += cnt[i]; }
  if(end == n) row_ptr[n] = run;
}
__global__ void k_fill_csr(const int* edst, int E, int* cursor, int* eid){
  int e = blockIdx.x*256 + threadIdx.x;
  if(e >= E) return;
  int pos = atomicAdd(&cursor[edst[e]], 1);
  eid[pos] = e;
}
// permute edge attribute arrays into CSR order (coalesced inner loops later)
__global__ void k_permute_edges(const int* eid, const int* esrc, const int* ew, const int* ety,
                                int E, int* esrc_s, int* ew_s, int* ety_s){
  int r = blockIdx.x*256 + threadIdx.x;
  if(r >= E) return;
  int e = eid[r];
  esrc_s[r] = esrc[e]; ew_s[r] = ew[e]; ety_s[r] = ety[e];
}

// fused per-dst attention: score + softmax + V-aggregate in one kernel.
// Q row loaded ONCE per dst (kills the 512B-per-edge Q refetch that made
// k_conv_score fetch 151MB). 128 threads; head h = o>>4 (16 dims each).
__global__ void k_attn_fused(const int* row_ptr, const int* esrc_s, const int* ew_s, const int* ety_s,
                             const float* Kbuf, const float* Vbuf, const float* Qbuf,
                             const float* EW2, const float* mu,
                             float* Sbuf, float* Abuf){
  int d = blockIdx.x; int o = threadIdx.x;
  int r0 = row_ptr[d], r1 = row_ptr[d+1];
  __shared__ float q[HH];
  q[o] = Qbuf[(size_t)d*HH+o];
  __syncthreads();
  int h = o >> 4;
  float qo = q[o];
  float m = -3.0e38f;
  // phase 1: scores (K gather coalesced; EW2 is a 25KB L2-resident table)
  for(int r=r0; r<r1; r++){
    int src = esrc_s[r], w = ew_s[r];
    float p = qo*(Kbuf[(size_t)src*HH+o] + EW2[w*HH+o]);
    p += __shfl_xor(p, 1, 64);
    p += __shfl_xor(p, 2, 64);
    p += __shfl_xor(p, 4, 64);
    p += __shfl_xor(p, 8, 64);   // all 16 lanes of the head group hold the sum
    float s = p * mu[ety_s[r]*NH+h] * 0.25f;
    if((o & 15) == 0) Sbuf[(size_t)r*8+h] = s;
    m = fmaxf(m, s);
  }
  __threadfence_block();
  __syncthreads();
  // phase 2: denom (16 lanes stride edges per head)
  float dd = 0.f;
  int j16 = o & 15;
  for(int r=r0+j16; r<r1; r+=16) dd += expf(Sbuf[(size_t)r*8+h] - m);
  dd += __shfl_xor(dd, 1, 64);
  dd += __shfl_xor(dd, 2, 64);
  dd += __shfl_xor(dd, 4, 64);
  dd += __shfl_xor(dd, 8, 64);
  float inv = 1.f / fmaxf(dd, 1e-9f);
  // phase 3: aggregate V (gather coalesced)
  float acc = 0.f;
  for(int r=r0; r<r1; r++){
    float a = expf(Sbuf[(size_t)r*8+h] - m) * inv;
    acc += a * Vbuf[(size_t)esrc_s[r]*HH + o];
  }
  Abuf[(size_t)d*HH + o] = acc;
}

// ---------------- stage D: token pooling ----------------
__global__ void k_seq2(const float* x2, float* xout){
  int bl = blockIdx.x; int o = threadIdx.x;
  int b = bl / LL, l = bl % LL;
  xout[bl*HH+o] = x2[(l*BB+b)*HH+o];
}

__global__ void k_zero_hist(float* hist2, float* cnt, unsigned* amax, float* aden){
  int i = blockIdx.x*blockDim.x + threadIdx.x;
  if(i < CHILDN*HH) hist2[i] = 0.f;
  if(i < CHILDN){ cnt[i] = 0.f; aden[i] = 0.f; amax[i] = 0x007FFFFFu; }
}

__global__ void k_tokatt(const float* h2f, const int* toknt, const float* ipW, const float* iaW,
                         float* abuf, unsigned* amax, const int* tokid){
  int t = blockIdx.x; int o = threadIdx.x;
  __shared__ float es[HH];
  __shared__ float red[HH];
  int b = t % BB, l = t / BB;
  es[o] = h2f[(b*LL+l)*HH+o];
  __syncthreads();
  int nt = toknt[t];
  const float* w = ipW + (size_t)nt*HH*HH;
  float acc = 0.f;
  for(int j=0;j<HH;j++) acc += es[j]*w[j*HH+o];
  float u = tanhf(acc);
  red[o] = u * iaW[nt*HH+o];
  __syncthreads();
  for(int s=64;s>0;s>>=1){ if(o<s) red[o]+=red[o+s]; __syncthreads(); }
  if(o==0){
    float a = red[0];
    abuf[t] = a;
    atomicMax(&amax[tokid[t]], fenc(a));
  }
}

__global__ void k_tokexp(const int* tokid, float* abuf, const unsigned* amax, float* aden, float* cnt){
  int t = blockIdx.x*blockDim.x + threadIdx.x;
  if(t >= TT) return;
  int c = tokid[t];
  float ex = expf(abuf[t]-fdec(amax[c]));
  abuf[t] = ex;
  atomicAdd(&aden[c], ex);
  atomicAdd(&cnt[c], 1.f);
}

__global__ void k_tokagg(const int* tokid, const float* abuf, const float* aden,
                         const float* h2f, float* hist2){
  int t = blockIdx.x; int o = threadIdx.x;
  int c = tokid[t];
  float w = abuf[t]/fmaxf(aden[c],1e-9f);
  int b = t % BB, l = t / BB;
  atomicAdd(&hist2[c*HH+o], w*h2f[(b*LL+l)*HH+o]);
}

__global__ void k_histfix(const float* cnt, const float* hist_emb, float* hist2){
  int c = blockIdx.x; int o = threadIdx.x;
  if(cnt[c] == 0.f) hist2[c*HH+o] = hist_emb[c*HH+o];
}

// ---------------- parent pooling ----------------
__global__ void k_zero_parent(float* psum, float* pcnt){
  int i = blockIdx.x*blockDim.x + threadIdx.x;
  if(i < PARENTN*HH) psum[i] = 0.f;
  if(i < PARENTN) pcnt[i] = 0.f;
}

__global__ void k_peagg(const int* pe_p, const int* pe_c, const float* cef, float* psum, float* pcnt){
  int i = blockIdx.x; int o = threadIdx.x;
  int p = pe_p[i], c = pe_c[i];
  atomicAdd(&psum[p*HH+o], cef[c*HH+o]);
  if(o==0) atomicAdd(&pcnt[p], 1.f);
}

__global__ void k_parent(const float* psum, const float* pcnt, float* out){
  int i = blockIdx.x; int o = threadIdx.x;
  out[i*HH+o] = psum[i*HH+o]/fmaxf(pcnt[i],1.f);
}

extern "C" void kernel_launch(void* const* d_in, const int* in_sizes, int n_in,
                              void* d_out, int out_size, void* d_ws, size_t ws_size,
                              hipStream_t stream){
  const int* seq     = (const int*)d_in[0];
  const int* seq_nt  = (const int*)d_in[1];
  const int* dur     = (const int*)d_in[2];
  const int* stime   = (const int*)d_in[3];
  const int* etime   = (const int*)d_in[4];
  const int* g1_nid  = (const int*)d_in[5];
  const int* g1_nt   = (const int*)d_in[6];
  const int* g1_esrc = (const int*)d_in[7];
  const int* g1_edst = (const int*)d_in[8];
  const int* g1_ety  = (const int*)d_in[9];
  const int* g1_ew   = (const int*)d_in[10];
  const int* g2_sel  = (const int*)d_in[11];
  const int* g2_esrc = (const int*)d_in[12];
  const int* g2_edst = (const int*)d_in[13];
  const int* g2_ety  = (const int*)d_in[14];
  const int* g2_ew   = (const int*)d_in[15];
  const int* tok_sel = (const int*)d_in[16];
  const int* g4_esrc = (const int*)d_in[17];
  const int* g4_edst = (const int*)d_in[18];
  const int* g4_ety  = (const int*)d_in[19];
  const int* g4_ew   = (const int*)d_in[20];
  const int* pe_p    = (const int*)d_in[21];
  const int* pe_c    = (const int*)d_in[22];
  const float* emb     = (const float*)d_in[23];
  const float* hist_emb= (const float*)d_in[24];
  const float* edge_emb= (const float*)d_in[25];
  const float* dia_w   = (const float*)d_in[26];
  const float* dia_b   = (const float*)d_in[27];
  const float* t2v_w   = (const float*)d_in[28];
  const float* t2v_b   = (const float*)d_in[29];
  const float* exp_W   = (const float*)d_in[30];
  const float* exp_b   = (const float*)d_in[31];
  const float* l1Wi    = (const float*)d_in[32];
  const float* l1Wh    = (const float*)d_in[33];
  const float* l1b     = (const float*)d_in[34];
  const float* l2Wi    = (const float*)d_in[35];
  const float* l2Wh    = (const float*)d_in[36];
  const float* l2b     = (const float*)d_in[37];
  const float* convK   = (const float*)d_in[38];
  const float* convQ   = (const float*)d_in[39];
  const float* convV   = (const float*)d_in[40];
  const float* convO   = (const float*)d_in[41];
  const float* convE   = (const float*)d_in[42];
  const float* convMu  = (const float*)d_in[43];
  const float* ipW     = (const float*)d_in[44];
  const float* iaW     = (const float*)d_in[45];
  const float* skip    = (const float*)d_in[46];
  float* outp = (float*)d_out;

  // workspace arena
  char* wsp = (char*)d_ws;
  size_t off = 0;
  auto A = [&](size_t nbytes)->char*{ char* p = wsp+off; off += (nbytes+255)&~(size_t)255; return p; };
  float*    srcbuf = (float*)   A((size_t)N1SN*HH*4);
  float*    Kbuf   = (float*)   A((size_t)N1SN*HH*4);
  float*    Vbuf   = (float*)   A((size_t)N1SN*HH*4);
  float*    Qbuf   = (float*)   A((size_t)N1DN*HH*4);
  float*    Sbuf   = (float*)   A((size_t)E1N*8*4);
  float*    Abuf   = (float*)   A((size_t)N1DN*HH*4);
  float*    lnq    = (float*)   A((size_t)N1DN*HH*4);
  float*    xbuf   = (float*)   A((size_t)TT*HH*4);
  float*    gpre   = (float*)   A((size_t)TT*512*4);
  float*    h1     = (float*)   A((size_t)TT*HH*4);
  float*    dst2   = (float*)   A((size_t)TT*HH*4);
  float*    xg     = (float*)   A((size_t)N1DN*HH*4);
  float*    x2     = (float*)   A((size_t)TT*HH*4);
  float*    h2f    = (float*)   A((size_t)TT*HH*4);
  // hsbuf aliases hist2 (disjoint lifetimes on the serial stream)
  float*    hsbuf  = (float*)   A((size_t)N1SN*HH*4);
  float*    hist2  = hsbuf;
  float*    cnt    = (float*)   A((size_t)CHILDN*4);
  float*    abuf   = (float*)   A((size_t)TT*4);
  unsigned* amax   = (unsigned*)A((size_t)CHILDN*4);
  float*    aden   = (float*)   A((size_t)CHILDN*4);
  float*    x3     = (float*)   A((size_t)N1DN*HH*4);
  float*    cef    = (float*)   A((size_t)N4DN*HH*4);
  float*    psum   = (float*)   A((size_t)PARENTN*HH*4);
  float*    pcnt   = (float*)   A((size_t)PARENTN*4);
  int*      tokid  = (int*)     A((size_t)TT*4);
  int*      toknt  = (int*)     A((size_t)TT*4);
  int*      gnid2  = (int*)     A((size_t)N2N*4);
  int*      tsrc2  = (int*)     A((size_t)N2N*4);
  int*      idxb   = (int*)     A((size_t)NTY*N1SN*4);
  int*      idxb2  = (int*)     A((size_t)NTY*N1DN*4);
  int*      cnts   = (int*)     A((size_t)NTY*4);
  int*      cnts2  = (int*)     A((size_t)NTY*4);
  float*    EW2    = (float*)   A((size_t)50*HH*4);
  float*    hstate = (float*)   A((size_t)BB*HH*4);
  float*    cstate = (float*)   A((size_t)BB*HH*4);
  // CSR structures + CSR-ordered edge attributes
  int*      g1row  = (int*)     A((size_t)(N1DN+1)*4);
  int*      g1eid  = (int*)     A((size_t)E1N*4);
  int*      g1src_s= (int*)     A((size_t)E1N*4);
  int*      g1ew_s = (int*)     A((size_t)E1N*4);
  int*      g1ety_s= (int*)     A((size_t)E1N*4);
  int*      g2row  = (int*)     A((size_t)(TT+1)*4);
  int*      g2eid  = (int*)     A((size_t)E2N*4);
  int*      g2src_s= (int*)     A((size_t)E2N*4);
  int*      g2ew_s = (int*)     A((size_t)E2N*4);
  int*      g2ety_s= (int*)     A((size_t)E2N*4);
  int*      g4row  = (int*)     A((size_t)(N4DN+1)*4);
  int*      g4eid  = (int*)     A((size_t)E4N*4);
  int*      g4src_s= (int*)     A((size_t)E4N*4);
  int*      g4ew_s = (int*)     A((size_t)E4N*4);
  int*      g4ety_s= (int*)     A((size_t)E4N*4);
  int*      icnt   = (int*)     A((size_t)(N1DN+1)*4);
  int*      icur   = (int*)     A((size_t)(N1DN+1)*4);
  if(off > ws_size) return;  // insufficient scratch: output stays zero

  auto build_csr = [&](const int* edst, const int* esrc, const int* ew, const int* ety,
                       int E, int ndst, int* rowp, int* eid, int* src_s, int* ew_s, int* ety_s){
    k_zero_int<<<(ndst+255)/256, 256, 0, stream>>>(icnt, ndst);
    k_hist_dst<<<(E+255)/256, 256, 0, stream>>>(edst, E, icnt);
    k_scan<<<1, 1024, 0, stream>>>(icnt, ndst, rowp, icur);
    k_fill_csr<<<(E+255)/256, 256, 0, stream>>>(edst, E, icur, eid);
    k_permute_edges<<<(E+255)/256, 256, 0, stream>>>(eid, esrc, ew, ety, E, src_s, ew_s, ety_s);
  };

  auto run_conv = [&](const float* src_h, const int* src_nid, const int* src_t, int nsrc,
                      const float* dst_h, const int* dst_t, int ndst,
                      const int* rowp, const int* src_s, const int* ew_s, const int* ety_s,
                      int layer, float* outbuf, float* out2, int relu){
    const float* KW  = convK  + (size_t)layer*NTY*HH*HH;
    const float* QW  = convQ  + (size_t)layer*NTY*HH*HH;
    const float* VW  = convV  + (size_t)layer*NTY*HH*HH;
    const float* OW  = convO  + (size_t)layer*NTY*HH*HH;
    const float* EWp = convE  + (size_t)layer*32*HH;
    const float* MU  = convMu + (size_t)layer*NRL*NH;
    // LN/mod inputs + type scatters (src and dst)
    k_ln_mod<<<nsrc, HH, 0, stream>>>(src_h, src_nid, dia_w, dia_b, hsbuf);
    k_ln<<<ndst, HH, 0, stream>>>(dst_h, lnq);
    k_zero_cnt2<<<1, 64, 0, stream>>>(cnts, cnts2);
    k_scatter_type<<<(nsrc+255)/256, 256, 0, stream>>>(src_t, nsrc, cnts, idxb, N1SN);
    k_scatter_type<<<(ndst+255)/256, 256, 0, stream>>>(dst_t, ndst, cnts2, idxb2, N1DN);
    // projections via tiled type-grouped GEMMs
    dim3 gkv((nsrc+GT2-1)/GT2, NTY);
    k_gemm_kv2<<<gkv, 256, 0, stream>>>(hsbuf, idxb, cnts, N1SN, KW, VW, Kbuf, Vbuf);
    dim3 gq((ndst+GT2-1)/GT2, NTY);
    k_gemm_t1<<<gq, 256, 0, stream>>>(lnq, idxb2, cnts2, N1DN, QW, (const float*)nullptr, Qbuf, (float*)nullptr, 0);
    // fused attention (score + softmax + aggregate), CSR-ordered, no atomics
    k_edge_tab<<<50, HH, 0, stream>>>(edge_emb, EWp, EW2);
    k_attn_fused<<<ndst, HH, 0, stream>>>(rowp, src_s, ew_s, ety_s, Kbuf, Vbuf, Qbuf, EW2, MU, Sbuf, Abuf);
    // output projection + residual (+relu) via GEMM
    k_gemm_t1<<<gq, 256, 0, stream>>>(Abuf, idxb2, cnts2, N1DN, OW, dst_h, outbuf, out2, relu);
  };

  // ---- stage A: features + LSTM1 ----
  k_featx<<<TT, HH, 0, stream>>>(seq, dur, stime, etime, emb, dia_w, dia_b, t2v_w, t2v_b, exp_W, exp_b, xbuf);
  k_xwi2<<<(TT+15)/16, 256, 0, stream>>>(xbuf, l1Wi, l1b, gpre, TT);
  k_zero_state<<<(BB*HH+255)/256, 256, 0, stream>>>(hstate, cstate);
  for(int l=0;l<LL;l++)
    k_lstm_step<<<BB, 512, 0, stream>>>(gpre, l1Wh, hstate, cstate, h1, (float*)nullptr, l);
  k_tok<<<(TT+255)/256, 256, 0, stream>>>(seq, seq_nt, tokid, toknt);

  // ---- CSR for g1 (reused by conv1 and conv3) ----
  build_csr(g1_edst, g1_esrc, g1_ew, g1_ety, E1N, N1DN, g1row, g1eid, g1src_s, g1ew_s, g1ety_s);

  // ---- conv1 on g1 ----
  k_gather_emb<<<N1SN, HH, 0, stream>>>(g1_nid, emb, srcbuf);
  run_conv(srcbuf, g1_nid, g1_nt, N1SN, srcbuf, g1_nt, N1DN,
           g1row, g1src_s, g1ew_s, g1ety_s, 0, xg, (float*)nullptr, 1);

  // ---- conv2 on g2 ----
  build_csr(g2_edst, g2_esrc, g2_ew, g2_ety, E2N, TT, g2row, g2eid, g2src_s, g2ew_s, g2ety_s);
  k_prep2<<<N2N, HH, 0, stream>>>(g2_sel, xg, g1_nid, g1_nt, srcbuf, gnid2, tsrc2);
  k_dst2<<<TT, HH, 0, stream>>>(tok_sel, xg, h1, dst2);
  run_conv(srcbuf, gnid2, tsrc2, N2N, dst2, toknt, TT,
           g2row, g2src_s, g2ew_s, g2ety_s, 1, x2, (float*)nullptr, 1);

  // ---- LSTM2 (h2 is output 0) ----
  k_seq2<<<TT, HH, 0, stream>>>(x2, xbuf);
  k_xwi2<<<(TT+15)/16, 256, 0, stream>>>(xbuf, l2Wi, l2b, gpre, TT);
  k_zero_state<<<(BB*HH+255)/256, 256, 0, stream>>>(hstate, cstate);
  for(int l=0;l<LL;l++)
    k_lstm_step<<<BB, 512, 0, stream>>>(gpre, l2Wh, hstate, cstate, h2f, outp, l);

  // ---- stage D: token attention pooling -> hist2 ----
  k_zero_hist<<<(CHILDN*HH+255)/256, 256, 0, stream>>>(hist2, cnt, amax, aden);
  k_tokatt<<<TT, HH, 0, stream>>>(h2f, toknt, ipW, iaW, abuf, amax, tokid);
  k_tokexp<<<(TT+255)/256, 256, 0, stream>>>(tokid, abuf, amax, aden, cnt);
  k_tokagg<<<TT, HH, 0, stream>>>(tokid, abuf, aden, h2f, hist2);
  k_histfix<<<CHILDN, HH, 0, stream>>>(cnt, hist_emb, hist2);

  // ---- conv3 on g1 with skip-mixed input (g1 CSR reused) ----
  k_x0<<<N1SN, HH, 0, stream>>>(g1_nid, g1_nt, emb, hist2, skip, srcbuf);
  run_conv(srcbuf, g1_nid, g1_nt, N1SN, srcbuf, g1_nt, N1DN,
           g1row, g1src_s, g1ew_s, g1ety_s, 2, x3, (float*)nullptr, 1);

  // ---- conv4 on g4 (child_embed = output 1, no relu) ----
  build_csr(g4_edst, g4_esrc, g4_ew, g4_ety, E4N, N4DN, g4row, g4eid, g4src_s, g4ew_s, g4ety_s);
  run_conv(x3, g1_nid, g1_nt, N1DN, x3, g1_nt, N4DN,
           g4row, g4src_s, g4ew_s, g4ety_s, 3, cef, outp + (size_t)TT*HH, 0);

  // ---- parent pooling (output 2) ----
  k_zero_parent<<<(PARENTN*HH+255)/256, 256, 0, stream>>>(psum, pcnt);
  k_peagg<<<EC2PN, HH, 0, stream>>>(pe_p, pe_c, cef, psum, pcnt);
  k_parent<<<PARENTN, HH, 0, stream>>>(psum, pcnt, outp + (size_t)TT*HH + (size_t)N4DN*HH);
}

// Round 8
// 1602.075 us; speedup vs baseline: 1.8143x; 1.0668x over previous
//
#include <hip/hip_runtime.h>
#include <math.h>

#define BB 256
#define LL 20
#define HH 128
#define NH 8
#define D2C 64
#define NTY 4
#define NRL 4
#define CHILDN 30001
#define PARENTN 500
#define N1SN 50000
#define N1DN 20000
#define E1N 300000
#define N2N 20000
#define E2N 200000
#define TT (BB*LL)
#define N4DN 5000
#define E4N 150000
#define EC2PN 8000
#define GT2 64   // nodes per GEMM tile

__device__ __forceinline__ unsigned fenc(float f){ unsigned u=__float_as_uint(f); return (u&0x80000000u)? ~u : (u|0x80000000u); }
__device__ __forceinline__ float fdec(unsigned u){ return (u&0x80000000u)? __uint_as_float(u^0x80000000u) : __uint_as_float(~u); }
__device__ __forceinline__ float sigf(float x){ return 1.f/(1.f+expf(-x)); }

// ---------------- Stage A: feature expansion ----------------
__global__ void k_featx(const int* seq, const int* dur, const int* stime, const int* etime,
                        const float* emb, const float* dia_w, const float* dia_b,
                        const float* t2v_w, const float* t2v_b,
                        const float* exp_W, const float* exp_b, float* xout){
  int bl = blockIdx.x; int o = threadIdx.x;
  __shared__ float feat[272];
  int node = seq[bl];
  float ts = (float)stime[bl], te = (float)etime[bl], td = (float)dur[bl];
  float e0 = emb[node*HH+o];
  float st, et;
  if(o < D2C){ st = e0; et = e0; }
  else {
    float w = dia_w[node*HH+o], b = dia_b[node*HH+o];
    st = e0 * sinf(w*ts + b);
    et = e0 * sinf(w*te + b);
  }
  feat[o] = st; feat[HH+o] = et;
  if(o < 16){
    float w = t2v_w[o], b = t2v_b[o];
    feat[256+o] = (o==0) ? (w*td + b) : sinf(w*td + b);
  }
  __syncthreads();
  float acc = exp_b[o];
  for(int j=0;j<272;j++) acc += feat[j]*exp_W[j*HH+o];
  xout[bl*HH+o] = fmaxf(acc, 0.f);
}

// tiled x @ Wi + b -> gpre: 16 rows x 512 cols per block
__global__ void k_xwi2(const float* x, const float* Wi, const float* bias, float* gpre, int rows){
  int base = blockIdx.x*16;
  __shared__ float xs[128*17];
  int tid = threadIdx.x;
  #pragma unroll
  for(int s=0;s<8;s++){
    int elem = tid + 256*s;
    int k = elem & 127, j = elem >> 7;
    int r = base + j;
    xs[k*17 + j] = (r < rows) ? x[(size_t)r*HH + k] : 0.f;
  }
  __syncthreads();
  int o4 = (tid & 127)*4;
  int ng = tid >> 7;
  float4 a[8];
  #pragma unroll
  for(int j=0;j<8;j++) a[j]=make_float4(0,0,0,0);
  for(int k=0;k<HH;k++){
    float4 w = *(const float4*)(Wi + (size_t)k*512 + o4);
    const float* xr = xs + k*17 + ng*8;
    #pragma unroll
    for(int j=0;j<8;j++){
      float xv = xr[j];
      a[j].x += xv*w.x; a[j].y += xv*w.y; a[j].z += xv*w.z; a[j].w += xv*w.w;
    }
  }
  float4 bv = *(const float4*)(bias + o4);
  #pragma unroll
  for(int j=0;j<8;j++){
    int r = base + ng*8 + j;
    if(r < rows){
      float4 v = a[j];
      v.x += bv.x; v.y += bv.y; v.z += bv.z; v.w += bv.w;
      *(float4*)(gpre + (size_t)r*512 + o4) = v;
    }
  }
}

__global__ void k_zero_state(float* h, float* c){
  int i = blockIdx.x*256 + threadIdx.x;
  if(i < BB*HH){ h[i]=0.f; c[i]=0.f; }
}

// one LSTM time step; 4 accumulators break the 128-deep dependent FMA chain
// (no fast-math -> compiler can't reassociate; manual ILP 4x)
__global__ void k_lstm_step(const float* gpre, const float* Wh, float* hstate, float* cstate,
                            float* hout, float* hout2, int l){
  int b = blockIdx.x; int o = threadIdx.x;
  __shared__ float hs[HH];
  __shared__ float gs[512];
  if(o < HH) hs[o] = hstate[b*HH+o];
  __syncthreads();
  float a0=0.f, a1=0.f, a2=0.f, a3=0.f;
  #pragma unroll 8
  for(int h=0;h<HH;h+=4){
    a0 += hs[h  ]*Wh[(h  )*512+o];
    a1 += hs[h+1]*Wh[(h+1)*512+o];
    a2 += hs[h+2]*Wh[(h+2)*512+o];
    a3 += hs[h+3]*Wh[(h+3)*512+o];
  }
  gs[o] = gpre[((size_t)b*LL+l)*512+o] + ((a0+a1)+(a2+a3));
  __syncthreads();
  if(o < HH){
    float ig = sigf(gs[o]);
    float fg = sigf(gs[HH+o]);
    float gg = tanhf(gs[2*HH+o]);
    float og = sigf(gs[3*HH+o]);
    float c = fg*cstate[b*HH+o] + ig*gg;
    float h = og*tanhf(c);
    cstate[b*HH+o] = c; hstate[b*HH+o] = h;
    hout[((size_t)b*LL+l)*HH+o] = h;
    if(hout2) hout2[((size_t)b*LL+l)*HH+o] = h;
  }
}

__global__ void k_tok(const int* seq, const int* seq_nt, int* tokid, int* toknt){
  int t = blockIdx.x*blockDim.x + threadIdx.x;
  if(t >= TT) return;
  int b = t % BB, l = t / BB;
  tokid[t] = seq[b*LL+l];
  toknt[t] = seq_nt[b*LL+l];
}

// ---------------- conv prep ----------------
__global__ void k_gather_emb(const int* nid, const float* emb, float* dst){
  int i = blockIdx.x; int o = threadIdx.x;
  dst[i*HH+o] = emb[nid[i]*HH+o];
}

__global__ void k_prep2(const int* sel, const float* xg, const int* g1_nid, const int* g1_nt,
                        float* srcbuf, int* gnid2, int* tsrc2){
  int i = blockIdx.x; int o = threadIdx.x;
  int s = sel[i];
  srcbuf[i*HH+o] = xg[s*HH+o];
  if(o==0){ gnid2[i] = g1_nid[s]; tsrc2[i] = g1_nt[s]; }
}

__global__ void k_dst2(const int* tok_sel, const float* xg, const float* h1, float* dst2){
  int t = blockIdx.x; int o = threadIdx.x;
  int b = t % BB, l = t / BB;
  dst2[t*HH+o] = xg[tok_sel[t]*HH+o] + h1[(b*LL+l)*HH+o];
}

__global__ void k_x0(const int* nid, const int* ntype, const float* emb, const float* hist2,
                     const float* skip, float* srcbuf){
  int i = blockIdx.x; int o = threadIdx.x;
  float a = sigf(skip[ntype[i]]);
  int nd = nid[i];
  srcbuf[i*HH+o] = emb[nd*HH+o]*a + hist2[nd*HH+o]*(1.f-a);
}

// LN + time-mod -> hsbuf; grid = nsrc, 128 threads
__global__ void k_ln_mod(const float* src_h, const int* src_nid,
                         const float* dia_w, const float* dia_b, float* hsbuf){
  int i = blockIdx.x; int o = threadIdx.x;
  __shared__ float red[HH];
  float v = src_h[i*HH+o];
  red[o] = v; __syncthreads();
  for(int s=64;s>0;s>>=1){ if(o<s) red[o]+=red[o+s]; __syncthreads(); }
  float mean = red[0]/(float)HH;
  __syncthreads();
  red[o] = v*v; __syncthreads();
  for(int s=64;s>0;s>>=1){ if(o<s) red[o]+=red[o+s]; __syncthreads(); }
  float var = red[0]/(float)HH - mean*mean;
  float h = (v-mean)*(1.f/sqrtf(fmaxf(var,0.f)+1e-5f));
  if(o >= D2C){
    int nd = src_nid[i];
    h *= sinf(dia_w[nd*HH+o] + dia_b[nd*HH+o]);
  }
  hsbuf[(size_t)i*HH+o] = h;
}

// plain LN (no time-mod) -> out; grid = n, 128 threads
__global__ void k_ln(const float* src_h, float* out){
  int i = blockIdx.x; int o = threadIdx.x;
  __shared__ float red[HH];
  float v = src_h[i*HH+o];
  red[o] = v; __syncthreads();
  for(int s=64;s>0;s>>=1){ if(o<s) red[o]+=red[o+s]; __syncthreads(); }
  float mean = red[0]/(float)HH;
  __syncthreads();
  red[o] = v*v; __syncthreads();
  for(int s=64;s>0;s>>=1){ if(o<s) red[o]+=red[o+s]; __syncthreads(); }
  float var = red[0]/(float)HH - mean*mean;
  out[(size_t)i*HH+o] = (v-mean)*(1.f/sqrtf(fmaxf(var,0.f)+1e-5f));
}

__global__ void k_zero_cnt2(int* a, int* b){
  if(threadIdx.x < NTY){ a[threadIdx.x] = 0; b[threadIdx.x] = 0; }
}

// block-aggregated type scatter
__global__ void k_scatter_type(const int* types, int n, int* cnts, int* idxb, int stride){
  __shared__ int hist[NTY];
  __shared__ int base[NTY];
  int i = blockIdx.x*256 + threadIdx.x;
  if(threadIdx.x < NTY) hist[threadIdx.x] = 0;
  __syncthreads();
  int t = 0, r = 0;
  bool act = (i < n);
  if(act){ t = types[i]; r = atomicAdd(&hist[t], 1); }
  __syncthreads();
  if(threadIdx.x < NTY && hist[threadIdx.x] > 0)
    base[threadIdx.x] = atomicAdd(&cnts[threadIdx.x], hist[threadIdx.x]);
  __syncthreads();
  if(act) idxb[t*stride + base[t] + r] = i;
}

// ---- tiled type-grouped GEMM: K,V -> interleaved KVbuf row [K(128)|V(128)]
// so the attention kernel fetches one contiguous 1KB row per edge.
__global__ void k_gemm_kv2(const float* X, const int* idxb, const int* cnts, int stride,
                           const float* KW, const float* VW, float* KVbuf){
  int t = blockIdx.y;
  int cnt = cnts[t];
  int base = blockIdx.x * GT2;
  if(base >= cnt || cnt == 0) return;
  int nn = min(GT2, cnt - base);
  const int* ids = idxb + t*stride + base;
  __shared__ float xs[128*65];
  __shared__ int sid[GT2];
  int tid = threadIdx.x;
  if(tid < GT2) sid[tid] = (tid < nn) ? ids[tid] : ids[0];
  __syncthreads();
  #pragma unroll
  for(int s=0;s<32;s++){
    int elem = tid + 256*s;
    int k = elem & 127, j = elem >> 7;
    xs[k*65 + j] = X[(size_t)sid[j]*HH + k];
  }
  __syncthreads();
  const float* kw = KW + (size_t)t*HH*HH;
  const float* vw = VW + (size_t)t*HH*HH;
  int o4 = (tid & 31)*4;
  int ng = tid >> 5;
  float4 ak[8], av[8];
  #pragma unroll
  for(int j=0;j<8;j++){ ak[j]=make_float4(0,0,0,0); av[j]=make_float4(0,0,0,0); }
  for(int k=0;k<HH;k++){
    float4 wk = *(const float4*)(kw + k*HH + o4);
    float4 wv = *(const float4*)(vw + k*HH + o4);
    const float* xr = xs + k*65 + ng*8;
    #pragma unroll
    for(int j=0;j<8;j++){
      float x = xr[j];
      ak[j].x += x*wk.x; ak[j].y += x*wk.y; ak[j].z += x*wk.z; ak[j].w += x*wk.w;
      av[j].x += x*wv.x; av[j].y += x*wv.y; av[j].z += x*wv.z; av[j].w += x*wv.w;
    }
  }
  #pragma unroll
  for(int j=0;j<8;j++){
    int n = ng*8+j;
    if(n < nn){
      size_t r = (size_t)sid[n]*256 + o4;
      *(float4*)(KVbuf + r) = ak[j];
      *(float4*)(KVbuf + r + 128) = av[j];
    }
  }
}

// single-output GEMM; resid!=null -> Y = acc + resid (+relu); Y2 optional copy
__global__ void k_gemm_t1(const float* X, const int* idxb, const int* cnts, int stride,
                          const float* W, const float* resid, float* Y, float* Y2, int relu){
  int t = blockIdx.y;
  int cnt = cnts[t];
  int base = blockIdx.x * GT2;
  if(base >= cnt || cnt == 0) return;
  int nn = min(GT2, cnt - base);
  const int* ids = idxb + t*stride + base;
  __shared__ float xs[128*65];
  __shared__ int sid[GT2];
  int tid = threadIdx.x;
  if(tid < GT2) sid[tid] = (tid < nn) ? ids[tid] : ids[0];
  __syncthreads();
  #pragma unroll
  for(int s=0;s<32;s++){
    int elem = tid + 256*s;
    int k = elem & 127, j = elem >> 7;
    xs[k*65 + j] = X[(size_t)sid[j]*HH + k];
  }
  __syncthreads();
  const float* w = W + (size_t)t*HH*HH;
  int o4 = (tid & 31)*4;
  int ng = tid >> 5;
  float4 a[8];
  #pragma unroll
  for(int j=0;j<8;j++) a[j]=make_float4(0,0,0,0);
  for(int k=0;k<HH;k++){
    float4 wk = *(const float4*)(w + k*HH + o4);
    const float* xr = xs + k*65 + ng*8;
    #pragma unroll
    for(int j=0;j<8;j++){
      float x = xr[j];
      a[j].x += x*wk.x; a[j].y += x*wk.y; a[j].z += x*wk.z; a[j].w += x*wk.w;
    }
  }
  #pragma unroll
  for(int j=0;j<8;j++){
    int n = ng*8+j;
    if(n < nn){
      size_t r = (size_t)sid[n]*HH + o4;
      float4 v = a[j];
      if(resid){
        float4 rs = *(const float4*)(resid + r);
        v.x += rs.x; v.y += rs.y; v.z += rs.z; v.w += rs.w;
        if(relu){ v.x=fmaxf(v.x,0.f); v.y=fmaxf(v.y,0.f); v.z=fmaxf(v.z,0.f); v.w=fmaxf(v.w,0.f); }
      }
      *(float4*)(Y + r) = v;
      if(Y2) *(float4*)(Y2 + r) = v;
    }
  }
}

// EW2[50][128] = edge_emb @ EW (per conv layer)
__global__ void k_edge_tab(const float* edge_emb, const float* EWp, float* EW2){
  int r = blockIdx.x; int o = threadIdx.x;
  float acc = 0.f;
  for(int j=0;j<32;j++) acc += edge_emb[r*32+j]*EWp[j*HH+o];
  EW2[r*HH+o] = acc;
}

// ---------------- CSR build (per graph) ----------------
__global__ void k_zero_int(int* p, int n){
  int i = blockIdx.x*256 + threadIdx.x;
  if(i < n) p[i] = 0;
}
__global__ void k_hist_dst(const int* edst, int E, int* cnt){
  int e = blockIdx.x*256 + threadIdx.x;
  if(e < E) atomicAdd(&cnt[edst[e]], 1);
}
__global__ void k_scan(const int* cnt, int n, int* row_ptr, int* cursor){
  __shared__ int tsum[1024];
  int tid = threadIdx.x;
  int per = (n + 1023) / 1024;
  int start = tid*per; int end = min(start+per, n);
  int s = 0;
  for(int i=start;i<end;i++) s += cnt[i];
  tsum[tid] = s; __syncthreads();
  for(int off=1;off<1024;off<<=1){
    int v = (tid>=off) ? tsum[tid-off] : 0;
    __syncthreads();
    tsum[tid] += v;
    __syncthreads();
  }
  int run = (tid==0) ? 0 : tsum[tid-1];
  for(int i=start;i<end;i++){ row_ptr[i]=run; cursor[i]=run; run += cnt[i]; }
  if(end == n) row_ptr[n] = run;
}
__global__ void k_fill_csr(const int* edst, int E, int* cursor, int* eid){
  int e = blockIdx.x*256 + threadIdx.x;
  if(e >= E) return;
  int pos = atomicAdd(&cursor[edst[e]], 1);
  eid[pos] = e;
}
__global__ void k_permute_edges(const int* eid, const int* esrc, const int* ew, const int* ety,
                                int E, int* esrc_s, int* ew_s, int* ety_s){
  int r = blockIdx.x*256 + threadIdx.x;
  if(r >= E) return;
  int e = eid[r];
  esrc_s[r] = esrc[e]; ew_s[r] = ew[e]; ety_s[r] = ety[e];
}

// single-pass online-softmax attention: one loop over the dst's edges,
// K+V fetched together from the interleaved KV row (1KB contiguous/edge).
// No Sbuf, no second/third pass. flash-attention recurrence per head.
__global__ void k_attn_fused2(const int* row_ptr, const int* esrc_s, const int* ew_s, const int* ety_s,
                              const float* KVbuf, const float* Qbuf,
                              const float* EW2, const float* mu, float* Abuf){
  int d = blockIdx.x; int o = threadIdx.x;
  int r0 = row_ptr[d], r1 = row_ptr[d+1];
  __shared__ float q[HH];
  q[o] = Qbuf[(size_t)d*HH+o];
  __syncthreads();
  int h = o >> 4;
  float qo = q[o];
  float m = -3.0e38f, dd = 0.f, acc = 0.f;
  for(int r=r0; r<r1; r++){
    int src = esrc_s[r], w = ew_s[r];
    const float* kv = KVbuf + (size_t)src*256;
    float kx = kv[o];
    float vx = kv[128+o];
    float p = qo*(kx + EW2[w*HH+o]);
    p += __shfl_xor(p, 1, 64);
    p += __shfl_xor(p, 2, 64);
    p += __shfl_xor(p, 4, 64);
    p += __shfl_xor(p, 8, 64);
    float s = p * mu[ety_s[r]*NH+h] * 0.25f;
    float mn = fmaxf(m, s);
    float scale = expf(m - mn);
    float e = expf(s - mn);
    dd  = dd*scale + e;
    acc = acc*scale + e*vx;
    m = mn;
  }
  Abuf[(size_t)d*HH + o] = acc / fmaxf(dd, 1e-9f);
}

// ---------------- stage D: token pooling ----------------
__global__ void k_seq2(const float* x2, float* xout){
  int bl = blockIdx.x; int o = threadIdx.x;
  int b = bl / LL, l = bl % LL;
  xout[bl*HH+o] = x2[(l*BB+b)*HH+o];
}

__global__ void k_zero_hist(float* hist2, float* cnt, unsigned* amax, float* aden){
  int i = blockIdx.x*blockDim.x + threadIdx.x;
  if(i < CHILDN*HH) hist2[i] = 0.f;
  if(i < CHILDN){ cnt[i] = 0.f; aden[i] = 0.f; amax[i] = 0x007FFFFFu; }
}

__global__ void k_tokatt(const float* h2f, const int* toknt, const float* ipW, const float* iaW,
                         float* abuf, unsigned* amax, const int* tokid){
  int t = blockIdx.x; int o = threadIdx.x;
  __shared__ float es[HH];
  __shared__ float red[HH];
  int b = t % BB, l = t / BB;
  es[o] = h2f[(b*LL+l)*HH+o];
  __syncthreads();
  int nt = toknt[t];
  const float* w = ipW + (size_t)nt*HH*HH;
  float acc = 0.f;
  for(int j=0;j<HH;j++) acc += es[j]*w[j*HH+o];
  float u = tanhf(acc);
  red[o] = u * iaW[nt*HH+o];
  __syncthreads();
  for(int s=64;s>0;s>>=1){ if(o<s) red[o]+=red[o+s]; __syncthreads(); }
  if(o==0){
    float a = red[0];
    abuf[t] = a;
    atomicMax(&amax[tokid[t]], fenc(a));
  }
}

__global__ void k_tokexp(const int* tokid, float* abuf, const unsigned* amax, float* aden, float* cnt){
  int t = blockIdx.x*blockDim.x + threadIdx.x;
  if(t >= TT) return;
  int c = tokid[t];
  float ex = expf(abuf[t]-fdec(amax[c]));
  abuf[t] = ex;
  atomicAdd(&aden[c], ex);
  atomicAdd(&cnt[c], 1.f);
}

__global__ void k_tokagg(const int* tokid, const float* abuf, const float* aden,
                         const float* h2f, float* hist2){
  int t = blockIdx.x; int o = threadIdx.x;
  int c = tokid[t];
  float w = abuf[t]/fmaxf(aden[c],1e-9f);
  int b = t % BB, l = t / BB;
  atomicAdd(&hist2[c*HH+o], w*h2f[(b*LL+l)*HH+o]);
}

__global__ void k_histfix(const float* cnt, const float* hist_emb, float* hist2){
  int c = blockIdx.x; int o = threadIdx.x;
  if(cnt[c] == 0.f) hist2[c*HH+o] = hist_emb[c*HH+o];
}

// ---------------- parent pooling ----------------
__global__ void k_zero_parent(float* psum, float* pcnt){
  int i = blockIdx.x*blockDim.x + threadIdx.x;
  if(i < PARENTN*HH) psum[i] = 0.f;
  if(i < PARENTN) pcnt[i] = 0.f;
}

__global__ void k_peagg(const int* pe_p, const int* pe_c, const float* cef, float* psum, float* pcnt){
  int i = blockIdx.x; int o = threadIdx.x;
  int p = pe_p[i], c = pe_c[i];
  atomicAdd(&psum[p*HH+o], cef[c*HH+o]);
  if(o==0) atomicAdd(&pcnt[p], 1.f);
}

__global__ void k_parent(const float* psum, const float* pcnt, float* out){
  int i = blockIdx.x; int o = threadIdx.x;
  out[i*HH+o] = psum[i*HH+o]/fmaxf(pcnt[i],1.f);
}

extern "C" void kernel_launch(void* const* d_in, const int* in_sizes, int n_in,
                              void* d_out, int out_size, void* d_ws, size_t ws_size,
                              hipStream_t stream){
  const int* seq     = (const int*)d_in[0];
  const int* seq_nt  = (const int*)d_in[1];
  const int* dur     = (const int*)d_in[2];
  const int* stime   = (const int*)d_in[3];
  const int* etime   = (const int*)d_in[4];
  const int* g1_nid  = (const int*)d_in[5];
  const int* g1_nt   = (const int*)d_in[6];
  const int* g1_esrc = (const int*)d_in[7];
  const int* g1_edst = (const int*)d_in[8];
  const int* g1_ety  = (const int*)d_in[9];
  const int* g1_ew   = (const int*)d_in[10];
  const int* g2_sel  = (const int*)d_in[11];
  const int* g2_esrc = (const int*)d_in[12];
  const int* g2_edst = (const int*)d_in[13];
  const int* g2_ety  = (const int*)d_in[14];
  const int* g2_ew   = (const int*)d_in[15];
  const int* tok_sel = (const int*)d_in[16];
  const int* g4_esrc = (const int*)d_in[17];
  const int* g4_edst = (const int*)d_in[18];
  const int* g4_ety  = (const int*)d_in[19];
  const int* g4_ew   = (const int*)d_in[20];
  const int* pe_p    = (const int*)d_in[21];
  const int* pe_c    = (const int*)d_in[22];
  const float* emb     = (const float*)d_in[23];
  const float* hist_emb= (const float*)d_in[24];
  const float* edge_emb= (const float*)d_in[25];
  const float* dia_w   = (const float*)d_in[26];
  const float* dia_b   = (const float*)d_in[27];
  const float* t2v_w   = (const float*)d_in[28];
  const float* t2v_b   = (const float*)d_in[29];
  const float* exp_W   = (const float*)d_in[30];
  const float* exp_b   = (const float*)d_in[31];
  const float* l1Wi    = (const float*)d_in[32];
  const float* l1Wh    = (const float*)d_in[33];
  const float* l1b     = (const float*)d_in[34];
  const float* l2Wi    = (const float*)d_in[35];
  const float* l2Wh    = (const float*)d_in[36];
  const float* l2b     = (const float*)d_in[37];
  const float* convK   = (const float*)d_in[38];
  const float* convQ   = (const float*)d_in[39];
  const float* convV   = (const float*)d_in[40];
  const float* convO   = (const float*)d_in[41];
  const float* convE   = (const float*)d_in[42];
  const float* convMu  = (const float*)d_in[43];
  const float* ipW     = (const float*)d_in[44];
  const float* iaW     = (const float*)d_in[45];
  const float* skip    = (const float*)d_in[46];
  float* outp = (float*)d_out;

  // workspace arena
  char* wsp = (char*)d_ws;
  size_t off = 0;
  auto A = [&](size_t nbytes)->char*{ char* p = wsp+off; off += (nbytes+255)&~(size_t)255; return p; };
  float*    srcbuf = (float*)   A((size_t)N1SN*HH*4);
  float*    KVbuf  = (float*)   A((size_t)N1SN*256*4);   // interleaved [K|V]
  float*    Qbuf   = (float*)   A((size_t)N1DN*HH*4);
  float*    Abuf   = (float*)   A((size_t)N1DN*HH*4);
  float*    lnq    = (float*)   A((size_t)N1DN*HH*4);
  float*    xbuf   = (float*)   A((size_t)TT*HH*4);
  float*    gpre   = (float*)   A((size_t)TT*512*4);
  float*    h1     = (float*)   A((size_t)TT*HH*4);
  float*    dst2   = (float*)   A((size_t)TT*HH*4);
  float*    xg     = (float*)   A((size_t)N1DN*HH*4);
  float*    x2     = (float*)   A((size_t)TT*HH*4);
  float*    h2f    = (float*)   A((size_t)TT*HH*4);
  // hsbuf aliases hist2 (disjoint lifetimes on the serial stream)
  float*    hsbuf  = (float*)   A((size_t)N1SN*HH*4);
  float*    hist2  = hsbuf;
  float*    cnt    = (float*)   A((size_t)CHILDN*4);
  float*    abuf   = (float*)   A((size_t)TT*4);
  unsigned* amax   = (unsigned*)A((size_t)CHILDN*4);
  float*    aden   = (float*)   A((size_t)CHILDN*4);
  float*    x3     = (float*)   A((size_t)N1DN*HH*4);
  float*    cef    = (float*)   A((size_t)N4DN*HH*4);
  float*    psum   = (float*)   A((size_t)PARENTN*HH*4);
  float*    pcnt   = (float*)   A((size_t)PARENTN*4);
  int*      tokid  = (int*)     A((size_t)TT*4);
  int*      toknt  = (int*)     A((size_t)TT*4);
  int*      gnid2  = (int*)     A((size_t)N2N*4);
  int*      tsrc2  = (int*)     A((size_t)N2N*4);
  int*      idxb   = (int*)     A((size_t)NTY*N1SN*4);
  int*      idxb2  = (int*)     A((size_t)NTY*N1DN*4);
  int*      cnts   = (int*)     A((size_t)NTY*4);
  int*      cnts2  = (int*)     A((size_t)NTY*4);
  float*    EW2    = (float*)   A((size_t)50*HH*4);
  float*    hstate = (float*)   A((size_t)BB*HH*4);
  float*    cstate = (float*)   A((size_t)BB*HH*4);
  // CSR structures + CSR-ordered edge attributes
  int*      g1row  = (int*)     A((size_t)(N1DN+1)*4);
  int*      g1eid  = (int*)     A((size_t)E1N*4);
  int*      g1src_s= (int*)     A((size_t)E1N*4);
  int*      g1ew_s = (int*)     A((size_t)E1N*4);
  int*      g1ety_s= (int*)     A((size_t)E1N*4);
  int*      g2row  = (int*)     A((size_t)(TT+1)*4);
  int*      g2eid  = (int*)     A((size_t)E2N*4);
  int*      g2src_s= (int*)     A((size_t)E2N*4);
  int*      g2ew_s = (int*)     A((size_t)E2N*4);
  int*      g2ety_s= (int*)     A((size_t)E2N*4);
  int*      g4row  = (int*)     A((size_t)(N4DN+1)*4);
  int*      g4eid  = (int*)     A((size_t)E4N*4);
  int*      g4src_s= (int*)     A((size_t)E4N*4);
  int*      g4ew_s = (int*)     A((size_t)E4N*4);
  int*      g4ety_s= (int*)     A((size_t)E4N*4);
  int*      icnt   = (int*)     A((size_t)(N1DN+1)*4);
  int*      icur   = (int*)     A((size_t)(N1DN+1)*4);
  if(off > ws_size) return;  // insufficient scratch: output stays zero

  auto build_csr = [&](const int* edst, const int* esrc, const int* ew, const int* ety,
                       int E, int ndst, int* rowp, int* eid, int* src_s, int* ew_s, int* ety_s){
    k_zero_int<<<(ndst+255)/256, 256, 0, stream>>>(icnt, ndst);
    k_hist_dst<<<(E+255)/256, 256, 0, stream>>>(edst, E, icnt);
    k_scan<<<1, 1024, 0, stream>>>(icnt, ndst, rowp, icur);
    k_fill_csr<<<(E+255)/256, 256, 0, stream>>>(edst, E, icur, eid);
    k_permute_edges<<<(E+255)/256, 256, 0, stream>>>(eid, esrc, ew, ety, E, src_s, ew_s, ety_s);
  };

  auto run_conv = [&](const float* src_h, const int* src_nid, const int* src_t, int nsrc,
                      const float* dst_h, const int* dst_t, int ndst,
                      const int* rowp, const int* src_s, const int* ew_s, const int* ety_s,
                      int layer, float* outbuf, float* out2, int relu){
    const float* KW  = convK  + (size_t)layer*NTY*HH*HH;
    const float* QW  = convQ  + (size_t)layer*NTY*HH*HH;
    const float* VW  = convV  + (size_t)layer*NTY*HH*HH;
    const float* OW  = convO  + (size_t)layer*NTY*HH*HH;
    const float* EWp = convE  + (size_t)layer*32*HH;
    const float* MU  = convMu + (size_t)layer*NRL*NH;
    k_ln_mod<<<nsrc, HH, 0, stream>>>(src_h, src_nid, dia_w, dia_b, hsbuf);
    k_ln<<<ndst, HH, 0, stream>>>(dst_h, lnq);
    k_zero_cnt2<<<1, 64, 0, stream>>>(cnts, cnts2);
    k_scatter_type<<<(nsrc+255)/256, 256, 0, stream>>>(src_t, nsrc, cnts, idxb, N1SN);
    k_scatter_type<<<(ndst+255)/256, 256, 0, stream>>>(dst_t, ndst, cnts2, idxb2, N1DN);
    dim3 gkv((nsrc+GT2-1)/GT2, NTY);
    k_gemm_kv2<<<gkv, 256, 0, stream>>>(hsbuf, idxb, cnts, N1SN, KW, VW, KVbuf);
    dim3 gq((ndst+GT2-1)/GT2, NTY);
    k_gemm_t1<<<gq, 256, 0, stream>>>(lnq, idxb2, cnts2, N1DN, QW, (const float*)nullptr, Qbuf, (float*)nullptr, 0);
    k_edge_tab<<<50, HH, 0, stream>>>(edge_emb, EWp, EW2);
    k_attn_fused2<<<ndst, HH, 0, stream>>>(rowp, src_s, ew_s, ety_s, KVbuf, Qbuf, EW2, MU, Abuf);
    k_gemm_t1<<<gq, 256, 0, stream>>>(Abuf, idxb2, cnts2, N1DN, OW, dst_h, outbuf, out2, relu);
  };

  // ---- stage A: features + LSTM1 ----
  k_featx<<<TT, HH, 0, stream>>>(seq, dur, stime, etime, emb, dia_w, dia_b, t2v_w, t2v_b, exp_W, exp_b, xbuf);
  k_xwi2<<<(TT+15)/16, 256, 0, stream>>>(xbuf, l1Wi, l1b, gpre, TT);
  k_zero_state<<<(BB*HH+255)/256, 256, 0, stream>>>(hstate, cstate);
  for(int l=0;l<LL;l++)
    k_lstm_step<<<BB, 512, 0, stream>>>(gpre, l1Wh, hstate, cstate, h1, (float*)nullptr, l);
  k_tok<<<(TT+255)/256, 256, 0, stream>>>(seq, seq_nt, tokid, toknt);

  // ---- CSR for g1 (reused by conv1 and conv3) ----
  build_csr(g1_edst, g1_esrc, g1_ew, g1_ety, E1N, N1DN, g1row, g1eid, g1src_s, g1ew_s, g1ety_s);

  // ---- conv1 on g1 ----
  k_gather_emb<<<N1SN, HH, 0, stream>>>(g1_nid, emb, srcbuf);
  run_conv(srcbuf, g1_nid, g1_nt, N1SN, srcbuf, g1_nt, N1DN,
           g1row, g1src_s, g1ew_s, g1ety_s, 0, xg, (float*)nullptr, 1);

  // ---- conv2 on g2 ----
  build_csr(g2_edst, g2_esrc, g2_ew, g2_ety, E2N, TT, g2row, g2eid, g2src_s, g2ew_s, g2ety_s);
  k_prep2<<<N2N, HH, 0, stream>>>(g2_sel, xg, g1_nid, g1_nt, srcbuf, gnid2, tsrc2);
  k_dst2<<<TT, HH, 0, stream>>>(tok_sel, xg, h1, dst2);
  run_conv(srcbuf, gnid2, tsrc2, N2N, dst2, toknt, TT,
           g2row, g2src_s, g2ew_s, g2ety_s, 1, x2, (float*)nullptr, 1);

  // ---- LSTM2 (h2 is output 0) ----
  k_seq2<<<TT, HH, 0, stream>>>(x2, xbuf);
  k_xwi2<<<(TT+15)/16, 256, 0, stream>>>(xbuf, l2Wi, l2b, gpre, TT);
  k_zero_state<<<(BB*HH+255)/256, 256, 0, stream>>>(hstate, cstate);
  for(int l=0;l<LL;l++)
    k_lstm_step<<<BB, 512, 0, stream>>>(gpre, l2Wh, hstate, cstate, h2f, outp, l);

  // ---- stage D: token attention pooling -> hist2 ----
  k_zero_hist<<<(CHILDN*HH+255)/256, 256, 0, stream>>>(hist2, cnt, amax, aden);
  k_tokatt<<<TT, HH, 0, stream>>>(h2f, toknt, ipW, iaW, abuf, amax, tokid);
  k_tokexp<<<(TT+255)/256, 256, 0, stream>>>(tokid, abuf, amax, aden, cnt);
  k_tokagg<<<TT, HH, 0, stream>>>(tokid, abuf, aden, h2f, hist2);
  k_histfix<<<CHILDN, HH, 0, stream>>>(cnt, hist_emb, hist2);

  // ---- conv3 on g1 with skip-mixed input (g1 CSR reused) ----
  k_x0<<<N1SN, HH, 0, stream>>>(g1_nid, g1_nt, emb, hist2, skip, srcbuf);
  run_conv(srcbuf, g1_nid, g1_nt, N1SN, srcbuf, g1_nt, N1DN,
           g1row, g1src_s, g1ew_s, g1ety_s, 2, x3, (float*)nullptr, 1);

  // ---- conv4 on g4 (child_embed = output 1, no relu) ----
  build_csr(g4_edst, g4_esrc, g4_ew, g4_ety, E4N, N4DN, g4row, g4eid, g4src_s, g4ew_s, g4ety_s);
  run_conv(x3, g1_nid, g1_nt, N1DN, x3, g1_nt, N4DN,
           g4row, g4src_s, g4ew_s, g4ety_s, 3, cef, outp + (size_t)TT*HH, 0);

  // ---- parent pooling (output 2) ----
  k_zero_parent<<<(PARENTN*HH+255)/256, 256, 0, stream>>>(psum, pcnt);
  k_peagg<<<EC2PN, HH, 0, stream>>>(pe_p, pe_c, cef, psum, pcnt);
  k_parent<<<PARENTN, HH, 0, stream>>>(psum, pcnt, outp + (size_t)TT*HH + (size_t)N4DN*HH);
}

// Round 9
// 1395.167 us; speedup vs baseline: 2.0834x; 1.1483x over previous
//
#include <hip/hip_runtime.h>
#include <math.h>

#define BB 256
#define LL 20
#define HH 128
#define NH 8
#define D2C 64
#define NTY 4
#define NRL 4
#define CHILDN 30001
#define PARENTN 500
#define N1SN 50000
#define N1DN 20000
#define E1N 300000
#define N2N 20000
#define E2N 200000
#define TT (BB*LL)
#define N4DN 5000
#define E4N 150000
#define EC2PN 8000
#define GT2 64   // nodes per GEMM tile
#define ST 68    // LDS row stride (68*4=272 B, 16B-aligned rows -> ds_read_b128)

__device__ __forceinline__ unsigned fenc(float f){ unsigned u=__float_as_uint(f); return (u&0x80000000u)? ~u : (u|0x80000000u); }
__device__ __forceinline__ float fdec(unsigned u){ return (u&0x80000000u)? __uint_as_float(u^0x80000000u) : __uint_as_float(~u); }
__device__ __forceinline__ float sigf(float x){ return 1.f/(1.f+expf(-x)); }

// ---------------- Stage A: feature expansion ----------------
__global__ void k_featx(const int* seq, const int* dur, const int* stime, const int* etime,
                        const float* emb, const float* dia_w, const float* dia_b,
                        const float* t2v_w, const float* t2v_b,
                        const float* exp_W, const float* exp_b, float* xout){
  int bl = blockIdx.x; int o = threadIdx.x;
  __shared__ float feat[272];
  int node = seq[bl];
  float ts = (float)stime[bl], te = (float)etime[bl], td = (float)dur[bl];
  float e0 = emb[node*HH+o];
  float st, et;
  if(o < D2C){ st = e0; et = e0; }
  else {
    float w = dia_w[node*HH+o], b = dia_b[node*HH+o];
    st = e0 * sinf(w*ts + b);
    et = e0 * sinf(w*te + b);
  }
  feat[o] = st; feat[HH+o] = et;
  if(o < 16){
    float w = t2v_w[o], b = t2v_b[o];
    feat[256+o] = (o==0) ? (w*td + b) : sinf(w*td + b);
  }
  __syncthreads();
  float acc = exp_b[o];
  for(int j=0;j<272;j++) acc += feat[j]*exp_W[j*HH+o];
  xout[bl*HH+o] = fmaxf(acc, 0.f);
}

// tiled x @ Wi + b -> gpre: 16 rows x 512 cols per block
__global__ void k_xwi2(const float* x, const float* Wi, const float* bias, float* gpre, int rows){
  int base = blockIdx.x*16;
  __shared__ float xs[128*17];
  int tid = threadIdx.x;
  #pragma unroll
  for(int s=0;s<8;s++){
    int elem = tid + 256*s;
    int k = elem & 127, j = elem >> 7;
    int r = base + j;
    xs[k*17 + j] = (r < rows) ? x[(size_t)r*HH + k] : 0.f;
  }
  __syncthreads();
  int o4 = (tid & 127)*4;
  int ng = tid >> 7;
  float4 a[8];
  #pragma unroll
  for(int j=0;j<8;j++) a[j]=make_float4(0,0,0,0);
  for(int k=0;k<HH;k++){
    float4 w = *(const float4*)(Wi + (size_t)k*512 + o4);
    const float* xr = xs + k*17 + ng*8;
    #pragma unroll
    for(int j=0;j<8;j++){
      float xv = xr[j];
      a[j].x += xv*w.x; a[j].y += xv*w.y; a[j].z += xv*w.z; a[j].w += xv*w.w;
    }
  }
  float4 bv = *(const float4*)(bias + o4);
  #pragma unroll
  for(int j=0;j<8;j++){
    int r = base + ng*8 + j;
    if(r < rows){
      float4 v = a[j];
      v.x += bv.x; v.y += bv.y; v.z += bv.z; v.w += bv.w;
      *(float4*)(gpre + (size_t)r*512 + o4) = v;
    }
  }
}

__global__ void k_zero_state(float* h, float* c){
  int i = blockIdx.x*256 + threadIdx.x;
  if(i < BB*HH){ h[i]=0.f; c[i]=0.f; }
}

// one LSTM time step; 4 accumulators for ILP on the dependent FMA chain
__global__ void k_lstm_step(const float* gpre, const float* Wh, float* hstate, float* cstate,
                            float* hout, float* hout2, int l){
  int b = blockIdx.x; int o = threadIdx.x;
  __shared__ float hs[HH];
  __shared__ float gs[512];
  if(o < HH) hs[o] = hstate[b*HH+o];
  __syncthreads();
  float a0=0.f, a1=0.f, a2=0.f, a3=0.f;
  #pragma unroll 8
  for(int h=0;h<HH;h+=4){
    a0 += hs[h  ]*Wh[(h  )*512+o];
    a1 += hs[h+1]*Wh[(h+1)*512+o];
    a2 += hs[h+2]*Wh[(h+2)*512+o];
    a3 += hs[h+3]*Wh[(h+3)*512+o];
  }
  gs[o] = gpre[((size_t)b*LL+l)*512+o] + ((a0+a1)+(a2+a3));
  __syncthreads();
  if(o < HH){
    float ig = sigf(gs[o]);
    float fg = sigf(gs[HH+o]);
    float gg = tanhf(gs[2*HH+o]);
    float og = sigf(gs[3*HH+o]);
    float c = fg*cstate[b*HH+o] + ig*gg;
    float h = og*tanhf(c);
    cstate[b*HH+o] = c; hstate[b*HH+o] = h;
    hout[((size_t)b*LL+l)*HH+o] = h;
    if(hout2) hout2[((size_t)b*LL+l)*HH+o] = h;
  }
}

__global__ void k_tok(const int* seq, const int* seq_nt, int* tokid, int* toknt){
  int t = blockIdx.x*blockDim.x + threadIdx.x;
  if(t >= TT) return;
  int b = t % BB, l = t / BB;
  tokid[t] = seq[b*LL+l];
  toknt[t] = seq_nt[b*LL+l];
}

// ---------------- conv prep ----------------
__global__ void k_gather_emb(const int* nid, const float* emb, float* dst){
  int i = blockIdx.x; int o = threadIdx.x;
  dst[i*HH+o] = emb[nid[i]*HH+o];
}

__global__ void k_prep2(const int* sel, const float* xg, const int* g1_nid, const int* g1_nt,
                        float* srcbuf, int* gnid2, int* tsrc2){
  int i = blockIdx.x; int o = threadIdx.x;
  int s = sel[i];
  srcbuf[i*HH+o] = xg[s*HH+o];
  if(o==0){ gnid2[i] = g1_nid[s]; tsrc2[i] = g1_nt[s]; }
}

__global__ void k_dst2(const int* tok_sel, const float* xg, const float* h1, float* dst2){
  int t = blockIdx.x; int o = threadIdx.x;
  int b = t % BB, l = t / BB;
  dst2[t*HH+o] = xg[tok_sel[t]*HH+o] + h1[(b*LL+l)*HH+o];
}

__global__ void k_x0(const int* nid, const int* ntype, const float* emb, const float* hist2,
                     const float* skip, float* srcbuf){
  int i = blockIdx.x; int o = threadIdx.x;
  float a = sigf(skip[ntype[i]]);
  int nd = nid[i];
  srcbuf[i*HH+o] = emb[nd*HH+o]*a + hist2[nd*HH+o]*(1.f-a);
}

__global__ void k_zero_intk(int* p, int n){
  int i = blockIdx.x*256 + threadIdx.x;
  if(i < n) p[i] = 0;
}

// block-aggregated type scatter
__global__ void k_scatter_type(const int* types, int n, int* cnts, int* idxb){
  __shared__ int hist[NTY];
  __shared__ int base[NTY];
  int i = blockIdx.x*256 + threadIdx.x;
  if(threadIdx.x < NTY) hist[threadIdx.x] = 0;
  __syncthreads();
  int t = 0, r = 0;
  bool act = (i < n);
  if(act){ t = types[i]; r = atomicAdd(&hist[t], 1); }
  __syncthreads();
  if(threadIdx.x < NTY && hist[threadIdx.x] > 0)
    base[threadIdx.x] = atomicAdd(&cnts[threadIdx.x], hist[threadIdx.x]);
  __syncthreads();
  if(act) idxb[t*n + base[t] + r] = i;   // stride = n
}

// ---- K/V GEMM, z-split (z=0 -> K, z=1 -> V), LN+time-mod fused into staging.
// xs rows stride 68 (16B-aligned) -> b128 fragment reads, broadcast (no conflicts).
__global__ void k_gemm_kv3(const float* X, const int* src_nid,
                           const float* dia_w, const float* dia_b,
                           const int* idxb, const int* cnts, int stride,
                           const float* KW, const float* VW, float* KVbuf){
  int t = blockIdx.y;
  int cnt = cnts[t];
  int base = blockIdx.x * GT2;
  if(base >= cnt || cnt == 0) return;
  int nn = min(GT2, cnt - base);
  const int* ids = idxb + (size_t)t*stride + base;
  __shared__ __align__(16) float xs[128*ST];
  __shared__ float red[8*68];
  __shared__ float mean_s[GT2], inv_s[GT2];
  __shared__ int sid[GT2], nid[GT2];
  int tid = threadIdx.x;
  if(tid < GT2){
    int s_ = (tid < nn) ? ids[tid] : ids[0];
    sid[tid] = s_;
    nid[tid] = src_nid[s_];
  }
  __syncthreads();
  #pragma unroll
  for(int s=0;s<32;s++){
    int elem = tid + 256*s;
    int k = elem & 127, j = elem >> 7;
    xs[k*ST + j] = X[(size_t)sid[j]*HH + k];
  }
  __syncthreads();
  // fused LN: 4 partials per node
  {
    int j = tid & 63, p = tid >> 6;
    float sm=0.f, sq=0.f;
    for(int i=0;i<32;i++){
      float v = xs[(p*32+i)*ST + j];
      sm += v; sq += v*v;
    }
    red[p*68 + j] = sm;
    red[(4+p)*68 + j] = sq;
  }
  __syncthreads();
  if(tid < GT2){
    float sm = red[tid] + red[68+tid] + red[136+tid] + red[204+tid];
    float sq = red[272+tid] + red[340+tid] + red[408+tid] + red[476+tid];
    float mean = sm*(1.f/128.f);
    float var = sq*(1.f/128.f) - mean*mean;
    mean_s[tid] = mean;
    inv_s[tid] = 1.f/sqrtf(fmaxf(var,0.f)+1e-5f);
  }
  __syncthreads();
  // normalize + time-mod (dims >= D2C)
  #pragma unroll
  for(int s=0;s<32;s++){
    int elem = tid + 256*s;
    int k = elem & 127, j = elem >> 7;
    float v = (xs[k*ST + j] - mean_s[j]) * inv_s[j];
    if(k >= D2C){
      int nd = nid[j];
      v *= sinf(dia_w[(size_t)nd*HH+k] + dia_b[(size_t)nd*HH+k]);
    }
    xs[k*ST + j] = v;
  }
  __syncthreads();
  const float* w = (blockIdx.z == 0) ? (KW + (size_t)t*HH*HH) : (VW + (size_t)t*HH*HH);
  int wroff = (blockIdx.z == 0) ? 0 : 128;
  int o4 = (tid & 31)*4;
  int ng = tid >> 5;
  float4 a[8];
  #pragma unroll
  for(int j=0;j<8;j++) a[j]=make_float4(0,0,0,0);
  for(int k=0;k<HH;k++){
    float4 wk = *(const float4*)(w + (size_t)k*HH + o4);
    const float4* xr = (const float4*)(xs + k*ST + ng*8);
    float4 xa = xr[0], xb = xr[1];
    a[0].x += xa.x*wk.x; a[0].y += xa.x*wk.y; a[0].z += xa.x*wk.z; a[0].w += xa.x*wk.w;
    a[1].x += xa.y*wk.x; a[1].y += xa.y*wk.y; a[1].z += xa.y*wk.z; a[1].w += xa.y*wk.w;
    a[2].x += xa.z*wk.x; a[2].y += xa.z*wk.y; a[2].z += xa.z*wk.z; a[2].w += xa.z*wk.w;
    a[3].x += xa.w*wk.x; a[3].y += xa.w*wk.y; a[3].z += xa.w*wk.z; a[3].w += xa.w*wk.w;
    a[4].x += xb.x*wk.x; a[4].y += xb.x*wk.y; a[4].z += xb.x*wk.z; a[4].w += xb.x*wk.w;
    a[5].x += xb.y*wk.x; a[5].y += xb.y*wk.y; a[5].z += xb.y*wk.z; a[5].w += xb.y*wk.w;
    a[6].x += xb.z*wk.x; a[6].y += xb.z*wk.y; a[6].z += xb.z*wk.z; a[6].w += xb.z*wk.w;
    a[7].x += xb.w*wk.x; a[7].y += xb.w*wk.y; a[7].z += xb.w*wk.z; a[7].w += xb.w*wk.w;
  }
  #pragma unroll
  for(int j=0;j<8;j++){
    int n = ng*8+j;
    if(n < nn){
      *(float4*)(KVbuf + (size_t)sid[n]*256 + wroff + o4) = a[j];
    }
  }
}

// single-output GEMM, z splits the 128 output columns; optional fused LN (no mod);
// resid -> Y = acc + resid (+relu); Y2 optional copy.
__global__ void k_gemm_t2(const float* X, const int* idxb, const int* cnts, int stride,
                          const float* W, const float* resid, float* Y, float* Y2,
                          int relu, int do_ln){
  int t = blockIdx.y;
  int cnt = cnts[t];
  int base = blockIdx.x * GT2;
  if(base >= cnt || cnt == 0) return;
  int nn = min(GT2, cnt - base);
  const int* ids = idxb + (size_t)t*stride + base;
  __shared__ __align__(16) float xs[128*ST];
  __shared__ float red[8*68];
  __shared__ float mean_s[GT2], inv_s[GT2];
  __shared__ int sid[GT2];
  int tid = threadIdx.x;
  if(tid < GT2) sid[tid] = (tid < nn) ? ids[tid] : ids[0];
  __syncthreads();
  #pragma unroll
  for(int s=0;s<32;s++){
    int elem = tid + 256*s;
    int k = elem & 127, j = elem >> 7;
    xs[k*ST + j] = X[(size_t)sid[j]*HH + k];
  }
  __syncthreads();
  if(do_ln){
    {
      int j = tid & 63, p = tid >> 6;
      float sm=0.f, sq=0.f;
      for(int i=0;i<32;i++){
        float v = xs[(p*32+i)*ST + j];
        sm += v; sq += v*v;
      }
      red[p*68 + j] = sm;
      red[(4+p)*68 + j] = sq;
    }
    __syncthreads();
    if(tid < GT2){
      float sm = red[tid] + red[68+tid] + red[136+tid] + red[204+tid];
      float sq = red[272+tid] + red[340+tid] + red[408+tid] + red[476+tid];
      float mean = sm*(1.f/128.f);
      float var = sq*(1.f/128.f) - mean*mean;
      mean_s[tid] = mean;
      inv_s[tid] = 1.f/sqrtf(fmaxf(var,0.f)+1e-5f);
    }
    __syncthreads();
    #pragma unroll
    for(int s=0;s<32;s++){
      int elem = tid + 256*s;
      int k = elem & 127, j = elem >> 7;
      xs[k*ST + j] = (xs[k*ST + j] - mean_s[j]) * inv_s[j];
    }
    __syncthreads();
  }
  const float* w = W + (size_t)t*HH*HH;
  int o4 = (blockIdx.z << 6) + (tid & 15)*4;
  int ng = tid >> 4;          // 16 groups x 4 nodes
  float4 a[4];
  #pragma unroll
  for(int j=0;j<4;j++) a[j]=make_float4(0,0,0,0);
  for(int k=0;k<HH;k++){
    float4 wk = *(const float4*)(w + (size_t)k*HH + o4);
    float4 x = *(const float4*)(xs + k*ST + ng*4);
    a[0].x += x.x*wk.x; a[0].y += x.x*wk.y; a[0].z += x.x*wk.z; a[0].w += x.x*wk.w;
    a[1].x += x.y*wk.x; a[1].y += x.y*wk.y; a[1].z += x.y*wk.z; a[1].w += x.y*wk.w;
    a[2].x += x.z*wk.x; a[2].y += x.z*wk.y; a[2].z += x.z*wk.z; a[2].w += x.z*wk.w;
    a[3].x += x.w*wk.x; a[3].y += x.w*wk.y; a[3].z += x.w*wk.z; a[3].w += x.w*wk.w;
  }
  #pragma unroll
  for(int j=0;j<4;j++){
    int n = ng*4+j;
    if(n < nn){
      size_t r = (size_t)sid[n]*HH + o4;
      float4 v = a[j];
      if(resid){
        float4 rs = *(const float4*)(resid + r);
        v.x += rs.x; v.y += rs.y; v.z += rs.z; v.w += rs.w;
        if(relu){ v.x=fmaxf(v.x,0.f); v.y=fmaxf(v.y,0.f); v.z=fmaxf(v.z,0.f); v.w=fmaxf(v.w,0.f); }
      }
      *(float4*)(Y + r) = v;
      if(Y2) *(float4*)(Y2 + r) = v;
    }
  }
}

// EW2all[layer][50][128] = edge_emb @ convE[layer]; one launch for all 4 layers
__global__ void k_edge_tab4(const float* edge_emb, const float* convE, float* EW2all){
  int r = blockIdx.x; int layer = blockIdx.y; int o = threadIdx.x;
  const float* EWp = convE + (size_t)layer*32*HH;
  float acc = 0.f;
  for(int j=0;j<32;j++) acc += edge_emb[r*32+j]*EWp[j*HH+o];
  EW2all[((size_t)layer*50 + r)*HH + o] = acc;
}

// ---------------- CSR build (per graph) ----------------
__global__ void k_hist_dst(const int* edst, int E, int* cnt){
  int e = blockIdx.x*256 + threadIdx.x;
  if(e < E) atomicAdd(&cnt[edst[e]], 1);
}
__global__ void k_scan(const int* cnt, int n, int* row_ptr, int* cursor){
  __shared__ int tsum[1024];
  int tid = threadIdx.x;
  int per = (n + 1023) / 1024;
  int start = tid*per; int end = min(start+per, n);
  int s = 0;
  for(int i=start;i<end;i++) s += cnt[i];
  tsum[tid] = s; __syncthreads();
  for(int off=1;off<1024;off<<=1){
    int v = (tid>=off) ? tsum[tid-off] : 0;
    __syncthreads();
    tsum[tid] += v;
    __syncthreads();
  }
  int run = (tid==0) ? 0 : tsum[tid-1];
  for(int i=start;i<end;i++){ row_ptr[i]=run; cursor[i]=run; run += cnt[i]; }
  if(end == n) row_ptr[n] = run;
}
__global__ void k_fill_csr(const int* edst, int E, int* cursor, int* eid){
  int e = blockIdx.x*256 + threadIdx.x;
  if(e >= E) return;
  int pos = atomicAdd(&cursor[edst[e]], 1);
  eid[pos] = e;
}
__global__ void k_permute_edges(const int* eid, const int* esrc, const int* ew, const int* ety,
                                int E, int* esrc_s, int* ew_s, int* ety_s){
  int r = blockIdx.x*256 + threadIdx.x;
  if(r >= E) return;
  int e = eid[r];
  esrc_s[r] = esrc[e]; ew_s[r] = ew[e]; ety_s[r] = ety[e];
}

// single-pass online-softmax attention, TWO independent edge states (ILP 2),
// exact merge at the end. K+V fetched from interleaved KV row.
__global__ void k_attn_fused3(const int* row_ptr, const int* esrc_s, const int* ew_s, const int* ety_s,
                              const float* KVbuf, const float* Qbuf,
                              const float* EW2, const float* mu, float* Abuf){
  int d = blockIdx.x; int o = threadIdx.x;
  int r0 = row_ptr[d], r1 = row_ptr[d+1];
  __shared__ float q[HH];
  q[o] = Qbuf[(size_t)d*HH+o];
  __syncthreads();
  int h = o >> 4;
  float qo = q[o];
  float m1=-3.0e38f, d1=0.f, a1=0.f;
  float m2=-3.0e38f, d2=0.f, a2=0.f;
  int r = r0;
  for(; r+1 < r1; r += 2){
    int sA = esrc_s[r],   wA = ew_s[r];
    int sB = esrc_s[r+1], wB = ew_s[r+1];
    const float* kvA = KVbuf + (size_t)sA*256;
    const float* kvB = KVbuf + (size_t)sB*256;
    float kA = kvA[o], vA = kvA[128+o];
    float kB = kvB[o], vB = kvB[128+o];
    float pA = qo*(kA + EW2[wA*HH+o]);
    float pB = qo*(kB + EW2[wB*HH+o]);
    pA += __shfl_xor(pA, 1, 64);  pB += __shfl_xor(pB, 1, 64);
    pA += __shfl_xor(pA, 2, 64);  pB += __shfl_xor(pB, 2, 64);
    pA += __shfl_xor(pA, 4, 64);  pB += __shfl_xor(pB, 4, 64);
    pA += __shfl_xor(pA, 8, 64);  pB += __shfl_xor(pB, 8, 64);
    float s1 = pA * mu[ety_s[r]*NH+h] * 0.25f;
    float s2 = pB * mu[ety_s[r+1]*NH+h] * 0.25f;
    float mn1 = fmaxf(m1, s1);
    float mn2 = fmaxf(m2, s2);
    float sc1 = expf(m1 - mn1), e1 = expf(s1 - mn1);
    float sc2 = expf(m2 - mn2), e2 = expf(s2 - mn2);
    d1 = d1*sc1 + e1;  a1 = a1*sc1 + e1*vA;  m1 = mn1;
    d2 = d2*sc2 + e2;  a2 = a2*sc2 + e2*vB;  m2 = mn2;
  }
  if(r < r1){
    int sA = esrc_s[r], wA = ew_s[r];
    const float* kvA = KVbuf + (size_t)sA*256;
    float kA = kvA[o], vA = kvA[128+o];
    float pA = qo*(kA + EW2[wA*HH+o]);
    pA += __shfl_xor(pA, 1, 64);
    pA += __shfl_xor(pA, 2, 64);
    pA += __shfl_xor(pA, 4, 64);
    pA += __shfl_xor(pA, 8, 64);
    float s1 = pA * mu[ety_s[r]*NH+h] * 0.25f;
    float mn1 = fmaxf(m1, s1);
    float sc1 = expf(m1 - mn1), e1 = expf(s1 - mn1);
    d1 = d1*sc1 + e1;  a1 = a1*sc1 + e1*vA;  m1 = mn1;
  }
  // exact merge of the two states
  float mn = fmaxf(m1, m2);
  float sc1 = expf(m1 - mn), sc2 = expf(m2 - mn);
  float dd  = d1*sc1 + d2*sc2;
  float acc = a1*sc1 + a2*sc2;
  Abuf[(size_t)d*HH + o] = acc / fmaxf(dd, 1e-9f);
}

// ---------------- stage D: token pooling ----------------
__global__ void k_seq2(const float* x2, float* xout){
  int bl = blockIdx.x; int o = threadIdx.x;
  int b = bl / LL, l = bl % LL;
  xout[bl*HH+o] = x2[(l*BB+b)*HH+o];
}

__global__ void k_zero_hist(float* hist2, float* cnt, unsigned* amax, float* aden){
  int i = blockIdx.x*blockDim.x + threadIdx.x;
  if(i < CHILDN*HH) hist2[i] = 0.f;
  if(i < CHILDN){ cnt[i] = 0.f; aden[i] = 0.f; amax[i] = 0x007FFFFFu; }
}

__global__ void k_tokatt(const float* h2f, const int* toknt, const float* ipW, const float* iaW,
                         float* abuf, unsigned* amax, const int* tokid){
  int t = blockIdx.x; int o = threadIdx.x;
  __shared__ float es[HH];
  __shared__ float red[HH];
  int b = t % BB, l = t / BB;
  es[o] = h2f[(b*LL+l)*HH+o];
  __syncthreads();
  int nt = toknt[t];
  const float* w = ipW + (size_t)nt*HH*HH;
  float acc = 0.f;
  for(int j=0;j<HH;j++) acc += es[j]*w[j*HH+o];
  float u = tanhf(acc);
  red[o] = u * iaW[nt*HH+o];
  __syncthreads();
  for(int s=64;s>0;s>>=1){ if(o<s) red[o]+=red[o+s]; __syncthreads(); }
  if(o==0){
    float a = red[0];
    abuf[t] = a;
    atomicMax(&amax[tokid[t]], fenc(a));
  }
}

__global__ void k_tokexp(const int* tokid, float* abuf, const unsigned* amax, float* aden, float* cnt){
  int t = blockIdx.x*blockDim.x + threadIdx.x;
  if(t >= TT) return;
  int c = tokid[t];
  float ex = expf(abuf[t]-fdec(amax[c]));
  abuf[t] = ex;
  atomicAdd(&aden[c], ex);
  atomicAdd(&cnt[c], 1.f);
}

__global__ void k_tokagg(const int* tokid, const float* abuf, const float* aden,
                         const float* h2f, float* hist2){
  int t = blockIdx.x; int o = threadIdx.x;
  int c = tokid[t];
  float w = abuf[t]/fmaxf(aden[c],1e-9f);
  int b = t % BB, l = t / BB;
  atomicAdd(&hist2[c*HH+o], w*h2f[(b*LL+l)*HH+o]);
}

__global__ void k_histfix(const float* cnt, const float* hist_emb, float* hist2){
  int c = blockIdx.x; int o = threadIdx.x;
  if(cnt[c] == 0.f) hist2[c*HH+o] = hist_emb[c*HH+o];
}

// ---------------- parent pooling ----------------
__global__ void k_zero_parent(float* psum, float* pcnt){
  int i = blockIdx.x*blockDim.x + threadIdx.x;
  if(i < PARENTN*HH) psum[i] = 0.f;
  if(i < PARENTN) pcnt[i] = 0.f;
}

__global__ void k_peagg(const int* pe_p, const int* pe_c, const float* cef, float* psum, float* pcnt){
  int i = blockIdx.x; int o = threadIdx.x;
  int p = pe_p[i], c = pe_c[i];
  atomicAdd(&psum[p*HH+o], cef[c*HH+o]);
  if(o==0) atomicAdd(&pcnt[p], 1.f);
}

__global__ void k_parent(const float* psum, const float* pcnt, float* out){
  int i = blockIdx.x; int o = threadIdx.x;
  out[i*HH+o] = psum[i*HH+o]/fmaxf(pcnt[i],1.f);
}

extern "C" void kernel_launch(void* const* d_in, const int* in_sizes, int n_in,
                              void* d_out, int out_size, void* d_ws, size_t ws_size,
                              hipStream_t stream){
  const int* seq     = (const int*)d_in[0];
  const int* seq_nt  = (const int*)d_in[1];
  const int* dur     = (const int*)d_in[2];
  const int* stime   = (const int*)d_in[3];
  const int* etime   = (const int*)d_in[4];
  const int* g1_nid  = (const int*)d_in[5];
  const int* g1_nt   = (const int*)d_in[6];
  const int* g1_esrc = (const int*)d_in[7];
  const int* g1_edst = (const int*)d_in[8];
  const int* g1_ety  = (const int*)d_in[9];
  const int* g1_ew   = (const int*)d_in[10];
  const int* g2_sel  = (const int*)d_in[11];
  const int* g2_esrc = (const int*)d_in[12];
  const int* g2_edst = (const int*)d_in[13];
  const int* g2_ety  = (const int*)d_in[14];
  const int* g2_ew   = (const int*)d_in[15];
  const int* tok_sel = (const int*)d_in[16];
  const int* g4_esrc = (const int*)d_in[17];
  const int* g4_edst = (const int*)d_in[18];
  const int* g4_ety  = (const int*)d_in[19];
  const int* g4_ew   = (const int*)d_in[20];
  const int* pe_p    = (const int*)d_in[21];
  const int* pe_c    = (const int*)d_in[22];
  const float* emb     = (const float*)d_in[23];
  const float* hist_emb= (const float*)d_in[24];
  const float* edge_emb= (const float*)d_in[25];
  const float* dia_w   = (const float*)d_in[26];
  const float* dia_b   = (const float*)d_in[27];
  const float* t2v_w   = (const float*)d_in[28];
  const float* t2v_b   = (const float*)d_in[29];
  const float* exp_W   = (const float*)d_in[30];
  const float* exp_b   = (const float*)d_in[31];
  const float* l1Wi    = (const float*)d_in[32];
  const float* l1Wh    = (const float*)d_in[33];
  const float* l1b     = (const float*)d_in[34];
  const float* l2Wi    = (const float*)d_in[35];
  const float* l2Wh    = (const float*)d_in[36];
  const float* l2b     = (const float*)d_in[37];
  const float* convK   = (const float*)d_in[38];
  const float* convQ   = (const float*)d_in[39];
  const float* convV   = (const float*)d_in[40];
  const float* convO   = (const float*)d_in[41];
  const float* convE   = (const float*)d_in[42];
  const float* convMu  = (const float*)d_in[43];
  const float* ipW     = (const float*)d_in[44];
  const float* iaW     = (const float*)d_in[45];
  const float* skip    = (const float*)d_in[46];
  float* outp = (float*)d_out;

  // workspace arena
  char* wsp = (char*)d_ws;
  size_t off = 0;
  auto A = [&](size_t nbytes)->char*{ char* p = wsp+off; off += (nbytes+255)&~(size_t)255; return p; };
  float*    srcbuf = (float*)   A((size_t)N1SN*HH*4);
  float*    KVbuf  = (float*)   A((size_t)N1SN*256*4);   // interleaved [K|V]
  float*    Qbuf   = (float*)   A((size_t)N1DN*HH*4);
  float*    Abuf   = (float*)   A((size_t)N1DN*HH*4);
  float*    xbuf   = (float*)   A((size_t)TT*HH*4);
  float*    gpre   = (float*)   A((size_t)TT*512*4);
  float*    h1     = (float*)   A((size_t)TT*HH*4);
  float*    dst2   = (float*)   A((size_t)TT*HH*4);
  float*    xg     = (float*)   A((size_t)N1DN*HH*4);
  float*    x2     = (float*)   A((size_t)TT*HH*4);
  float*    h2f    = (float*)   A((size_t)TT*HH*4);
  float*    hist2  = (float*)   A((size_t)CHILDN*HH*4);
  float*    cnt    = (float*)   A((size_t)CHILDN*4);
  float*    abuf   = (float*)   A((size_t)TT*4);
  unsigned* amax   = (unsigned*)A((size_t)CHILDN*4);
  float*    aden   = (float*)   A((size_t)CHILDN*4);
  float*    x3     = (float*)   A((size_t)N1DN*HH*4);
  float*    cef    = (float*)   A((size_t)N4DN*HH*4);
  float*    psum   = (float*)   A((size_t)PARENTN*HH*4);
  float*    pcnt   = (float*)   A((size_t)PARENTN*4);
  int*      tokid  = (int*)     A((size_t)TT*4);
  int*      toknt  = (int*)     A((size_t)TT*4);
  int*      gnid2  = (int*)     A((size_t)N2N*4);
  int*      tsrc2  = (int*)     A((size_t)N2N*4);
  // precomputed type scatters: S1 g1src(50000), S2 g1(20000), S3 conv2src(20000),
  // S4 tok(5120), S5 g1(5000)
  int*      idxS1  = (int*)     A((size_t)NTY*N1SN*4);
  int*      idxS2  = (int*)     A((size_t)NTY*N1DN*4);
  int*      idxS3  = (int*)     A((size_t)NTY*N2N*4);
  int*      idxS4  = (int*)     A((size_t)NTY*TT*4);
  int*      idxS5  = (int*)     A((size_t)NTY*N4DN*4);
  int*      cntall = (int*)     A((size_t)5*NTY*4);
  float*    EW2all = (float*)   A((size_t)4*50*HH*4);
  float*    hstate = (float*)   A((size_t)BB*HH*4);
  float*    cstate = (float*)   A((size_t)BB*HH*4);
  // CSR structures + CSR-ordered edge attributes
  int*      g1row  = (int*)     A((size_t)(N1DN+1)*4);
  int*      g1eid  = (int*)     A((size_t)E1N*4);
  int*      g1src_s= (int*)     A((size_t)E1N*4);
  int*      g1ew_s = (int*)     A((size_t)E1N*4);
  int*      g1ety_s= (int*)     A((size_t)E1N*4);
  int*      g2row  = (int*)     A((size_t)(TT+1)*4);
  int*      g2eid  = (int*)     A((size_t)E2N*4);
  int*      g2src_s= (int*)     A((size_t)E2N*4);
  int*      g2ew_s = (int*)     A((size_t)E2N*4);
  int*      g2ety_s= (int*)     A((size_t)E2N*4);
  int*      g4row  = (int*)     A((size_t)(N4DN+1)*4);
  int*      g4eid  = (int*)     A((size_t)E4N*4);
  int*      g4src_s= (int*)     A((size_t)E4N*4);
  int*      g4ew_s = (int*)     A((size_t)E4N*4);
  int*      g4ety_s= (int*)     A((size_t)E4N*4);
  int*      icnt   = (int*)     A((size_t)(N1DN+1)*4);
  int*      icur   = (int*)     A((size_t)(N1DN+1)*4);
  if(off > ws_size) return;  // insufficient scratch: output stays zero

  auto build_csr = [&](const int* edst, const int* esrc, const int* ew, const int* ety,
                       int E, int ndst, int* rowp, int* eid, int* src_s, int* ew_s, int* ety_s){
    k_zero_intk<<<(ndst+255)/256, 256, 0, stream>>>(icnt, ndst);
    k_hist_dst<<<(E+255)/256, 256, 0, stream>>>(edst, E, icnt);
    k_scan<<<1, 1024, 0, stream>>>(icnt, ndst, rowp, icur);
    k_fill_csr<<<(E+255)/256, 256, 0, stream>>>(edst, E, icur, eid);
    k_permute_edges<<<(E+255)/256, 256, 0, stream>>>(eid, esrc, ew, ety, E, src_s, ew_s, ety_s);
  };

  auto run_conv = [&](const float* src_h, const int* src_nid, int nsrc,
                      const int* idx_src, int* cnt_src, int stride_src,
                      const float* dst_h, int ndst,
                      const int* idx_dst, int* cnt_dst, int stride_dst,
                      const int* rowp, const int* src_s, const int* ew_s, const int* ety_s,
                      int layer, float* outbuf, float* out2, int relu){
    const float* KW  = convK  + (size_t)layer*NTY*HH*HH;
    const float* QW  = convQ  + (size_t)layer*NTY*HH*HH;
    const float* VW  = convV  + (size_t)layer*NTY*HH*HH;
    const float* OW  = convO  + (size_t)layer*NTY*HH*HH;
    const float* MU  = convMu + (size_t)layer*NRL*NH;
    const float* EW2 = EW2all + (size_t)layer*50*HH;
    dim3 gkv((nsrc+GT2-1)/GT2, NTY, 2);
    k_gemm_kv3<<<gkv, 256, 0, stream>>>(src_h, src_nid, dia_w, dia_b,
                                        idx_src, cnt_src, stride_src, KW, VW, KVbuf);
    dim3 gq((ndst+GT2-1)/GT2, NTY, 2);
    k_gemm_t2<<<gq, 256, 0, stream>>>(dst_h, idx_dst, cnt_dst, stride_dst, QW,
                                      (const float*)nullptr, Qbuf, (float*)nullptr, 0, 1);
    k_attn_fused3<<<ndst, HH, 0, stream>>>(rowp, src_s, ew_s, ety_s, KVbuf, Qbuf, EW2, MU, Abuf);
    k_gemm_t2<<<gq, 256, 0, stream>>>(Abuf, idx_dst, cnt_dst, stride_dst, OW,
                                      dst_h, outbuf, out2, relu, 0);
  };

  // ---- stage A: features + LSTM1 ----
  k_featx<<<TT, HH, 0, stream>>>(seq, dur, stime, etime, emb, dia_w, dia_b, t2v_w, t2v_b, exp_W, exp_b, xbuf);
  k_xwi2<<<(TT+15)/16, 256, 0, stream>>>(xbuf, l1Wi, l1b, gpre, TT);
  k_zero_state<<<(BB*HH+255)/256, 256, 0, stream>>>(hstate, cstate);
  for(int l=0;l<LL;l++)
    k_lstm_step<<<BB, 512, 0, stream>>>(gpre, l1Wh, hstate, cstate, h1, (float*)nullptr, l);
  k_tok<<<(TT+255)/256, 256, 0, stream>>>(seq, seq_nt, tokid, toknt);

  // ---- upfront: edge tables, type scatters, g1 CSR ----
  k_edge_tab4<<<dim3(50,4), HH, 0, stream>>>(edge_emb, convE, EW2all);
  k_zero_intk<<<1, 64, 0, stream>>>(cntall, 5*NTY);
  k_scatter_type<<<(N1SN+255)/256, 256, 0, stream>>>(g1_nt, N1SN, cntall+0*NTY, idxS1);
  k_scatter_type<<<(N1DN+255)/256, 256, 0, stream>>>(g1_nt, N1DN, cntall+1*NTY, idxS2);
  k_scatter_type<<<(TT+255)/256, 256, 0, stream>>>(toknt, TT, cntall+3*NTY, idxS4);
  k_scatter_type<<<(N4DN+255)/256, 256, 0, stream>>>(g1_nt, N4DN, cntall+4*NTY, idxS5);
  build_csr(g1_edst, g1_esrc, g1_ew, g1_ety, E1N, N1DN, g1row, g1eid, g1src_s, g1ew_s, g1ety_s);

  // ---- conv1 on g1 ----
  k_gather_emb<<<N1SN, HH, 0, stream>>>(g1_nid, emb, srcbuf);
  run_conv(srcbuf, g1_nid, N1SN, idxS1, cntall+0*NTY, N1SN,
           srcbuf, N1DN, idxS2, cntall+1*NTY, N1DN,
           g1row, g1src_s, g1ew_s, g1ety_s, 0, xg, (float*)nullptr, 1);

  // ---- conv2 on g2 ----
  build_csr(g2_edst, g2_esrc, g2_ew, g2_ety, E2N, TT, g2row, g2eid, g2src_s, g2ew_s, g2ety_s);
  k_prep2<<<N2N, HH, 0, stream>>>(g2_sel, xg, g1_nid, g1_nt, srcbuf, gnid2, tsrc2);
  k_scatter_type<<<(N2N+255)/256, 256, 0, stream>>>(tsrc2, N2N, cntall+2*NTY, idxS3);
  k_dst2<<<TT, HH, 0, stream>>>(tok_sel, xg, h1, dst2);
  run_conv(srcbuf, gnid2, N2N, idxS3, cntall+2*NTY, N2N,
           dst2, TT, idxS4, cntall+3*NTY, TT,
           g2row, g2src_s, g2ew_s, g2ety_s, 1, x2, (float*)nullptr, 1);

  // ---- LSTM2 (h2 is output 0) ----
  k_seq2<<<TT, HH, 0, stream>>>(x2, xbuf);
  k_xwi2<<<(TT+15)/16, 256, 0, stream>>>(xbuf, l2Wi, l2b, gpre, TT);
  k_zero_state<<<(BB*HH+255)/256, 256, 0, stream>>>(hstate, cstate);
  for(int l=0;l<LL;l++)
    k_lstm_step<<<BB, 512, 0, stream>>>(gpre, l2Wh, hstate, cstate, h2f, outp, l);

  // ---- stage D: token attention pooling -> hist2 ----
  k_zero_hist<<<(CHILDN*HH+255)/256, 256, 0, stream>>>(hist2, cnt, amax, aden);
  k_tokatt<<<TT, HH, 0, stream>>>(h2f, toknt, ipW, iaW, abuf, amax, tokid);
  k_tokexp<<<(TT+255)/256, 256, 0, stream>>>(tokid, abuf, amax, aden, cnt);
  k_tokagg<<<TT, HH, 0, stream>>>(tokid, abuf, aden, h2f, hist2);
  k_histfix<<<CHILDN, HH, 0, stream>>>(cnt, hist_emb, hist2);

  // ---- conv3 on g1 with skip-mixed input (g1 CSR + scatters reused) ----
  k_x0<<<N1SN, HH, 0, stream>>>(g1_nid, g1_nt, emb, hist2, skip, srcbuf);
  run_conv(srcbuf, g1_nid, N1SN, idxS1, cntall+0*NTY, N1SN,
           srcbuf, N1DN, idxS2, cntall+1*NTY, N1DN,
           g1row, g1src_s, g1ew_s, g1ety_s, 2, x3, (float*)nullptr, 1);

  // ---- conv4 on g4 (child_embed = output 1, no relu) ----
  build_csr(g4_edst, g4_esrc, g4_ew, g4_ety, E4N, N4DN, g4row, g4eid, g4src_s, g4ew_s, g4ety_s);
  run_conv(x3, g1_nid, N1DN, idxS2, cntall+1*NTY, N1DN,
           x3, N4DN, idxS5, cntall+4*NTY, N4DN,
           g4row, g4src_s, g4ew_s, g4ety_s, 3, cef, outp + (size_t)TT*HH, 0);

  // ---- parent pooling (output 2) ----
  k_zero_parent<<<(PARENTN*HH+255)/256, 256, 0, stream>>>(psum, pcnt);
  k_peagg<<<EC2PN, HH, 0, stream>>>(pe_p, pe_c, cef, psum, pcnt);
  k_parent<<<PARENTN, HH, 0, stream>>>(psum, pcnt, outp + (size_t)TT*HH + (size_t)N4DN*HH);
}

// Round 10
// 1381.049 us; speedup vs baseline: 2.1047x; 1.0102x over previous
//
#include <hip/hip_runtime.h>
#include <math.h>

#define BB 256
#define LL 20
#define HH 128
#define NH 8
#define D2C 64
#define NTY 4
#define NRL 4
#define CHILDN 30001
#define PARENTN 500
#define N1SN 50000
#define N1DN 20000
#define E1N 300000
#define N2N 20000
#define E2N 200000
#define TT (BB*LL)
#define N4DN 5000
#define E4N 150000
#define EC2PN 8000
#define GT3 32   // nodes per GEMM tile
#define ST3 33   // LDS row stride: 33%32=1 -> conflict-free staging & broadcast reads

__device__ __forceinline__ unsigned fenc(float f){ unsigned u=__float_as_uint(f); return (u&0x80000000u)? ~u : (u|0x80000000u); }
__device__ __forceinline__ float fdec(unsigned u){ return (u&0x80000000u)? __uint_as_float(u^0x80000000u) : __uint_as_float(~u); }
__device__ __forceinline__ float sigf(float x){ return 1.f/(1.f+expf(-x)); }

// ---------------- Stage A: feature expansion ----------------
__global__ void k_featx(const int* seq, const int* dur, const int* stime, const int* etime,
                        const float* emb, const float* dia_w, const float* dia_b,
                        const float* t2v_w, const float* t2v_b,
                        const float* exp_W, const float* exp_b, float* xout){
  int bl = blockIdx.x; int o = threadIdx.x;
  __shared__ float feat[272];
  int node = seq[bl];
  float ts = (float)stime[bl], te = (float)etime[bl], td = (float)dur[bl];
  float e0 = emb[node*HH+o];
  float st, et;
  if(o < D2C){ st = e0; et = e0; }
  else {
    float w = dia_w[node*HH+o], b = dia_b[node*HH+o];
    st = e0 * sinf(w*ts + b);
    et = e0 * sinf(w*te + b);
  }
  feat[o] = st; feat[HH+o] = et;
  if(o < 16){
    float w = t2v_w[o], b = t2v_b[o];
    feat[256+o] = (o==0) ? (w*td + b) : sinf(w*td + b);
  }
  __syncthreads();
  float acc = exp_b[o];
  for(int j=0;j<272;j++) acc += feat[j]*exp_W[j*HH+o];
  xout[bl*HH+o] = fmaxf(acc, 0.f);
}

// tiled x @ Wi + b -> gpre: 16 rows x 512 cols per block
__global__ void k_xwi2(const float* x, const float* Wi, const float* bias, float* gpre, int rows){
  int base = blockIdx.x*16;
  __shared__ float xs[128*17];
  int tid = threadIdx.x;
  #pragma unroll
  for(int s=0;s<8;s++){
    int elem = tid + 256*s;
    int k = elem & 127, j = elem >> 7;
    int r = base + j;
    xs[k*17 + j] = (r < rows) ? x[(size_t)r*HH + k] : 0.f;
  }
  __syncthreads();
  int o4 = (tid & 127)*4;
  int ng = tid >> 7;
  float4 a[8];
  #pragma unroll
  for(int j=0;j<8;j++) a[j]=make_float4(0,0,0,0);
  for(int k=0;k<HH;k++){
    float4 w = *(const float4*)(Wi + (size_t)k*512 + o4);
    const float* xr = xs + k*17 + ng*8;
    #pragma unroll
    for(int j=0;j<8;j++){
      float xv = xr[j];
      a[j].x += xv*w.x; a[j].y += xv*w.y; a[j].z += xv*w.z; a[j].w += xv*w.w;
    }
  }
  float4 bv = *(const float4*)(bias + o4);
  #pragma unroll
  for(int j=0;j<8;j++){
    int r = base + ng*8 + j;
    if(r < rows){
      float4 v = a[j];
      v.x += bv.x; v.y += bv.y; v.z += bv.z; v.w += bv.w;
      *(float4*)(gpre + (size_t)r*512 + o4) = v;
    }
  }
}

__global__ void k_zero_state(float* h, float* c){
  int i = blockIdx.x*256 + threadIdx.x;
  if(i < BB*HH){ h[i]=0.f; c[i]=0.f; }
}

// one LSTM time step; 4 accumulators for ILP on the dependent FMA chain
__global__ void k_lstm_step(const float* gpre, const float* Wh, float* hstate, float* cstate,
                            float* hout, float* hout2, int l){
  int b = blockIdx.x; int o = threadIdx.x;
  __shared__ float hs[HH];
  __shared__ float gs[512];
  if(o < HH) hs[o] = hstate[b*HH+o];
  __syncthreads();
  float a0=0.f, a1=0.f, a2=0.f, a3=0.f;
  #pragma unroll 8
  for(int h=0;h<HH;h+=4){
    a0 += hs[h  ]*Wh[(h  )*512+o];
    a1 += hs[h+1]*Wh[(h+1)*512+o];
    a2 += hs[h+2]*Wh[(h+2)*512+o];
    a3 += hs[h+3]*Wh[(h+3)*512+o];
  }
  gs[o] = gpre[((size_t)b*LL+l)*512+o] + ((a0+a1)+(a2+a3));
  __syncthreads();
  if(o < HH){
    float ig = sigf(gs[o]);
    float fg = sigf(gs[HH+o]);
    float gg = tanhf(gs[2*HH+o]);
    float og = sigf(gs[3*HH+o]);
    float c = fg*cstate[b*HH+o] + ig*gg;
    float h = og*tanhf(c);
    cstate[b*HH+o] = c; hstate[b*HH+o] = h;
    hout[((size_t)b*LL+l)*HH+o] = h;
    if(hout2) hout2[((size_t)b*LL+l)*HH+o] = h;
  }
}

__global__ void k_tok(const int* seq, const int* seq_nt, int* tokid, int* toknt){
  int t = blockIdx.x*blockDim.x + threadIdx.x;
  if(t >= TT) return;
  int b = t % BB, l = t / BB;
  tokid[t] = seq[b*LL+l];
  toknt[t] = seq_nt[b*LL+l];
}

// ---------------- conv prep ----------------
__global__ void k_gather_emb(const int* nid, const float* emb, float* dst){
  int i = blockIdx.x; int o = threadIdx.x;
  dst[i*HH+o] = emb[nid[i]*HH+o];
}

__global__ void k_prep2(const int* sel, const float* xg, const int* g1_nid, const int* g1_nt,
                        float* srcbuf, int* gnid2, int* tsrc2){
  int i = blockIdx.x; int o = threadIdx.x;
  int s = sel[i];
  srcbuf[i*HH+o] = xg[s*HH+o];
  if(o==0){ gnid2[i] = g1_nid[s]; tsrc2[i] = g1_nt[s]; }
}

__global__ void k_dst2(const int* tok_sel, const float* xg, const float* h1, float* dst2){
  int t = blockIdx.x; int o = threadIdx.x;
  int b = t % BB, l = t / BB;
  dst2[t*HH+o] = xg[tok_sel[t]*HH+o] + h1[(b*LL+l)*HH+o];
}

__global__ void k_x0(const int* nid, const int* ntype, const float* emb, const float* hist2,
                     const float* skip, float* srcbuf){
  int i = blockIdx.x; int o = threadIdx.x;
  float a = sigf(skip[ntype[i]]);
  int nd = nid[i];
  srcbuf[i*HH+o] = emb[nd*HH+o]*a + hist2[nd*HH+o]*(1.f-a);
}

__global__ void k_zero_intk(int* p, int n){
  int i = blockIdx.x*256 + threadIdx.x;
  if(i < n) p[i] = 0;
}

// block-aggregated type scatter
__global__ void k_scatter_type(const int* types, int n, int* cnts, int* idxb){
  __shared__ int hist[NTY];
  __shared__ int base[NTY];
  int i = blockIdx.x*256 + threadIdx.x;
  if(threadIdx.x < NTY) hist[threadIdx.x] = 0;
  __syncthreads();
  int t = 0, r = 0;
  bool act = (i < n);
  if(act){ t = types[i]; r = atomicAdd(&hist[t], 1); }
  __syncthreads();
  if(threadIdx.x < NTY && hist[threadIdx.x] > 0)
    base[threadIdx.x] = atomicAdd(&cnts[threadIdx.x], hist[threadIdx.x]);
  __syncthreads();
  if(act) idxb[t*n + base[t] + r] = i;   // stride = n
}

// ---- K+V GEMM, 32-node tile, dual output, LN+time-mod fused into staging.
// ST3=33 -> staging writes, LN passes, and broadcast compute reads all conflict-free.
// LDS ~17KB -> up to 8 blocks/CU. Inner loop: 2 float4 weight loads + 32 FMAs.
__global__ void k_gemm_kv4(const float* X, const int* src_nid,
                           const float* dia_w, const float* dia_b,
                           const int* idxb, const int* cnts, int stride,
                           const float* KW, const float* VW, float* KVbuf){
  int t = blockIdx.y;
  int cnt = cnts[t];
  int base = blockIdx.x * GT3;
  if(base >= cnt || cnt == 0) return;
  int nn = min(GT3, cnt - base);
  const int* ids = idxb + (size_t)t*stride + base;
  __shared__ float xs[128*ST3];
  __shared__ float red[16*36];
  __shared__ float mean_s[GT3], inv_s[GT3];
  __shared__ int sid[GT3], nid[GT3];
  int tid = threadIdx.x;
  if(tid < GT3){
    int s_ = (tid < nn) ? ids[tid] : ids[0];
    sid[tid] = s_;
    nid[tid] = src_nid[s_];
  }
  __syncthreads();
  #pragma unroll
  for(int s=0;s<16;s++){
    int elem = tid + 256*s;
    int k = elem & 127, j = elem >> 7;
    xs[k*ST3 + j] = X[(size_t)sid[j]*HH + k];
  }
  __syncthreads();
  // fused LN: 8 partials per node (j = node, p = partial)
  {
    int j = tid & 31, p = tid >> 5;
    float sm=0.f, sq=0.f;
    for(int i=0;i<16;i++){
      float v = xs[(p*16+i)*ST3 + j];
      sm += v; sq += v*v;
    }
    red[p*36 + j] = sm;
    red[(8+p)*36 + j] = sq;
  }
  __syncthreads();
  if(tid < GT3){
    float sm=0.f, sq=0.f;
    #pragma unroll
    for(int p=0;p<8;p++){ sm += red[p*36+tid]; sq += red[(8+p)*36+tid]; }
    float mean = sm*(1.f/128.f);
    float var = sq*(1.f/128.f) - mean*mean;
    mean_s[tid] = mean;
    inv_s[tid] = 1.f/sqrtf(fmaxf(var,0.f)+1e-5f);
  }
  __syncthreads();
  // normalize + time-mod (dims >= D2C); dia gathers coalesced per node
  #pragma unroll
  for(int s=0;s<16;s++){
    int elem = tid + 256*s;
    int k = elem & 127, j = elem >> 7;
    float v = (xs[k*ST3 + j] - mean_s[j]) * inv_s[j];
    if(k >= D2C){
      int nd = nid[j];
      v *= sinf(dia_w[(size_t)nd*HH+k] + dia_b[(size_t)nd*HH+k]);
    }
    xs[k*ST3 + j] = v;
  }
  __syncthreads();
  const float* kw = KW + (size_t)t*HH*HH;
  const float* vw = VW + (size_t)t*HH*HH;
  int o4 = (tid & 31)*4;
  int ng = tid >> 5;          // 8 groups x 4 nodes
  float4 ak[4], av[4];
  #pragma unroll
  for(int j=0;j<4;j++){ ak[j]=make_float4(0,0,0,0); av[j]=make_float4(0,0,0,0); }
  for(int k=0;k<HH;k++){
    float4 wk = *(const float4*)(kw + (size_t)k*HH + o4);
    float4 wv = *(const float4*)(vw + (size_t)k*HH + o4);
    const float* xr = xs + k*ST3 + ng*4;
    #pragma unroll
    for(int j=0;j<4;j++){
      float x = xr[j];
      ak[j].x += x*wk.x; ak[j].y += x*wk.y; ak[j].z += x*wk.z; ak[j].w += x*wk.w;
      av[j].x += x*wv.x; av[j].y += x*wv.y; av[j].z += x*wv.z; av[j].w += x*wv.w;
    }
  }
  #pragma unroll
  for(int j=0;j<4;j++){
    int n = ng*4+j;
    if(n < nn){
      size_t r = (size_t)sid[n]*256 + o4;
      *(float4*)(KVbuf + r) = ak[j];
      *(float4*)(KVbuf + r + 128) = av[j];
    }
  }
}

// single-output GEMM, 32-node tile, z splits the 128 cols x2; optional fused LN;
// resid -> Y = acc + resid (+relu); Y2 optional copy.
__global__ void k_gemm_t3(const float* X, const int* idxb, const int* cnts, int stride,
                          const float* W, const float* resid, float* Y, float* Y2,
                          int relu, int do_ln){
  int t = blockIdx.y;
  int cnt = cnts[t];
  int base = blockIdx.x * GT3;
  if(base >= cnt || cnt == 0) return;
  int nn = min(GT3, cnt - base);
  const int* ids = idxb + (size_t)t*stride + base;
  __shared__ float xs[128*ST3];
  __shared__ float red[16*36];
  __shared__ float mean_s[GT3], inv_s[GT3];
  __shared__ int sid[GT3];
  int tid = threadIdx.x;
  if(tid < GT3) sid[tid] = (tid < nn) ? ids[tid] : ids[0];
  __syncthreads();
  #pragma unroll
  for(int s=0;s<16;s++){
    int elem = tid + 256*s;
    int k = elem & 127, j = elem >> 7;
    xs[k*ST3 + j] = X[(size_t)sid[j]*HH + k];
  }
  __syncthreads();
  if(do_ln){
    {
      int j = tid & 31, p = tid >> 5;
      float sm=0.f, sq=0.f;
      for(int i=0;i<16;i++){
        float v = xs[(p*16+i)*ST3 + j];
        sm += v; sq += v*v;
      }
      red[p*36 + j] = sm;
      red[(8+p)*36 + j] = sq;
    }
    __syncthreads();
    if(tid < GT3){
      float sm=0.f, sq=0.f;
      #pragma unroll
      for(int p=0;p<8;p++){ sm += red[p*36+tid]; sq += red[(8+p)*36+tid]; }
      float mean = sm*(1.f/128.f);
      float var = sq*(1.f/128.f) - mean*mean;
      mean_s[tid] = mean;
      inv_s[tid] = 1.f/sqrtf(fmaxf(var,0.f)+1e-5f);
    }
    __syncthreads();
    #pragma unroll
    for(int s=0;s<16;s++){
      int elem = tid + 256*s;
      int k = elem & 127, j = elem >> 7;
      xs[k*ST3 + j] = (xs[k*ST3 + j] - mean_s[j]) * inv_s[j];
    }
    __syncthreads();
  }
  const float* w = W + (size_t)t*HH*HH;
  int o4 = (blockIdx.z << 6) + (tid & 15)*4;
  int ng = tid >> 4;          // 16 groups x 2 nodes
  float4 a[2];
  a[0]=make_float4(0,0,0,0); a[1]=make_float4(0,0,0,0);
  for(int k=0;k<HH;k++){
    float4 wk = *(const float4*)(w + (size_t)k*HH + o4);
    const float* xr = xs + k*ST3 + ng*2;
    float x0 = xr[0], x1 = xr[1];
    a[0].x += x0*wk.x; a[0].y += x0*wk.y; a[0].z += x0*wk.z; a[0].w += x0*wk.w;
    a[1].x += x1*wk.x; a[1].y += x1*wk.y; a[1].z += x1*wk.z; a[1].w += x1*wk.w;
  }
  #pragma unroll
  for(int j=0;j<2;j++){
    int n = ng*2+j;
    if(n < nn){
      size_t r = (size_t)sid[n]*HH + o4;
      float4 v = a[j];
      if(resid){
        float4 rs = *(const float4*)(resid + r);
        v.x += rs.x; v.y += rs.y; v.z += rs.z; v.w += rs.w;
        if(relu){ v.x=fmaxf(v.x,0.f); v.y=fmaxf(v.y,0.f); v.z=fmaxf(v.z,0.f); v.w=fmaxf(v.w,0.f); }
      }
      *(float4*)(Y + r) = v;
      if(Y2) *(float4*)(Y2 + r) = v;
    }
  }
}

// EW2all[layer][50][128] = edge_emb @ convE[layer]; one launch for all 4 layers
__global__ void k_edge_tab4(const float* edge_emb, const float* convE, float* EW2all){
  int r = blockIdx.x; int layer = blockIdx.y; int o = threadIdx.x;
  const float* EWp = convE + (size_t)layer*32*HH;
  float acc = 0.f;
  for(int j=0;j<32;j++) acc += edge_emb[r*32+j]*EWp[j*HH+o];
  EW2all[((size_t)layer*50 + r)*HH + o] = acc;
}

// ---------------- CSR build (per graph) ----------------
__global__ void k_hist_dst(const int* edst, int E, int* cnt){
  int e = blockIdx.x*256 + threadIdx.x;
  if(e < E) atomicAdd(&cnt[edst[e]], 1);
}
__global__ void k_scan(const int* cnt, int n, int* row_ptr, int* cursor){
  __shared__ int tsum[1024];
  int tid = threadIdx.x;
  int per = (n + 1023) / 1024;
  int start = tid*per; int end = min(start+per, n);
  int s = 0;
  for(int i=start;i<end;i++) s += cnt[i];
  tsum[tid] = s; __syncthreads();
  for(int off=1;off<1024;off<<=1){
    int v = (tid>=off) ? tsum[tid-off] : 0;
    __syncthreads();
    tsum[tid] += v;
    __syncthreads();
  }
  int run = (tid==0) ? 0 : tsum[tid-1];
  for(int i=start;i<end;i++){ row_ptr[i]=run; cursor[i]=run; run += cnt[i]; }
  if(end == n) row_ptr[n] = run;
}
__global__ void k_fill_csr(const int* edst, int E, int* cursor, int* eid){
  int e = blockIdx.x*256 + threadIdx.x;
  if(e >= E) return;
  int pos = atomicAdd(&cursor[edst[e]], 1);
  eid[pos] = e;
}
__global__ void k_permute_edges(const int* eid, const int* esrc, const int* ew, const int* ety,
                                int E, int* esrc_s, int* ew_s, int* ety_s){
  int r = blockIdx.x*256 + threadIdx.x;
  if(r >= E) return;
  int e = eid[r];
  esrc_s[r] = esrc[e]; ew_s[r] = ew[e]; ety_s[r] = ety[e];
}

// single-pass online-softmax attention, TWO independent edge states (ILP 2),
// exact merge at the end. K+V fetched from interleaved KV row.
__global__ void k_attn_fused3(const int* row_ptr, const int* esrc_s, const int* ew_s, const int* ety_s,
                              const float* KVbuf, const float* Qbuf,
                              const float* EW2, const float* mu, float* Abuf){
  int d = blockIdx.x; int o = threadIdx.x;
  int r0 = row_ptr[d], r1 = row_ptr[d+1];
  __shared__ float q[HH];
  q[o] = Qbuf[(size_t)d*HH+o];
  __syncthreads();
  int h = o >> 4;
  float qo = q[o];
  float m1=-3.0e38f, d1=0.f, a1=0.f;
  float m2=-3.0e38f, d2=0.f, a2=0.f;
  int r = r0;
  for(; r+1 < r1; r += 2){
    int sA = esrc_s[r],   wA = ew_s[r];
    int sB = esrc_s[r+1], wB = ew_s[r+1];
    const float* kvA = KVbuf + (size_t)sA*256;
    const float* kvB = KVbuf + (size_t)sB*256;
    float kA = kvA[o], vA = kvA[128+o];
    float kB = kvB[o], vB = kvB[128+o];
    float pA = qo*(kA + EW2[wA*HH+o]);
    float pB = qo*(kB + EW2[wB*HH+o]);
    pA += __shfl_xor(pA, 1, 64);  pB += __shfl_xor(pB, 1, 64);
    pA += __shfl_xor(pA, 2, 64);  pB += __shfl_xor(pB, 2, 64);
    pA += __shfl_xor(pA, 4, 64);  pB += __shfl_xor(pB, 4, 64);
    pA += __shfl_xor(pA, 8, 64);  pB += __shfl_xor(pB, 8, 64);
    float s1 = pA * mu[ety_s[r]*NH+h] * 0.25f;
    float s2 = pB * mu[ety_s[r+1]*NH+h] * 0.25f;
    float mn1 = fmaxf(m1, s1);
    float mn2 = fmaxf(m2, s2);
    float sc1 = expf(m1 - mn1), e1 = expf(s1 - mn1);
    float sc2 = expf(m2 - mn2), e2 = expf(s2 - mn2);
    d1 = d1*sc1 + e1;  a1 = a1*sc1 + e1*vA;  m1 = mn1;
    d2 = d2*sc2 + e2;  a2 = a2*sc2 + e2*vB;  m2 = mn2;
  }
  if(r < r1){
    int sA = esrc_s[r], wA = ew_s[r];
    const float* kvA = KVbuf + (size_t)sA*256;
    float kA = kvA[o], vA = kvA[128+o];
    float pA = qo*(kA + EW2[wA*HH+o]);
    pA += __shfl_xor(pA, 1, 64);
    pA += __shfl_xor(pA, 2, 64);
    pA += __shfl_xor(pA, 4, 64);
    pA += __shfl_xor(pA, 8, 64);
    float s1 = pA * mu[ety_s[r]*NH+h] * 0.25f;
    float mn1 = fmaxf(m1, s1);
    float sc1 = expf(m1 - mn1), e1 = expf(s1 - mn1);
    d1 = d1*sc1 + e1;  a1 = a1*sc1 + e1*vA;  m1 = mn1;
  }
  float mn = fmaxf(m1, m2);
  float sc1 = expf(m1 - mn), sc2 = expf(m2 - mn);
  float dd  = d1*sc1 + d2*sc2;
  float acc = a1*sc1 + a2*sc2;
  Abuf[(size_t)d*HH + o] = acc / fmaxf(dd, 1e-9f);
}

// ---------------- stage D: token pooling ----------------
__global__ void k_seq2(const float* x2, float* xout){
  int bl = blockIdx.x; int o = threadIdx.x;
  int b = bl / LL, l = bl % LL;
  xout[bl*HH+o] = x2[(l*BB+b)*HH+o];
}

__global__ void k_zero_hist(float* hist2, float* cnt, unsigned* amax, float* aden){
  int i = blockIdx.x*blockDim.x + threadIdx.x;
  if(i < CHILDN*HH) hist2[i] = 0.f;
  if(i < CHILDN){ cnt[i] = 0.f; aden[i] = 0.f; amax[i] = 0x007FFFFFu; }
}

__global__ void k_tokatt(const float* h2f, const int* toknt, const float* ipW, const float* iaW,
                         float* abuf, unsigned* amax, const int* tokid){
  int t = blockIdx.x; int o = threadIdx.x;
  __shared__ float es[HH];
  __shared__ float red[HH];
  int b = t % BB, l = t / BB;
  es[o] = h2f[(b*LL+l)*HH+o];
  __syncthreads();
  int nt = toknt[t];
  const float* w = ipW + (size_t)nt*HH*HH;
  float acc = 0.f;
  for(int j=0;j<HH;j++) acc += es[j]*w[j*HH+o];
  float u = tanhf(acc);
  red[o] = u * iaW[nt*HH+o];
  __syncthreads();
  for(int s=64;s>0;s>>=1){ if(o<s) red[o]+=red[o+s]; __syncthreads(); }
  if(o==0){
    float a = red[0];
    abuf[t] = a;
    atomicMax(&amax[tokid[t]], fenc(a));
  }
}

__global__ void k_tokexp(const int* tokid, float* abuf, const unsigned* amax, float* aden, float* cnt){
  int t = blockIdx.x*blockDim.x + threadIdx.x;
  if(t >= TT) return;
  int c = tokid[t];
  float ex = expf(abuf[t]-fdec(amax[c]));
  abuf[t] = ex;
  atomicAdd(&aden[c], ex);
  atomicAdd(&cnt[c], 1.f);
}

__global__ void k_tokagg(const int* tokid, const float* abuf, const float* aden,
                         const float* h2f, float* hist2){
  int t = blockIdx.x; int o = threadIdx.x;
  int c = tokid[t];
  float w = abuf[t]/fmaxf(aden[c],1e-9f);
  int b = t % BB, l = t / BB;
  atomicAdd(&hist2[c*HH+o], w*h2f[(b*LL+l)*HH+o]);
}

__global__ void k_histfix(const float* cnt, const float* hist_emb, float* hist2){
  int c = blockIdx.x; int o = threadIdx.x;
  if(cnt[c] == 0.f) hist2[c*HH+o] = hist_emb[c*HH+o];
}

// ---------------- parent pooling ----------------
__global__ void k_zero_parent(float* psum, float* pcnt){
  int i = blockIdx.x*blockDim.x + threadIdx.x;
  if(i < PARENTN*HH) psum[i] = 0.f;
  if(i < PARENTN) pcnt[i] = 0.f;
}

__global__ void k_peagg(const int* pe_p, const int* pe_c, const float* cef, float* psum, float* pcnt){
  int i = blockIdx.x; int o = threadIdx.x;
  int p = pe_p[i], c = pe_c[i];
  atomicAdd(&psum[p*HH+o], cef[c*HH+o]);
  if(o==0) atomicAdd(&pcnt[p], 1.f);
}

__global__ void k_parent(const float* psum, const float* pcnt, float* out){
  int i = blockIdx.x; int o = threadIdx.x;
  out[i*HH+o] = psum[i*HH+o]/fmaxf(pcnt[i],1.f);
}

extern "C" void kernel_launch(void* const* d_in, const int* in_sizes, int n_in,
                              void* d_out, int out_size, void* d_ws, size_t ws_size,
                              hipStream_t stream){
  const int* seq     = (const int*)d_in[0];
  const int* seq_nt  = (const int*)d_in[1];
  const int* dur     = (const int*)d_in[2];
  const int* stime   = (const int*)d_in[3];
  const int* etime   = (const int*)d_in[4];
  const int* g1_nid  = (const int*)d_in[5];
  const int* g1_nt   = (const int*)d_in[6];
  const int* g1_esrc = (const int*)d_in[7];
  const int* g1_edst = (const int*)d_in[8];
  const int* g1_ety  = (const int*)d_in[9];
  const int* g1_ew   = (const int*)d_in[10];
  const int* g2_sel  = (const int*)d_in[11];
  const int* g2_esrc = (const int*)d_in[12];
  const int* g2_edst = (const int*)d_in[13];
  const int* g2_ety  = (const int*)d_in[14];
  const int* g2_ew   = (const int*)d_in[15];
  const int* tok_sel = (const int*)d_in[16];
  const int* g4_esrc = (const int*)d_in[17];
  const int* g4_edst = (const int*)d_in[18];
  const int* g4_ety  = (const int*)d_in[19];
  const int* g4_ew   = (const int*)d_in[20];
  const int* pe_p    = (const int*)d_in[21];
  const int* pe_c    = (const int*)d_in[22];
  const float* emb     = (const float*)d_in[23];
  const float* hist_emb= (const float*)d_in[24];
  const float* edge_emb= (const float*)d_in[25];
  const float* dia_w   = (const float*)d_in[26];
  const float* dia_b   = (const float*)d_in[27];
  const float* t2v_w   = (const float*)d_in[28];
  const float* t2v_b   = (const float*)d_in[29];
  const float* exp_W   = (const float*)d_in[30];
  const float* exp_b   = (const float*)d_in[31];
  const float* l1Wi    = (const float*)d_in[32];
  const float* l1Wh    = (const float*)d_in[33];
  const float* l1b     = (const float*)d_in[34];
  const float* l2Wi    = (const float*)d_in[35];
  const float* l2Wh    = (const float*)d_in[36];
  const float* l2b     = (const float*)d_in[37];
  const float* convK   = (const float*)d_in[38];
  const float* convQ   = (const float*)d_in[39];
  const float* convV   = (const float*)d_in[40];
  const float* convO   = (const float*)d_in[41];
  const float* convE   = (const float*)d_in[42];
  const float* convMu  = (const float*)d_in[43];
  const float* ipW     = (const float*)d_in[44];
  const float* iaW     = (const float*)d_in[45];
  const float* skip    = (const float*)d_in[46];
  float* outp = (float*)d_out;

  // workspace arena
  char* wsp = (char*)d_ws;
  size_t off = 0;
  auto A = [&](size_t nbytes)->char*{ char* p = wsp+off; off += (nbytes+255)&~(size_t)255; return p; };
  float*    srcbuf = (float*)   A((size_t)N1SN*HH*4);
  float*    KVbuf  = (float*)   A((size_t)N1SN*256*4);   // interleaved [K|V]
  float*    Qbuf   = (float*)   A((size_t)N1DN*HH*4);
  float*    Abuf   = (float*)   A((size_t)N1DN*HH*4);
  float*    xbuf   = (float*)   A((size_t)TT*HH*4);
  float*    gpre   = (float*)   A((size_t)TT*512*4);
  float*    h1     = (float*)   A((size_t)TT*HH*4);
  float*    dst2   = (float*)   A((size_t)TT*HH*4);
  float*    xg     = (float*)   A((size_t)N1DN*HH*4);
  float*    x2     = (float*)   A((size_t)TT*HH*4);
  float*    h2f    = (float*)   A((size_t)TT*HH*4);
  float*    hist2  = (float*)   A((size_t)CHILDN*HH*4);
  float*    cnt    = (float*)   A((size_t)CHILDN*4);
  float*    abuf   = (float*)   A((size_t)TT*4);
  unsigned* amax   = (unsigned*)A((size_t)CHILDN*4);
  float*    aden   = (float*)   A((size_t)CHILDN*4);
  float*    x3     = (float*)   A((size_t)N1DN*HH*4);
  float*    cef    = (float*)   A((size_t)N4DN*HH*4);
  float*    psum   = (float*)   A((size_t)PARENTN*HH*4);
  float*    pcnt   = (float*)   A((size_t)PARENTN*4);
  int*      tokid  = (int*)     A((size_t)TT*4);
  int*      toknt  = (int*)     A((size_t)TT*4);
  int*      gnid2  = (int*)     A((size_t)N2N*4);
  int*      tsrc2  = (int*)     A((size_t)N2N*4);
  int*      idxS1  = (int*)     A((size_t)NTY*N1SN*4);
  int*      idxS2  = (int*)     A((size_t)NTY*N1DN*4);
  int*      idxS3  = (int*)     A((size_t)NTY*N2N*4);
  int*      idxS4  = (int*)     A((size_t)NTY*TT*4);
  int*      idxS5  = (int*)     A((size_t)NTY*N4DN*4);
  int*      cntall = (int*)     A((size_t)5*NTY*4);
  float*    EW2all = (float*)   A((size_t)4*50*HH*4);
  float*    hstate = (float*)   A((size_t)BB*HH*4);
  float*    cstate = (float*)   A((size_t)BB*HH*4);
  int*      g1row  = (int*)     A((size_t)(N1DN+1)*4);
  int*      g1eid  = (int*)     A((size_t)E1N*4);
  int*      g1src_s= (int*)     A((size_t)E1N*4);
  int*      g1ew_s = (int*)     A((size_t)E1N*4);
  int*      g1ety_s= (int*)     A((size_t)E1N*4);
  int*      g2row  = (int*)     A((size_t)(TT+1)*4);
  int*      g2eid  = (int*)     A((size_t)E2N*4);
  int*      g2src_s= (int*)     A((size_t)E2N*4);
  int*      g2ew_s = (int*)     A((size_t)E2N*4);
  int*      g2ety_s= (int*)     A((size_t)E2N*4);
  int*      g4row  = (int*)     A((size_t)(N4DN+1)*4);
  int*      g4eid  = (int*)     A((size_t)E4N*4);
  int*      g4src_s= (int*)     A((size_t)E4N*4);
  int*      g4ew_s = (int*)     A((size_t)E4N*4);
  int*      g4ety_s= (int*)     A((size_t)E4N*4);
  int*      icnt   = (int*)     A((size_t)(N1DN+1)*4);
  int*      icur   = (int*)     A((size_t)(N1DN+1)*4);
  if(off > ws_size) return;  // insufficient scratch: output stays zero

  auto build_csr = [&](const int* edst, const int* esrc, const int* ew, const int* ety,
                       int E, int ndst, int* rowp, int* eid, int* src_s, int* ew_s, int* ety_s){
    k_zero_intk<<<(ndst+255)/256, 256, 0, stream>>>(icnt, ndst);
    k_hist_dst<<<(E+255)/256, 256, 0, stream>>>(edst, E, icnt);
    k_scan<<<1, 1024, 0, stream>>>(icnt, ndst, rowp, icur);
    k_fill_csr<<<(E+255)/256, 256, 0, stream>>>(edst, E, icur, eid);
    k_permute_edges<<<(E+255)/256, 256, 0, stream>>>(eid, esrc, ew, ety, E, src_s, ew_s, ety_s);
  };

  auto run_conv = [&](const float* src_h, const int* src_nid, int nsrc,
                      const int* idx_src, int* cnt_src, int stride_src,
                      const float* dst_h, int ndst,
                      const int* idx_dst, int* cnt_dst, int stride_dst,
                      const int* rowp, const int* src_s, const int* ew_s, const int* ety_s,
                      int layer, float* outbuf, float* out2, int relu){
    const float* KW  = convK  + (size_t)layer*NTY*HH*HH;
    const float* QW  = convQ  + (size_t)layer*NTY*HH*HH;
    const float* VW  = convV  + (size_t)layer*NTY*HH*HH;
    const float* OW  = convO  + (size_t)layer*NTY*HH*HH;
    const float* MU  = convMu + (size_t)layer*NRL*NH;
    const float* EW2 = EW2all + (size_t)layer*50*HH;
    dim3 gkv((nsrc+GT3-1)/GT3, NTY);
    k_gemm_kv4<<<gkv, 256, 0, stream>>>(src_h, src_nid, dia_w, dia_b,
                                        idx_src, cnt_src, stride_src, KW, VW, KVbuf);
    dim3 gq((ndst+GT3-1)/GT3, NTY, 2);
    k_gemm_t3<<<gq, 256, 0, stream>>>(dst_h, idx_dst, cnt_dst, stride_dst, QW,
                                      (const float*)nullptr, Qbuf, (float*)nullptr, 0, 1);
    k_attn_fused3<<<ndst, HH, 0, stream>>>(rowp, src_s, ew_s, ety_s, KVbuf, Qbuf, EW2, MU, Abuf);
    k_gemm_t3<<<gq, 256, 0, stream>>>(Abuf, idx_dst, cnt_dst, stride_dst, OW,
                                      dst_h, outbuf, out2, relu, 0);
  };

  // ---- stage A: features + LSTM1 ----
  k_featx<<<TT, HH, 0, stream>>>(seq, dur, stime, etime, emb, dia_w, dia_b, t2v_w, t2v_b, exp_W, exp_b, xbuf);
  k_xwi2<<<(TT+15)/16, 256, 0, stream>>>(xbuf, l1Wi, l1b, gpre, TT);
  k_zero_state<<<(BB*HH+255)/256, 256, 0, stream>>>(hstate, cstate);
  for(int l=0;l<LL;l++)
    k_lstm_step<<<BB, 512, 0, stream>>>(gpre, l1Wh, hstate, cstate, h1, (float*)nullptr, l);
  k_tok<<<(TT+255)/256, 256, 0, stream>>>(seq, seq_nt, tokid, toknt);

  // ---- upfront: edge tables, type scatters, g1 CSR ----
  k_edge_tab4<<<dim3(50,4), HH, 0, stream>>>(edge_emb, convE, EW2all);
  k_zero_intk<<<1, 64, 0, stream>>>(cntall, 5*NTY);
  k_scatter_type<<<(N1SN+255)/256, 256, 0, stream>>>(g1_nt, N1SN, cntall+0*NTY, idxS1);
  k_scatter_type<<<(N1DN+255)/256, 256, 0, stream>>>(g1_nt, N1DN, cntall+1*NTY, idxS2);
  k_scatter_type<<<(TT+255)/256, 256, 0, stream>>>(toknt, TT, cntall+3*NTY, idxS4);
  k_scatter_type<<<(N4DN+255)/256, 256, 0, stream>>>(g1_nt, N4DN, cntall+4*NTY, idxS5);
  build_csr(g1_edst, g1_esrc, g1_ew, g1_ety, E1N, N1DN, g1row, g1eid, g1src_s, g1ew_s, g1ety_s);

  // ---- conv1 on g1 ----
  k_gather_emb<<<N1SN, HH, 0, stream>>>(g1_nid, emb, srcbuf);
  run_conv(srcbuf, g1_nid, N1SN, idxS1, cntall+0*NTY, N1SN,
           srcbuf, N1DN, idxS2, cntall+1*NTY, N1DN,
           g1row, g1src_s, g1ew_s, g1ety_s, 0, xg, (float*)nullptr, 1);

  // ---- conv2 on g2 ----
  build_csr(g2_edst, g2_esrc, g2_ew, g2_ety, E2N, TT, g2row, g2eid, g2src_s, g2ew_s, g2ety_s);
  k_prep2<<<N2N, HH, 0, stream>>>(g2_sel, xg, g1_nid, g1_nt, srcbuf, gnid2, tsrc2);
  k_scatter_type<<<(N2N+255)/256, 256, 0, stream>>>(tsrc2, N2N, cntall+2*NTY, idxS3);
  k_dst2<<<TT, HH, 0, stream>>>(tok_sel, xg, h1, dst2);
  run_conv(srcbuf, gnid2, N2N, idxS3, cntall+2*NTY, N2N,
           dst2, TT, idxS4, cntall+3*NTY, TT,
           g2row, g2src_s, g2ew_s, g2ety_s, 1, x2, (float*)nullptr, 1);

  // ---- LSTM2 (h2 is output 0) ----
  k_seq2<<<TT, HH, 0, stream>>>(x2, xbuf);
  k_xwi2<<<(TT+15)/16, 256, 0, stream>>>(xbuf, l2Wi, l2b, gpre, TT);
  k_zero_state<<<(BB*HH+255)/256, 256, 0, stream>>>(hstate, cstate);
  for(int l=0;l<LL;l++)
    k_lstm_step<<<BB, 512, 0, stream>>>(gpre, l2Wh, hstate, cstate, h2f, outp, l);

  // ---- stage D: token attention pooling -> hist2 ----
  k_zero_hist<<<(CHILDN*HH+255)/256, 256, 0, stream>>>(hist2, cnt, amax, aden);
  k_tokatt<<<TT, HH, 0, stream>>>(h2f, toknt, ipW, iaW, abuf, amax, tokid);
  k_tokexp<<<(TT+255)/256, 256, 0, stream>>>(tokid, abuf, amax, aden, cnt);
  k_tokagg<<<TT, HH, 0, stream>>>(tokid, abuf, aden, h2f, hist2);
  k_histfix<<<CHILDN, HH, 0, stream>>>(cnt, hist_emb, hist2);

  // ---- conv3 on g1 with skip-mixed input (g1 CSR + scatters reused) ----
  k_x0<<<N1SN, HH, 0, stream>>>(g1_nid, g1_nt, emb, hist2, skip, srcbuf);
  run_conv(srcbuf, g1_nid, N1SN, idxS1, cntall+0*NTY, N1SN,
           srcbuf, N1DN, idxS2, cntall+1*NTY, N1DN,
           g1row, g1src_s, g1ew_s, g1ety_s, 2, x3, (float*)nullptr, 1);

  // ---- conv4 on g4 (child_embed = output 1, no relu) ----
  build_csr(g4_edst, g4_esrc, g4_ew, g4_ety, E4N, N4DN, g4row, g4eid, g4src_s, g4ew_s, g4ety_s);
  run_conv(x3, g1_nid, N1DN, idxS2, cntall+1*NTY, N1DN,
           x3, N4DN, idxS5, cntall+4*NTY, N4DN,
           g4row, g4src_s, g4ew_s, g4ety_s, 3, cef, outp + (size_t)TT*HH, 0);

  // ---- parent pooling (output 2) ----
  k_zero_parent<<<(PARENTN*HH+255)/256, 256, 0, stream>>>(psum, pcnt);
  k_peagg<<<EC2PN, HH, 0, stream>>>(pe_p, pe_c, cef, psum, pcnt);
  k_parent<<<PARENTN, HH, 0, stream>>>(psum, pcnt, outp + (size_t)TT*HH + (size_t)N4DN*HH);
}

// Round 11
// 1138.759 us; speedup vs baseline: 2.5525x; 1.2128x over previous
//
#include <hip/hip_runtime.h>
#include <math.h>

#define BB 256
#define LL 20
#define HH 128
#define NH 8
#define D2C 64
#define NTY 4
#define NRL 4
#define CHILDN 30001
#define PARENTN 500
#define N1SN 50000
#define N1DN 20000
#define E1N 300000
#define N2N 20000
#define E2N 200000
#define TT (BB*LL)
#define N4DN 5000
#define E4N 150000
#define EC2PN 8000

typedef __attribute__((ext_vector_type(8))) short bfrag;   // 8 bf16 in 4 VGPRs
typedef __attribute__((ext_vector_type(4))) float ffrag;   // MFMA accumulator

__device__ __forceinline__ unsigned fenc(float f){ unsigned u=__float_as_uint(f); return (u&0x80000000u)? ~u : (u|0x80000000u); }
__device__ __forceinline__ float fdec(unsigned u){ return (u&0x80000000u)? __uint_as_float(u^0x80000000u) : __uint_as_float(~u); }
__device__ __forceinline__ float sigf(float x){ return 1.f/(1.f+expf(-x)); }
__device__ __forceinline__ short f2bf(float f){
  unsigned u = __float_as_uint(f);
  unsigned r = u + 0x7FFFu + ((u>>16)&1u);   // round-to-nearest-even
  return (short)(r>>16);
}

// ---------------- Stage A: feature expansion ----------------
__global__ void k_featx(const int* seq, const int* dur, const int* stime, const int* etime,
                        const float* emb, const float* dia_w, const float* dia_b,
                        const float* t2v_w, const float* t2v_b,
                        const float* exp_W, const float* exp_b, float* xout){
  int bl = blockIdx.x; int o = threadIdx.x;
  __shared__ float feat[272];
  int node = seq[bl];
  float ts = (float)stime[bl], te = (float)etime[bl], td = (float)dur[bl];
  float e0 = emb[node*HH+o];
  float st, et;
  if(o < D2C){ st = e0; et = e0; }
  else {
    float w = dia_w[node*HH+o], b = dia_b[node*HH+o];
    st = e0 * sinf(w*ts + b);
    et = e0 * sinf(w*te + b);
  }
  feat[o] = st; feat[HH+o] = et;
  if(o < 16){
    float w = t2v_w[o], b = t2v_b[o];
    feat[256+o] = (o==0) ? (w*td + b) : sinf(w*td + b);
  }
  __syncthreads();
  float acc = exp_b[o];
  for(int j=0;j<272;j++) acc += feat[j]*exp_W[j*HH+o];
  xout[bl*HH+o] = fmaxf(acc, 0.f);
}

// tiled x @ Wi + b -> gpre: 16 rows x 512 cols per block
__global__ void k_xwi2(const float* x, const float* Wi, const float* bias, float* gpre, int rows){
  int base = blockIdx.x*16;
  __shared__ float xs[128*17];
  int tid = threadIdx.x;
  #pragma unroll
  for(int s=0;s<8;s++){
    int elem = tid + 256*s;
    int k = elem & 127, j = elem >> 7;
    int r = base + j;
    xs[k*17 + j] = (r < rows) ? x[(size_t)r*HH + k] : 0.f;
  }
  __syncthreads();
  int o4 = (tid & 127)*4;
  int ng = tid >> 7;
  float4 a[8];
  #pragma unroll
  for(int j=0;j<8;j++) a[j]=make_float4(0,0,0,0);
  for(int k=0;k<HH;k++){
    float4 w = *(const float4*)(Wi + (size_t)k*512 + o4);
    const float* xr = xs + k*17 + ng*8;
    #pragma unroll
    for(int j=0;j<8;j++){
      float xv = xr[j];
      a[j].x += xv*w.x; a[j].y += xv*w.y; a[j].z += xv*w.z; a[j].w += xv*w.w;
    }
  }
  float4 bv = *(const float4*)(bias + o4);
  #pragma unroll
  for(int j=0;j<8;j++){
    int r = base + ng*8 + j;
    if(r < rows){
      float4 v = a[j];
      v.x += bv.x; v.y += bv.y; v.z += bv.z; v.w += bv.w;
      *(float4*)(gpre + (size_t)r*512 + o4) = v;
    }
  }
}

__global__ void k_zero_state(float* h, float* c){
  int i = blockIdx.x*256 + threadIdx.x;
  if(i < BB*HH){ h[i]=0.f; c[i]=0.f; }
}

// one LSTM time step; 4 accumulators for ILP on the dependent FMA chain
__global__ void k_lstm_step(const float* gpre, const float* Wh, float* hstate, float* cstate,
                            float* hout, float* hout2, int l){
  int b = blockIdx.x; int o = threadIdx.x;
  __shared__ float hs[HH];
  __shared__ float gs[512];
  if(o < HH) hs[o] = hstate[b*HH+o];
  __syncthreads();
  float a0=0.f, a1=0.f, a2=0.f, a3=0.f;
  #pragma unroll 8
  for(int h=0;h<HH;h+=4){
    a0 += hs[h  ]*Wh[(h  )*512+o];
    a1 += hs[h+1]*Wh[(h+1)*512+o];
    a2 += hs[h+2]*Wh[(h+2)*512+o];
    a3 += hs[h+3]*Wh[(h+3)*512+o];
  }
  gs[o] = gpre[((size_t)b*LL+l)*512+o] + ((a0+a1)+(a2+a3));
  __syncthreads();
  if(o < HH){
    float ig = sigf(gs[o]);
    float fg = sigf(gs[HH+o]);
    float gg = tanhf(gs[2*HH+o]);
    float og = sigf(gs[3*HH+o]);
    float c = fg*cstate[b*HH+o] + ig*gg;
    float h = og*tanhf(c);
    cstate[b*HH+o] = c; hstate[b*HH+o] = h;
    hout[((size_t)b*LL+l)*HH+o] = h;
    if(hout2) hout2[((size_t)b*LL+l)*HH+o] = h;
  }
}

__global__ void k_tok(const int* seq, const int* seq_nt, int* tokid, int* toknt){
  int t = blockIdx.x*blockDim.x + threadIdx.x;
  if(t >= TT) return;
  int b = t % BB, l = t / BB;
  tokid[t] = seq[b*LL+l];
  toknt[t] = seq_nt[b*LL+l];
}

// ---------------- conv prep ----------------
__global__ void k_gather_emb(const int* nid, const float* emb, float* dst){
  int i = blockIdx.x; int o = threadIdx.x;
  dst[i*HH+o] = emb[nid[i]*HH+o];
}

__global__ void k_prep2(const int* sel, const float* xg, const int* g1_nid, const int* g1_nt,
                        float* srcbuf, int* gnid2, int* tsrc2){
  int i = blockIdx.x; int o = threadIdx.x;
  int s = sel[i];
  srcbuf[i*HH+o] = xg[s*HH+o];
  if(o==0){ gnid2[i] = g1_nid[s]; tsrc2[i] = g1_nt[s]; }
}

__global__ void k_dst2(const int* tok_sel, const float* xg, const float* h1, float* dst2){
  int t = blockIdx.x; int o = threadIdx.x;
  int b = t % BB, l = t / BB;
  dst2[t*HH+o] = xg[tok_sel[t]*HH+o] + h1[(b*LL+l)*HH+o];
}

__global__ void k_x0(const int* nid, const int* ntype, const float* emb, const float* hist2,
                     const float* skip, float* srcbuf){
  int i = blockIdx.x; int o = threadIdx.x;
  float a = sigf(skip[ntype[i]]);
  int nd = nid[i];
  srcbuf[i*HH+o] = emb[nd*HH+o]*a + hist2[nd*HH+o]*(1.f-a);
}

__global__ void k_zero_intk(int* p, int n){
  int i = blockIdx.x*256 + threadIdx.x;
  if(i < n) p[i] = 0;
}

// block-aggregated type scatter
__global__ void k_scatter_type(const int* types, int n, int* cnts, int* idxb){
  __shared__ int hist[NTY];
  __shared__ int base[NTY];
  int i = blockIdx.x*256 + threadIdx.x;
  if(threadIdx.x < NTY) hist[threadIdx.x] = 0;
  __syncthreads();
  int t = 0, r = 0;
  bool act = (i < n);
  if(act){ t = types[i]; r = atomicAdd(&hist[t], 1); }
  __syncthreads();
  if(threadIdx.x < NTY && hist[threadIdx.x] > 0)
    base[threadIdx.x] = atomicAdd(&cnts[threadIdx.x], hist[threadIdx.x]);
  __syncthreads();
  if(act) idxb[t*n + base[t] + r] = i;   // stride = n
}

// ---- weight prepack: fp32 -> bf16 + MFMA B-fragment swizzle.
// B-frag for mfma_f32_16x16x32_bf16: lane holds B[k=(lane>>4)*8+j][n=lane&15].
// Wsw layout per matrix: [ntile(8)][kchunk(4)][lane(64)][j(8)] -> lane loads 16B coalesced.
// Matrix order: fam(K=0,V=1,Q=2,O=3) x layer(4) x type(4), 16384 bf16 each.
__global__ void k_prepack(const float* convK, const float* convV, const float* convQ,
                          const float* convO, short* Wsw){
  int m = blockIdx.x;          // 0..63
  int fam = m >> 4;
  int lt = m & 15;             // layer*4 + type
  const float* src = (fam==0?convK:fam==1?convV:fam==2?convQ:convO) + (size_t)lt*HH*HH;
  short* dst = Wsw + (size_t)m*16384;
  for(int s=0;s<64;s++){
    int i = threadIdx.x + 256*s;
    int j = i & 7, lane = (i>>3)&63, kc = (i>>9)&3, nt = i>>11;
    int k = kc*32 + (lane>>4)*8 + j;
    int n = nt*16 + (lane&15);
    dst[i] = f2bf(src[k*HH+n]);
  }
}

// ---- K+V projection via MFMA: 32-node tile, fused LN+time-mod, bf16 in / fp32 out.
// xs layout [node][k] stride 132 (conflict-free staging; A-frag reads 16B-aligned).
// 4 waves: wave w -> m-tile (w&1), n-tiles (w>>1)*4 .. +3; 32 MFMAs/wave.
__global__ void k_gemm_kv5(const float* X, const int* src_nid,
                           const float* dia_w, const float* dia_b,
                           const int* idxb, const int* cnts, int stride,
                           const bfrag* WK, const bfrag* WV, float* KVbuf){
  int t = blockIdx.y;
  int cnt = cnts[t];
  int base = blockIdx.x * 32;
  if(base >= cnt || cnt == 0) return;
  int nn = min(32, cnt - base);
  const int* ids = idxb + (size_t)t*stride + base;
  __shared__ float xs[32*132];
  __shared__ float red[512];
  __shared__ float mean_s[32], inv_s[32];
  __shared__ int sid[32], nid[32];
  int tid = threadIdx.x;
  if(tid < 32){
    int s_ = (tid < nn) ? ids[tid] : ids[0];
    sid[tid] = s_; nid[tid] = src_nid[s_];
  }
  __syncthreads();
  #pragma unroll
  for(int s=0;s<16;s++){
    int elem = tid + 256*s;
    int k = elem & 127, j = elem >> 7;
    xs[j*132 + k] = X[(size_t)sid[j]*HH + k];
  }
  __syncthreads();
  {
    int j = tid >> 3, p = tid & 7;
    float sm=0.f, sq=0.f;
    const float* xr = xs + j*132 + p*16;
    #pragma unroll
    for(int i=0;i<16;i++){ float v = xr[i]; sm += v; sq += v*v; }
    red[j*8+p] = sm; red[256 + j*8+p] = sq;
  }
  __syncthreads();
  if(tid < 32){
    float sm=0.f, sq=0.f;
    #pragma unroll
    for(int p=0;p<8;p++){ sm += red[tid*8+p]; sq += red[256+tid*8+p]; }
    float mean = sm*(1.f/128.f);
    float var = sq*(1.f/128.f) - mean*mean;
    mean_s[tid] = mean;
    inv_s[tid] = 1.f/sqrtf(fmaxf(var,0.f)+1e-5f);
  }
  __syncthreads();
  #pragma unroll
  for(int s=0;s<16;s++){
    int elem = tid + 256*s;
    int k = elem & 127, j = elem >> 7;
    float v = (xs[j*132+k] - mean_s[j]) * inv_s[j];
    if(k >= D2C) v *= sinf(dia_w[(size_t)nid[j]*HH+k] + dia_b[(size_t)nid[j]*HH+k]);
    xs[j*132+k] = v;
  }
  __syncthreads();
  int lane = tid & 63, w = tid >> 6;
  int mt = w & 1, ng0 = (w>>1)*4;
  int arow = mt*16 + (lane & 15);
  int koff = (lane >> 4)*8;
  int tb = t*2048;
  ffrag aK[4], aV[4];
  #pragma unroll
  for(int i=0;i<4;i++){ aK[i] = (ffrag){0.f,0.f,0.f,0.f}; aV[i] = (ffrag){0.f,0.f,0.f,0.f}; }
  #pragma unroll
  for(int kc=0;kc<4;kc++){
    const float* ap = xs + arow*132 + kc*32 + koff;
    bfrag a;
    #pragma unroll
    for(int j=0;j<8;j++) a[j] = f2bf(ap[j]);
    #pragma unroll
    for(int nt=0;nt<4;nt++){
      int fi = tb + ((ng0+nt)*4 + kc)*64 + lane;
      bfrag bk = WK[fi];
      bfrag bv = WV[fi];
      aK[nt] = __builtin_amdgcn_mfma_f32_16x16x32_bf16(a, bk, aK[nt], 0, 0, 0);
      aV[nt] = __builtin_amdgcn_mfma_f32_16x16x32_bf16(a, bv, aV[nt], 0, 0, 0);
    }
  }
  // C/D layout: col = lane&15, row = (lane>>4)*4 + reg
  int col0 = lane & 15;
  int rb = mt*16 + (lane>>4)*4;
  #pragma unroll
  for(int nt=0;nt<4;nt++){
    int col = (ng0+nt)*16 + col0;
    #pragma unroll
    for(int i=0;i<4;i++){
      int n = rb + i;
      if(n < nn){
        size_t r = (size_t)sid[n]*256;
        KVbuf[r + col] = aK[nt][i];
        KVbuf[r + 128 + col] = aV[nt][i];
      }
    }
  }
}

// ---- single-matrix projection via MFMA (Q: do_ln=1; O: resid+relu, optional copy).
__global__ void k_gemm_t5(const float* X, const int* idxb, const int* cnts, int stride,
                          const bfrag* W, const float* resid, float* Y, float* Y2,
                          int relu, int do_ln){
  int t = blockIdx.y;
  int cnt = cnts[t];
  int base = blockIdx.x * 32;
  if(base >= cnt || cnt == 0) return;
  int nn = min(32, cnt - base);
  const int* ids = idxb + (size_t)t*stride + base;
  __shared__ float xs[32*132];
  __shared__ float red[512];
  __shared__ float mean_s[32], inv_s[32];
  __shared__ int sid[32];
  int tid = threadIdx.x;
  if(tid < 32) sid[tid] = (tid < nn) ? ids[tid] : ids[0];
  __syncthreads();
  #pragma unroll
  for(int s=0;s<16;s++){
    int elem = tid + 256*s;
    int k = elem & 127, j = elem >> 7;
    xs[j*132 + k] = X[(size_t)sid[j]*HH + k];
  }
  __syncthreads();
  if(do_ln){
    {
      int j = tid >> 3, p = tid & 7;
      float sm=0.f, sq=0.f;
      const float* xr = xs + j*132 + p*16;
      #pragma unroll
      for(int i=0;i<16;i++){ float v = xr[i]; sm += v; sq += v*v; }
      red[j*8+p] = sm; red[256 + j*8+p] = sq;
    }
    __syncthreads();
    if(tid < 32){
      float sm=0.f, sq=0.f;
      #pragma unroll
      for(int p=0;p<8;p++){ sm += red[tid*8+p]; sq += red[256+tid*8+p]; }
      float mean = sm*(1.f/128.f);
      float var = sq*(1.f/128.f) - mean*mean;
      mean_s[tid] = mean;
      inv_s[tid] = 1.f/sqrtf(fmaxf(var,0.f)+1e-5f);
    }
    __syncthreads();
    #pragma unroll
    for(int s=0;s<16;s++){
      int elem = tid + 256*s;
      int k = elem & 127, j = elem >> 7;
      xs[j*132+k] = (xs[j*132+k] - mean_s[j]) * inv_s[j];
    }
    __syncthreads();
  }
  int lane = tid & 63, w = tid >> 6;
  int mt = w & 1, ng0 = (w>>1)*4;
  int arow = mt*16 + (lane & 15);
  int koff = (lane >> 4)*8;
  int tb = t*2048;
  ffrag acc[4];
  #pragma unroll
  for(int i=0;i<4;i++) acc[i] = (ffrag){0.f,0.f,0.f,0.f};
  #pragma unroll
  for(int kc=0;kc<4;kc++){
    const float* ap = xs + arow*132 + kc*32 + koff;
    bfrag a;
    #pragma unroll
    for(int j=0;j<8;j++) a[j] = f2bf(ap[j]);
    #pragma unroll
    for(int nt=0;nt<4;nt++){
      bfrag b = W[tb + ((ng0+nt)*4 + kc)*64 + lane];
      acc[nt] = __builtin_amdgcn_mfma_f32_16x16x32_bf16(a, b, acc[nt], 0, 0, 0);
    }
  }
  int col0 = lane & 15;
  int rb = mt*16 + (lane>>4)*4;
  #pragma unroll
  for(int nt=0;nt<4;nt++){
    int col = (ng0+nt)*16 + col0;
    #pragma unroll
    for(int i=0;i<4;i++){
      int n = rb + i;
      if(n < nn){
        size_t r = (size_t)sid[n]*HH + col;
        float v = acc[nt][i];
        if(resid){
          v += resid[r];
          if(relu) v = fmaxf(v, 0.f);
        }
        Y[r] = v;
        if(Y2) Y2[r] = v;
      }
    }
  }
}

// EW2all[layer][50][128] = edge_emb @ convE[layer]; one launch for all 4 layers
__global__ void k_edge_tab4(const float* edge_emb, const float* convE, float* EW2all){
  int r = blockIdx.x; int layer = blockIdx.y; int o = threadIdx.x;
  const float* EWp = convE + (size_t)layer*32*HH;
  float acc = 0.f;
  for(int j=0;j<32;j++) acc += edge_emb[r*32+j]*EWp[j*HH+o];
  EW2all[((size_t)layer*50 + r)*HH + o] = acc;
}

// ---------------- CSR build (per graph) ----------------
__global__ void k_hist_dst(const int* edst, int E, int* cnt){
  int e = blockIdx.x*256 + threadIdx.x;
  if(e < E) atomicAdd(&cnt[edst[e]], 1);
}
__global__ void k_scan(const int* cnt, int n, int* row_ptr, int* cursor){
  __shared__ int tsum[1024];
  int tid = threadIdx.x;
  int per = (n + 1023) / 1024;
  int start = tid*per; int end = min(start+per, n);
  int s = 0;
  for(int i=start;i<end;i++) s += cnt[i];
  tsum[tid] = s; __syncthreads();
  for(int off=1;off<1024;off<<=1){
    int v = (tid>=off) ? tsum[tid-off] : 0;
    __syncthreads();
    tsum[tid] += v;
    __syncthreads();
  }
  int run = (tid==0) ? 0 : tsum[tid-1];
  for(int i=start;i<end;i++){ row_ptr[i]=run; cursor[i]=run; run += cnt[i]; }
  if(end == n) row_ptr[n] = run;
}
__global__ void k_fill_csr(const int* edst, int E, int* cursor, int* eid){
  int e = blockIdx.x*256 + threadIdx.x;
  if(e >= E) return;
  int pos = atomicAdd(&cursor[edst[e]], 1);
  eid[pos] = e;
}
__global__ void k_permute_edges(const int* eid, const int* esrc, const int* ew, const int* ety,
                                int E, int* esrc_s, int* ew_s, int* ety_s){
  int r = blockIdx.x*256 + threadIdx.x;
  if(r >= E) return;
  int e = eid[r];
  esrc_s[r] = esrc[e]; ew_s[r] = ew[e]; ety_s[r] = ety[e];
}

// single-pass online-softmax attention, TWO independent edge states (ILP 2)
__global__ void k_attn_fused3(const int* row_ptr, const int* esrc_s, const int* ew_s, const int* ety_s,
                              const float* KVbuf, const float* Qbuf,
                              const float* EW2, const float* mu, float* Abuf){
  int d = blockIdx.x; int o = threadIdx.x;
  int r0 = row_ptr[d], r1 = row_ptr[d+1];
  __shared__ float q[HH];
  q[o] = Qbuf[(size_t)d*HH+o];
  __syncthreads();
  int h = o >> 4;
  float qo = q[o];
  float m1=-3.0e38f, d1=0.f, a1=0.f;
  float m2=-3.0e38f, d2=0.f, a2=0.f;
  int r = r0;
  for(; r+1 < r1; r += 2){
    int sA = esrc_s[r],   wA = ew_s[r];
    int sB = esrc_s[r+1], wB = ew_s[r+1];
    const float* kvA = KVbuf + (size_t)sA*256;
    const float* kvB = KVbuf + (size_t)sB*256;
    float kA = kvA[o], vA = kvA[128+o];
    float kB = kvB[o], vB = kvB[128+o];
    float pA = qo*(kA + EW2[wA*HH+o]);
    float pB = qo*(kB + EW2[wB*HH+o]);
    pA += __shfl_xor(pA, 1, 64);  pB += __shfl_xor(pB, 1, 64);
    pA += __shfl_xor(pA, 2, 64);  pB += __shfl_xor(pB, 2, 64);
    pA += __shfl_xor(pA, 4, 64);  pB += __shfl_xor(pB, 4, 64);
    pA += __shfl_xor(pA, 8, 64);  pB += __shfl_xor(pB, 8, 64);
    float s1 = pA * mu[ety_s[r]*NH+h] * 0.25f;
    float s2 = pB * mu[ety_s[r+1]*NH+h] * 0.25f;
    float mn1 = fmaxf(m1, s1);
    float mn2 = fmaxf(m2, s2);
    float sc1 = expf(m1 - mn1), e1 = expf(s1 - mn1);
    float sc2 = expf(m2 - mn2), e2 = expf(s2 - mn2);
    d1 = d1*sc1 + e1;  a1 = a1*sc1 + e1*vA;  m1 = mn1;
    d2 = d2*sc2 + e2;  a2 = a2*sc2 + e2*vB;  m2 = mn2;
  }
  if(r < r1){
    int sA = esrc_s[r], wA = ew_s[r];
    const float* kvA = KVbuf + (size_t)sA*256;
    float kA = kvA[o], vA = kvA[128+o];
    float pA = qo*(kA + EW2[wA*HH+o]);
    pA += __shfl_xor(pA, 1, 64);
    pA += __shfl_xor(pA, 2, 64);
    pA += __shfl_xor(pA, 4, 64);
    pA += __shfl_xor(pA, 8, 64);
    float s1 = pA * mu[ety_s[r]*NH+h] * 0.25f;
    float mn1 = fmaxf(m1, s1);
    float sc1 = expf(m1 - mn1), e1 = expf(s1 - mn1);
    d1 = d1*sc1 + e1;  a1 = a1*sc1 + e1*vA;  m1 = mn1;
  }
  float mn = fmaxf(m1, m2);
  float sc1 = expf(m1 - mn), sc2 = expf(m2 - mn);
  float dd  = d1*sc1 + d2*sc2;
  float acc = a1*sc1 + a2*sc2;
  Abuf[(size_t)d*HH + o] = acc / fmaxf(dd, 1e-9f);
}

// ---------------- stage D: token pooling ----------------
__global__ void k_seq2(const float* x2, float* xout){
  int bl = blockIdx.x; int o = threadIdx.x;
  int b = bl / LL, l = bl % LL;
  xout[bl*HH+o] = x2[(l*BB+b)*HH+o];
}

__global__ void k_zero_hist(float* hist2, float* cnt, unsigned* amax, float* aden){
  int i = blockIdx.x*blockDim.x + threadIdx.x;
  if(i < CHILDN*HH) hist2[i] = 0.f;
  if(i < CHILDN){ cnt[i] = 0.f; aden[i] = 0.f; amax[i] = 0x007FFFFFu; }
}

__global__ void k_tokatt(const float* h2f, const int* toknt, const float* ipW, const float* iaW,
                         float* abuf, unsigned* amax, const int* tokid){
  int t = blockIdx.x; int o = threadIdx.x;
  __shared__ float es[HH];
  __shared__ float red[HH];
  int b = t % BB, l = t / BB;
  es[o] = h2f[(b*LL+l)*HH+o];
  __syncthreads();
  int nt = toknt[t];
  const float* w = ipW + (size_t)nt*HH*HH;
  float acc = 0.f;
  for(int j=0;j<HH;j++) acc += es[j]*w[j*HH+o];
  float u = tanhf(acc);
  red[o] = u * iaW[nt*HH+o];
  __syncthreads();
  for(int s=64;s>0;s>>=1){ if(o<s) red[o]+=red[o+s]; __syncthreads(); }
  if(o==0){
    float a = red[0];
    abuf[t] = a;
    atomicMax(&amax[tokid[t]], fenc(a));
  }
}

__global__ void k_tokexp(const int* tokid, float* abuf, const unsigned* amax, float* aden, float* cnt){
  int t = blockIdx.x*blockDim.x + threadIdx.x;
  if(t >= TT) return;
  int c = tokid[t];
  float ex = expf(abuf[t]-fdec(amax[c]));
  abuf[t] = ex;
  atomicAdd(&aden[c], ex);
  atomicAdd(&cnt[c], 1.f);
}

__global__ void k_tokagg(const int* tokid, const float* abuf, const float* aden,
                         const float* h2f, float* hist2){
  int t = blockIdx.x; int o = threadIdx.x;
  int c = tokid[t];
  float w = abuf[t]/fmaxf(aden[c],1e-9f);
  int b = t % BB, l = t / BB;
  atomicAdd(&hist2[c*HH+o], w*h2f[(b*LL+l)*HH+o]);
}

__global__ void k_histfix(const float* cnt, const float* hist_emb, float* hist2){
  int c = blockIdx.x; int o = threadIdx.x;
  if(cnt[c] == 0.f) hist2[c*HH+o] = hist_emb[c*HH+o];
}

// ---------------- parent pooling ----------------
__global__ void k_zero_parent(float* psum, float* pcnt){
  int i = blockIdx.x*blockDim.x + threadIdx.x;
  if(i < PARENTN*HH) psum[i] = 0.f;
  if(i < PARENTN) pcnt[i] = 0.f;
}

__global__ void k_peagg(const int* pe_p, const int* pe_c, const float* cef, float* psum, float* pcnt){
  int i = blockIdx.x; int o = threadIdx.x;
  int p = pe_p[i], c = pe_c[i];
  atomicAdd(&psum[p*HH+o], cef[c*HH+o]);
  if(o==0) atomicAdd(&pcnt[p], 1.f);
}

__global__ void k_parent(const float* psum, const float* pcnt, float* out){
  int i = blockIdx.x; int o = threadIdx.x;
  out[i*HH+o] = psum[i*HH+o]/fmaxf(pcnt[i],1.f);
}

extern "C" void kernel_launch(void* const* d_in, const int* in_sizes, int n_in,
                              void* d_out, int out_size, void* d_ws, size_t ws_size,
                              hipStream_t stream){
  const int* seq     = (const int*)d_in[0];
  const int* seq_nt  = (const int*)d_in[1];
  const int* dur     = (const int*)d_in[2];
  const int* stime   = (const int*)d_in[3];
  const int* etime   = (const int*)d_in[4];
  const int* g1_nid  = (const int*)d_in[5];
  const int* g1_nt   = (const int*)d_in[6];
  const int* g1_esrc = (const int*)d_in[7];
  const int* g1_edst = (const int*)d_in[8];
  const int* g1_ety  = (const int*)d_in[9];
  const int* g1_ew   = (const int*)d_in[10];
  const int* g2_sel  = (const int*)d_in[11];
  const int* g2_esrc = (const int*)d_in[12];
  const int* g2_edst = (const int*)d_in[13];
  const int* g2_ety  = (const int*)d_in[14];
  const int* g2_ew   = (const int*)d_in[15];
  const int* tok_sel = (const int*)d_in[16];
  const int* g4_esrc = (const int*)d_in[17];
  const int* g4_edst = (const int*)d_in[18];
  const int* g4_ety  = (const int*)d_in[19];
  const int* g4_ew   = (const int*)d_in[20];
  const int* pe_p    = (const int*)d_in[21];
  const int* pe_c    = (const int*)d_in[22];
  const float* emb     = (const float*)d_in[23];
  const float* hist_emb= (const float*)d_in[24];
  const float* edge_emb= (const float*)d_in[25];
  const float* dia_w   = (const float*)d_in[26];
  const float* dia_b   = (const float*)d_in[27];
  const float* t2v_w   = (const float*)d_in[28];
  const float* t2v_b   = (const float*)d_in[29];
  const float* exp_W   = (const float*)d_in[30];
  const float* exp_b   = (const float*)d_in[31];
  const float* l1Wi    = (const float*)d_in[32];
  const float* l1Wh    = (const float*)d_in[33];
  const float* l1b     = (const float*)d_in[34];
  const float* l2Wi    = (const float*)d_in[35];
  const float* l2Wh    = (const float*)d_in[36];
  const float* l2b     = (const float*)d_in[37];
  const float* convK   = (const float*)d_in[38];
  const float* convQ   = (const float*)d_in[39];
  const float* convV   = (const float*)d_in[40];
  const float* convO   = (const float*)d_in[41];
  const float* convE   = (const float*)d_in[42];
  const float* convMu  = (const float*)d_in[43];
  const float* ipW     = (const float*)d_in[44];
  const float* iaW     = (const float*)d_in[45];
  const float* skip    = (const float*)d_in[46];
  float* outp = (float*)d_out;

  // workspace arena
  char* wsp = (char*)d_ws;
  size_t off = 0;
  auto A = [&](size_t nbytes)->char*{ char* p = wsp+off; off += (nbytes+255)&~(size_t)255; return p; };
  float*    srcbuf = (float*)   A((size_t)N1SN*HH*4);
  float*    KVbuf  = (float*)   A((size_t)N1SN*256*4);   // interleaved [K|V]
  float*    Qbuf   = (float*)   A((size_t)N1DN*HH*4);
  float*    Abuf   = (float*)   A((size_t)N1DN*HH*4);
  float*    xbuf   = (float*)   A((size_t)TT*HH*4);
  float*    gpre   = (float*)   A((size_t)TT*512*4);
  float*    h1     = (float*)   A((size_t)TT*HH*4);
  float*    dst2   = (float*)   A((size_t)TT*HH*4);
  float*    xg     = (float*)   A((size_t)N1DN*HH*4);
  float*    x2     = (float*)   A((size_t)TT*HH*4);
  float*    h2f    = (float*)   A((size_t)TT*HH*4);
  float*    hist2  = (float*)   A((size_t)CHILDN*HH*4);
  float*    cnt    = (float*)   A((size_t)CHILDN*4);
  float*    abuf   = (float*)   A((size_t)TT*4);
  unsigned* amax   = (unsigned*)A((size_t)CHILDN*4);
  float*    aden   = (float*)   A((size_t)CHILDN*4);
  float*    x3     = (float*)   A((size_t)N1DN*HH*4);
  float*    cef    = (float*)   A((size_t)N4DN*HH*4);
  float*    psum   = (float*)   A((size_t)PARENTN*HH*4);
  float*    pcnt   = (float*)   A((size_t)PARENTN*4);
  int*      tokid  = (int*)     A((size_t)TT*4);
  int*      toknt  = (int*)     A((size_t)TT*4);
  int*      gnid2  = (int*)     A((size_t)N2N*4);
  int*      tsrc2  = (int*)     A((size_t)N2N*4);
  int*      idxS1  = (int*)     A((size_t)NTY*N1SN*4);
  int*      idxS2  = (int*)     A((size_t)NTY*N1DN*4);
  int*      idxS3  = (int*)     A((size_t)NTY*N2N*4);
  int*      idxS4  = (int*)     A((size_t)NTY*TT*4);
  int*      idxS5  = (int*)     A((size_t)NTY*N4DN*4);
  int*      cntall = (int*)     A((size_t)5*NTY*4);
  float*    EW2all = (float*)   A((size_t)4*50*HH*4);
  float*    hstate = (float*)   A((size_t)BB*HH*4);
  float*    cstate = (float*)   A((size_t)BB*HH*4);
  short*    Wsw    = (short*)   A((size_t)64*16384*2);   // bf16-swizzled weights
  int*      g1row  = (int*)     A((size_t)(N1DN+1)*4);
  int*      g1eid  = (int*)     A((size_t)E1N*4);
  int*      g1src_s= (int*)     A((size_t)E1N*4);
  int*      g1ew_s = (int*)     A((size_t)E1N*4);
  int*      g1ety_s= (int*)     A((size_t)E1N*4);
  int*      g2row  = (int*)     A((size_t)(TT+1)*4);
  int*      g2eid  = (int*)     A((size_t)E2N*4);
  int*      g2src_s= (int*)     A((size_t)E2N*4);
  int*      g2ew_s = (int*)     A((size_t)E2N*4);
  int*      g2ety_s= (int*)     A((size_t)E2N*4);
  int*      g4row  = (int*)     A((size_t)(N4DN+1)*4);
  int*      g4eid  = (int*)     A((size_t)E4N*4);
  int*      g4src_s= (int*)     A((size_t)E4N*4);
  int*      g4ew_s = (int*)     A((size_t)E4N*4);
  int*      g4ety_s= (int*)     A((size_t)E4N*4);
  int*      icnt   = (int*)     A((size_t)(N1DN+1)*4);
  int*      icur   = (int*)     A((size_t)(N1DN+1)*4);
  if(off > ws_size) return;  // insufficient scratch: output stays zero

  auto build_csr = [&](const int* edst, const int* esrc, const int* ew, const int* ety,
                       int E, int ndst, int* rowp, int* eid, int* src_s, int* ew_s, int* ety_s){
    k_zero_intk<<<(ndst+255)/256, 256, 0, stream>>>(icnt, ndst);
    k_hist_dst<<<(E+255)/256, 256, 0, stream>>>(edst, E, icnt);
    k_scan<<<1, 1024, 0, stream>>>(icnt, ndst, rowp, icur);
    k_fill_csr<<<(E+255)/256, 256, 0, stream>>>(edst, E, icur, eid);
    k_permute_edges<<<(E+255)/256, 256, 0, stream>>>(eid, esrc, ew, ety, E, src_s, ew_s, ety_s);
  };

  auto run_conv = [&](const float* src_h, const int* src_nid, int nsrc,
                      const int* idx_src, int* cnt_src, int stride_src,
                      const float* dst_h, int ndst,
                      const int* idx_dst, int* cnt_dst, int stride_dst,
                      const int* rowp, const int* src_s, const int* ew_s, const int* ety_s,
                      int layer, float* outbuf, float* out2, int relu){
    const bfrag* WB = (const bfrag*)Wsw;
    const bfrag* WK = WB + (size_t)( 0 + layer*4)*2048;
    const bfrag* WV = WB + (size_t)(16 + layer*4)*2048;
    const bfrag* WQ = WB + (size_t)(32 + layer*4)*2048;
    const bfrag* WO = WB + (size_t)(48 + layer*4)*2048;
    const float* MU  = convMu + (size_t)layer*NRL*NH;
    const float* EW2 = EW2all + (size_t)layer*50*HH;
    dim3 gkv((nsrc+31)/32, NTY);
    k_gemm_kv5<<<gkv, 256, 0, stream>>>(src_h, src_nid, dia_w, dia_b,
                                        idx_src, cnt_src, stride_src, WK, WV, KVbuf);
    dim3 gq((ndst+31)/32, NTY);
    k_gemm_t5<<<gq, 256, 0, stream>>>(dst_h, idx_dst, cnt_dst, stride_dst, WQ,
                                      (const float*)nullptr, Qbuf, (float*)nullptr, 0, 1);
    k_attn_fused3<<<ndst, HH, 0, stream>>>(rowp, src_s, ew_s, ety_s, KVbuf, Qbuf, EW2, MU, Abuf);
    k_gemm_t5<<<gq, 256, 0, stream>>>(Abuf, idx_dst, cnt_dst, stride_dst, WO,
                                      dst_h, outbuf, out2, relu, 0);
  };

  // ---- stage A: features + LSTM1 ----
  k_featx<<<TT, HH, 0, stream>>>(seq, dur, stime, etime, emb, dia_w, dia_b, t2v_w, t2v_b, exp_W, exp_b, xbuf);
  k_xwi2<<<(TT+15)/16, 256, 0, stream>>>(xbuf, l1Wi, l1b, gpre, TT);
  k_zero_state<<<(BB*HH+255)/256, 256, 0, stream>>>(hstate, cstate);
  for(int l=0;l<LL;l++)
    k_lstm_step<<<BB, 512, 0, stream>>>(gpre, l1Wh, hstate, cstate, h1, (float*)nullptr, l);
  k_tok<<<(TT+255)/256, 256, 0, stream>>>(seq, seq_nt, tokid, toknt);

  // ---- upfront: weight prepack, edge tables, type scatters, g1 CSR ----
  k_prepack<<<64, 256, 0, stream>>>(convK, convV, convQ, convO, Wsw);
  k_edge_tab4<<<dim3(50,4), HH, 0, stream>>>(edge_emb, convE, EW2all);
  k_zero_intk<<<1, 64, 0, stream>>>(cntall, 5*NTY);
  k_scatter_type<<<(N1SN+255)/256, 256, 0, stream>>>(g1_nt, N1SN, cntall+0*NTY, idxS1);
  k_scatter_type<<<(N1DN+255)/256, 256, 0, stream>>>(g1_nt, N1DN, cntall+1*NTY, idxS2);
  k_scatter_type<<<(TT+255)/256, 256, 0, stream>>>(toknt, TT, cntall+3*NTY, idxS4);
  k_scatter_type<<<(N4DN+255)/256, 256, 0, stream>>>(g1_nt, N4DN, cntall+4*NTY, idxS5);
  build_csr(g1_edst, g1_esrc, g1_ew, g1_ety, E1N, N1DN, g1row, g1eid, g1src_s, g1ew_s, g1ety_s);

  // ---- conv1 on g1 ----
  k_gather_emb<<<N1SN, HH, 0, stream>>>(g1_nid, emb, srcbuf);
  run_conv(srcbuf, g1_nid, N1SN, idxS1, cntall+0*NTY, N1SN,
           srcbuf, N1DN, idxS2, cntall+1*NTY, N1DN,
           g1row, g1src_s, g1ew_s, g1ety_s, 0, xg, (float*)nullptr, 1);

  // ---- conv2 on g2 ----
  build_csr(g2_edst, g2_esrc, g2_ew, g2_ety, E2N, TT, g2row, g2eid, g2src_s, g2ew_s, g2ety_s);
  k_prep2<<<N2N, HH, 0, stream>>>(g2_sel, xg, g1_nid, g1_nt, srcbuf, gnid2, tsrc2);
  k_scatter_type<<<(N2N+255)/256, 256, 0, stream>>>(tsrc2, N2N, cntall+2*NTY, idxS3);
  k_dst2<<<TT, HH, 0, stream>>>(tok_sel, xg, h1, dst2);
  run_conv(srcbuf, gnid2, N2N, idxS3, cntall+2*NTY, N2N,
           dst2, TT, idxS4, cntall+3*NTY, TT,
           g2row, g2src_s, g2ew_s, g2ety_s, 1, x2, (float*)nullptr, 1);

  // ---- LSTM2 (h2 is output 0) ----
  k_seq2<<<TT, HH, 0, stream>>>(x2, xbuf);
  k_xwi2<<<(TT+15)/16, 256, 0, stream>>>(xbuf, l2Wi, l2b, gpre, TT);
  k_zero_state<<<(BB*HH+255)/256, 256, 0, stream>>>(hstate, cstate);
  for(int l=0;l<LL;l++)
    k_lstm_step<<<BB, 512, 0, stream>>>(gpre, l2Wh, hstate, cstate, h2f, outp, l);

  // ---- stage D: token attention pooling -> hist2 ----
  k_zero_hist<<<(CHILDN*HH+255)/256, 256, 0, stream>>>(hist2, cnt, amax, aden);
  k_tokatt<<<TT, HH, 0, stream>>>(h2f, toknt, ipW, iaW, abuf, amax, tokid);
  k_tokexp<<<(TT+255)/256, 256, 0, stream>>>(tokid, abuf, amax, aden, cnt);
  k_tokagg<<<TT, HH, 0, stream>>>(tokid, abuf, aden, h2f, hist2);
  k_histfix<<<CHILDN, HH, 0, stream>>>(cnt, hist_emb, hist2);

  // ---- conv3 on g1 with skip-mixed input (g1 CSR + scatters reused) ----
  k_x0<<<N1SN, HH, 0, stream>>>(g1_nid, g1_nt, emb, hist2, skip, srcbuf);
  run_conv(srcbuf, g1_nid, N1SN, idxS1, cntall+0*NTY, N1SN,
           srcbuf, N1DN, idxS2, cntall+1*NTY, N1DN,
           g1row, g1src_s, g1ew_s, g1ety_s, 2, x3, (float*)nullptr, 1);

  // ---- conv4 on g4 (child_embed = output 1, no relu) ----
  build_csr(g4_edst, g4_esrc, g4_ew, g4_ety, E4N, N4DN, g4row, g4eid, g4src_s, g4ew_s, g4ety_s);
  run_conv(x3, g1_nid, N1DN, idxS2, cntall+1*NTY, N1DN,
           x3, N4DN, idxS5, cntall+4*NTY, N4DN,
           g4row, g4src_s, g4ew_s, g4ety_s, 3, cef, outp + (size_t)TT*HH, 0);

  // ---- parent pooling (output 2) ----
  k_zero_parent<<<(PARENTN*HH+255)/256, 256, 0, stream>>>(psum, pcnt);
  k_peagg<<<EC2PN, HH, 0, stream>>>(pe_p, pe_c, cef, psum, pcnt);
  k_parent<<<PARENTN, HH, 0, stream>>>(psum, pcnt, outp + (size_t)TT*HH + (size_t)N4DN*HH);
}

// Round 12
// 1085.780 us; speedup vs baseline: 2.6771x; 1.0488x over previous
//
#include <hip/hip_runtime.h>
#include <math.h>

#define BB 256
#define LL 20
#define HH 128
#define NH 8
#define D2C 64
#define NTY 4
#define NRL 4
#define CHILDN 30001
#define PARENTN 500
#define N1SN 50000
#define N1DN 20000
#define E1N 300000
#define N2N 20000
#define E2N 200000
#define TT (BB*LL)
#define N4DN 5000
#define E4N 150000
#define EC2PN 8000

typedef __attribute__((ext_vector_type(8))) short bfrag;   // 8 bf16 in 4 VGPRs
typedef __attribute__((ext_vector_type(4))) float ffrag;   // MFMA accumulator

__device__ __forceinline__ unsigned fenc(float f){ unsigned u=__float_as_uint(f); return (u&0x80000000u)? ~u : (u|0x80000000u); }
__device__ __forceinline__ float fdec(unsigned u){ return (u&0x80000000u)? __uint_as_float(u^0x80000000u) : __uint_as_float(~u); }
__device__ __forceinline__ float sigf(float x){ return 1.f/(1.f+expf(-x)); }
__device__ __forceinline__ short f2bf(float f){
  unsigned u = __float_as_uint(f);
  unsigned r = u + 0x7FFFu + ((u>>16)&1u);   // round-to-nearest-even
  return (short)(r>>16);
}

// ---------------- Stage A: feature expansion ----------------
__global__ void k_featx(const int* seq, const int* dur, const int* stime, const int* etime,
                        const float* emb, const float* dia_w, const float* dia_b,
                        const float* t2v_w, const float* t2v_b,
                        const float* exp_W, const float* exp_b, float* xout){
  int bl = blockIdx.x; int o = threadIdx.x;
  __shared__ float feat[272];
  int node = seq[bl];
  float ts = (float)stime[bl], te = (float)etime[bl], td = (float)dur[bl];
  float e0 = emb[node*HH+o];
  float st, et;
  if(o < D2C){ st = e0; et = e0; }
  else {
    float w = dia_w[node*HH+o], b = dia_b[node*HH+o];
    st = e0 * sinf(w*ts + b);
    et = e0 * sinf(w*te + b);
  }
  feat[o] = st; feat[HH+o] = et;
  if(o < 16){
    float w = t2v_w[o], b = t2v_b[o];
    feat[256+o] = (o==0) ? (w*td + b) : sinf(w*td + b);
  }
  __syncthreads();
  float acc = exp_b[o];
  for(int j=0;j<272;j++) acc += feat[j]*exp_W[j*HH+o];
  xout[bl*HH+o] = fmaxf(acc, 0.f);
}

// tiled x @ Wi + b -> gpre: 16 rows x 512 cols per block
__global__ void k_xwi2(const float* x, const float* Wi, const float* bias, float* gpre, int rows){
  int base = blockIdx.x*16;
  __shared__ float xs[128*17];
  int tid = threadIdx.x;
  #pragma unroll
  for(int s=0;s<8;s++){
    int elem = tid + 256*s;
    int k = elem & 127, j = elem >> 7;
    int r = base + j;
    xs[k*17 + j] = (r < rows) ? x[(size_t)r*HH + k] : 0.f;
  }
  __syncthreads();
  int o4 = (tid & 127)*4;
  int ng = tid >> 7;
  float4 a[8];
  #pragma unroll
  for(int j=0;j<8;j++) a[j]=make_float4(0,0,0,0);
  for(int k=0;k<HH;k++){
    float4 w = *(const float4*)(Wi + (size_t)k*512 + o4);
    const float* xr = xs + k*17 + ng*8;
    #pragma unroll
    for(int j=0;j<8;j++){
      float xv = xr[j];
      a[j].x += xv*w.x; a[j].y += xv*w.y; a[j].z += xv*w.z; a[j].w += xv*w.w;
    }
  }
  float4 bv = *(const float4*)(bias + o4);
  #pragma unroll
  for(int j=0;j<8;j++){
    int r = base + ng*8 + j;
    if(r < rows){
      float4 v = a[j];
      v.x += bv.x; v.y += bv.y; v.z += bv.z; v.w += bv.w;
      *(float4*)(gpre + (size_t)r*512 + o4) = v;
    }
  }
}

__global__ void k_zero_state(float* h, float* c){
  int i = blockIdx.x*256 + threadIdx.x;
  if(i < BB*HH){ h[i]=0.f; c[i]=0.f; }
}

// one LSTM time step; 4 accumulators for ILP on the dependent FMA chain
__global__ void k_lstm_step(const float* gpre, const float* Wh, float* hstate, float* cstate,
                            float* hout, float* hout2, int l){
  int b = blockIdx.x; int o = threadIdx.x;
  __shared__ float hs[HH];
  __shared__ float gs[512];
  if(o < HH) hs[o] = hstate[b*HH+o];
  __syncthreads();
  float a0=0.f, a1=0.f, a2=0.f, a3=0.f;
  #pragma unroll 8
  for(int h=0;h<HH;h+=4){
    a0 += hs[h  ]*Wh[(h  )*512+o];
    a1 += hs[h+1]*Wh[(h+1)*512+o];
    a2 += hs[h+2]*Wh[(h+2)*512+o];
    a3 += hs[h+3]*Wh[(h+3)*512+o];
  }
  gs[o] = gpre[((size_t)b*LL+l)*512+o] + ((a0+a1)+(a2+a3));
  __syncthreads();
  if(o < HH){
    float ig = sigf(gs[o]);
    float fg = sigf(gs[HH+o]);
    float gg = tanhf(gs[2*HH+o]);
    float og = sigf(gs[3*HH+o]);
    float c = fg*cstate[b*HH+o] + ig*gg;
    float h = og*tanhf(c);
    cstate[b*HH+o] = c; hstate[b*HH+o] = h;
    hout[((size_t)b*LL+l)*HH+o] = h;
    if(hout2) hout2[((size_t)b*LL+l)*HH+o] = h;
  }
}

__global__ void k_tok(const int* seq, const int* seq_nt, int* tokid, int* toknt){
  int t = blockIdx.x*blockDim.x + threadIdx.x;
  if(t >= TT) return;
  int b = t % BB, l = t / BB;
  tokid[t] = seq[b*LL+l];
  toknt[t] = seq_nt[b*LL+l];
}

// ---------------- conv prep ----------------
__global__ void k_gather_emb(const int* nid, const float* emb, float* dst){
  int i = blockIdx.x; int o = threadIdx.x;
  dst[i*HH+o] = emb[nid[i]*HH+o];
}

__global__ void k_prep2(const int* sel, const float* xg, const int* g1_nid, const int* g1_nt,
                        float* srcbuf, int* gnid2, int* tsrc2){
  int i = blockIdx.x; int o = threadIdx.x;
  int s = sel[i];
  srcbuf[i*HH+o] = xg[s*HH+o];
  if(o==0){ gnid2[i] = g1_nid[s]; tsrc2[i] = g1_nt[s]; }
}

__global__ void k_dst2(const int* tok_sel, const float* xg, const float* h1, float* dst2){
  int t = blockIdx.x; int o = threadIdx.x;
  int b = t % BB, l = t / BB;
  dst2[t*HH+o] = xg[tok_sel[t]*HH+o] + h1[(b*LL+l)*HH+o];
}

__global__ void k_x0(const int* nid, const int* ntype, const float* emb, const float* hist2,
                     const float* skip, float* srcbuf){
  int i = blockIdx.x; int o = threadIdx.x;
  float a = sigf(skip[ntype[i]]);
  int nd = nid[i];
  srcbuf[i*HH+o] = emb[nd*HH+o]*a + hist2[nd*HH+o]*(1.f-a);
}

__global__ void k_zero_intk(int* p, int n){
  int i = blockIdx.x*256 + threadIdx.x;
  if(i < n) p[i] = 0;
}

// block-aggregated type scatter
__global__ void k_scatter_type(const int* types, int n, int* cnts, int* idxb){
  __shared__ int hist[NTY];
  __shared__ int base[NTY];
  int i = blockIdx.x*256 + threadIdx.x;
  if(threadIdx.x < NTY) hist[threadIdx.x] = 0;
  __syncthreads();
  int t = 0, r = 0;
  bool act = (i < n);
  if(act){ t = types[i]; r = atomicAdd(&hist[t], 1); }
  __syncthreads();
  if(threadIdx.x < NTY && hist[threadIdx.x] > 0)
    base[threadIdx.x] = atomicAdd(&cnts[threadIdx.x], hist[threadIdx.x]);
  __syncthreads();
  if(act) idxb[t*n + base[t] + r] = i;   // stride = n
}

// ---- weight prepack: fp32 -> bf16 + MFMA B-fragment swizzle.
__global__ void k_prepack(const float* convK, const float* convV, const float* convQ,
                          const float* convO, short* Wsw){
  int m = blockIdx.x;          // 0..63
  int fam = m >> 4;
  int lt = m & 15;             // layer*4 + type
  const float* src = (fam==0?convK:fam==1?convV:fam==2?convQ:convO) + (size_t)lt*HH*HH;
  short* dst = Wsw + (size_t)m*16384;
  for(int s=0;s<64;s++){
    int i = threadIdx.x + 256*s;
    int j = i & 7, lane = (i>>3)&63, kc = (i>>9)&3, nt = i>>11;
    int k = kc*32 + (lane>>4)*8 + j;
    int n = nt*16 + (lane&15);
    dst[i] = f2bf(src[k*HH+n]);
  }
}

// ---- K+V projection via MFMA: 32-node tile, fused LN+time-mod, bf16 in / fp32 acc.
// Output packed bf16: KVp[node*128+col] = (V<<16)|K  -> 512B/row, L2-resident (25.6MB).
__global__ void k_gemm_kv5(const float* X, const int* src_nid,
                           const float* dia_w, const float* dia_b,
                           const int* idxb, const int* cnts, int stride,
                           const bfrag* WK, const bfrag* WV, unsigned* KVp){
  int t = blockIdx.y;
  int cnt = cnts[t];
  int base = blockIdx.x * 32;
  if(base >= cnt || cnt == 0) return;
  int nn = min(32, cnt - base);
  const int* ids = idxb + (size_t)t*stride + base;
  __shared__ float xs[32*132];
  __shared__ float red[512];
  __shared__ float mean_s[32], inv_s[32];
  __shared__ int sid[32], nid[32];
  int tid = threadIdx.x;
  if(tid < 32){
    int s_ = (tid < nn) ? ids[tid] : ids[0];
    sid[tid] = s_; nid[tid] = src_nid[s_];
  }
  __syncthreads();
  #pragma unroll
  for(int s=0;s<16;s++){
    int elem = tid + 256*s;
    int k = elem & 127, j = elem >> 7;
    xs[j*132 + k] = X[(size_t)sid[j]*HH + k];
  }
  __syncthreads();
  {
    int j = tid >> 3, p = tid & 7;
    float sm=0.f, sq=0.f;
    const float* xr = xs + j*132 + p*16;
    #pragma unroll
    for(int i=0;i<16;i++){ float v = xr[i]; sm += v; sq += v*v; }
    red[j*8+p] = sm; red[256 + j*8+p] = sq;
  }
  __syncthreads();
  if(tid < 32){
    float sm=0.f, sq=0.f;
    #pragma unroll
    for(int p=0;p<8;p++){ sm += red[tid*8+p]; sq += red[256+tid*8+p]; }
    float mean = sm*(1.f/128.f);
    float var = sq*(1.f/128.f) - mean*mean;
    mean_s[tid] = mean;
    inv_s[tid] = 1.f/sqrtf(fmaxf(var,0.f)+1e-5f);
  }
  __syncthreads();
  #pragma unroll
  for(int s=0;s<16;s++){
    int elem = tid + 256*s;
    int k = elem & 127, j = elem >> 7;
    float v = (xs[j*132+k] - mean_s[j]) * inv_s[j];
    if(k >= D2C) v *= sinf(dia_w[(size_t)nid[j]*HH+k] + dia_b[(size_t)nid[j]*HH+k]);
    xs[j*132+k] = v;
  }
  __syncthreads();
  int lane = tid & 63, w = tid >> 6;
  int mt = w & 1, ng0 = (w>>1)*4;
  int arow = mt*16 + (lane & 15);
  int koff = (lane >> 4)*8;
  int tb = t*2048;
  ffrag aK[4], aV[4];
  #pragma unroll
  for(int i=0;i<4;i++){ aK[i] = (ffrag){0.f,0.f,0.f,0.f}; aV[i] = (ffrag){0.f,0.f,0.f,0.f}; }
  #pragma unroll
  for(int kc=0;kc<4;kc++){
    const float* ap = xs + arow*132 + kc*32 + koff;
    bfrag a;
    #pragma unroll
    for(int j=0;j<8;j++) a[j] = f2bf(ap[j]);
    #pragma unroll
    for(int nt=0;nt<4;nt++){
      int fi = tb + ((ng0+nt)*4 + kc)*64 + lane;
      bfrag bk = WK[fi];
      bfrag bv = WV[fi];
      aK[nt] = __builtin_amdgcn_mfma_f32_16x16x32_bf16(a, bk, aK[nt], 0, 0, 0);
      aV[nt] = __builtin_amdgcn_mfma_f32_16x16x32_bf16(a, bv, aV[nt], 0, 0, 0);
    }
  }
  int col0 = lane & 15;
  int rb = mt*16 + (lane>>4)*4;
  #pragma unroll
  for(int nt=0;nt<4;nt++){
    int col = (ng0+nt)*16 + col0;
    #pragma unroll
    for(int i=0;i<4;i++){
      int n = rb + i;
      if(n < nn){
        unsigned pk = (unsigned short)f2bf(aK[nt][i]);
        unsigned pv = (unsigned short)f2bf(aV[nt][i]);
        KVp[(size_t)sid[n]*HH + col] = (pv<<16) | pk;
      }
    }
  }
}

// ---- single-matrix projection via MFMA (Q: do_ln=1; O: resid+relu, optional copy).
__global__ void k_gemm_t5(const float* X, const int* idxb, const int* cnts, int stride,
                          const bfrag* W, const float* resid, float* Y, float* Y2,
                          int relu, int do_ln){
  int t = blockIdx.y;
  int cnt = cnts[t];
  int base = blockIdx.x * 32;
  if(base >= cnt || cnt == 0) return;
  int nn = min(32, cnt - base);
  const int* ids = idxb + (size_t)t*stride + base;
  __shared__ float xs[32*132];
  __shared__ float red[512];
  __shared__ float mean_s[32], inv_s[32];
  __shared__ int sid[32];
  int tid = threadIdx.x;
  if(tid < 32) sid[tid] = (tid < nn) ? ids[tid] : ids[0];
  __syncthreads();
  #pragma unroll
  for(int s=0;s<16;s++){
    int elem = tid + 256*s;
    int k = elem & 127, j = elem >> 7;
    xs[j*132 + k] = X[(size_t)sid[j]*HH + k];
  }
  __syncthreads();
  if(do_ln){
    {
      int j = tid >> 3, p = tid & 7;
      float sm=0.f, sq=0.f;
      const float* xr = xs + j*132 + p*16;
      #pragma unroll
      for(int i=0;i<16;i++){ float v = xr[i]; sm += v; sq += v*v; }
      red[j*8+p] = sm; red[256 + j*8+p] = sq;
    }
    __syncthreads();
    if(tid < 32){
      float sm=0.f, sq=0.f;
      #pragma unroll
      for(int p=0;p<8;p++){ sm += red[tid*8+p]; sq += red[256+tid*8+p]; }
      float mean = sm*(1.f/128.f);
      float var = sq*(1.f/128.f) - mean*mean;
      mean_s[tid] = mean;
      inv_s[tid] = 1.f/sqrtf(fmaxf(var,0.f)+1e-5f);
    }
    __syncthreads();
    #pragma unroll
    for(int s=0;s<16;s++){
      int elem = tid + 256*s;
      int k = elem & 127, j = elem >> 7;
      xs[j*132+k] = (xs[j*132+k] - mean_s[j]) * inv_s[j];
    }
    __syncthreads();
  }
  int lane = tid & 63, w = tid >> 6;
  int mt = w & 1, ng0 = (w>>1)*4;
  int arow = mt*16 + (lane & 15);
  int koff = (lane >> 4)*8;
  int tb = t*2048;
  ffrag acc[4];
  #pragma unroll
  for(int i=0;i<4;i++) acc[i] = (ffrag){0.f,0.f,0.f,0.f};
  #pragma unroll
  for(int kc=0;kc<4;kc++){
    const float* ap = xs + arow*132 + kc*32 + koff;
    bfrag a;
    #pragma unroll
    for(int j=0;j<8;j++) a[j] = f2bf(ap[j]);
    #pragma unroll
    for(int nt=0;nt<4;nt++){
      bfrag b = W[tb + ((ng0+nt)*4 + kc)*64 + lane];
      acc[nt] = __builtin_amdgcn_mfma_f32_16x16x32_bf16(a, b, acc[nt], 0, 0, 0);
    }
  }
  int col0 = lane & 15;
  int rb = mt*16 + (lane>>4)*4;
  #pragma unroll
  for(int nt=0;nt<4;nt++){
    int col = (ng0+nt)*16 + col0;
    #pragma unroll
    for(int i=0;i<4;i++){
      int n = rb + i;
      if(n < nn){
        size_t r = (size_t)sid[n]*HH + col;
        float v = acc[nt][i];
        if(resid){
          v += resid[r];
          if(relu) v = fmaxf(v, 0.f);
        }
        Y[r] = v;
        if(Y2) Y2[r] = v;
      }
    }
  }
}

// EW2all[layer][50][128] = edge_emb @ convE[layer]
__global__ void k_edge_tab4(const float* edge_emb, const float* convE, float* EW2all){
  int r = blockIdx.x; int layer = blockIdx.y; int o = threadIdx.x;
  const float* EWp = convE + (size_t)layer*32*HH;
  float acc = 0.f;
  for(int j=0;j<32;j++) acc += edge_emb[r*32+j]*EWp[j*HH+o];
  EW2all[((size_t)layer*50 + r)*HH + o] = acc;
}

// ---------------- CSR build (per graph) ----------------
__global__ void k_hist_dst(const int* edst, int E, int* cnt){
  int e = blockIdx.x*256 + threadIdx.x;
  if(e < E) atomicAdd(&cnt[edst[e]], 1);
}
__global__ void k_scan(const int* cnt, int n, int* row_ptr, int* cursor){
  __shared__ int tsum[1024];
  int tid = threadIdx.x;
  int per = (n + 1023) / 1024;
  int start = tid*per; int end = min(start+per, n);
  int s = 0;
  for(int i=start;i<end;i++) s += cnt[i];
  tsum[tid] = s; __syncthreads();
  for(int off=1;off<1024;off<<=1){
    int v = (tid>=off) ? tsum[tid-off] : 0;
    __syncthreads();
    tsum[tid] += v;
    __syncthreads();
  }
  int run = (tid==0) ? 0 : tsum[tid-1];
  for(int i=start;i<end;i++){ row_ptr[i]=run; cursor[i]=run; run += cnt[i]; }
  if(end == n) row_ptr[n] = run;
}
__global__ void k_fill_csr(const int* edst, int E, int* cursor, int* eid){
  int e = blockIdx.x*256 + threadIdx.x;
  if(e >= E) return;
  int pos = atomicAdd(&cursor[edst[e]], 1);
  eid[pos] = e;
}
__global__ void k_permute_edges(const int* eid, const int* esrc, const int* ew, const int* ety,
                                int E, int* esrc_s, int* ew_s, int* ety_s){
  int r = blockIdx.x*256 + threadIdx.x;
  if(r >= E) return;
  int e = eid[r];
  esrc_s[r] = esrc[e]; ew_s[r] = ew[e]; ety_s[r] = ety[e];
}

// single-pass attention on packed bf16 KV, no max-subtraction (scores bounded;
// exp(s)/sum exp(s) identical to max-subtracted form), fast exp, 2-edge ILP.
__global__ void k_attn_fused4(const int* row_ptr, const int* esrc_s, const int* ew_s, const int* ety_s,
                              const unsigned* KVp, const float* Qbuf,
                              const float* EW2, const float* mu, float* Abuf){
  int d = blockIdx.x; int o = threadIdx.x;
  int r0 = row_ptr[d], r1 = row_ptr[d+1];
  __shared__ float q[HH];
  q[o] = Qbuf[(size_t)d*HH+o];
  __syncthreads();
  int h = o >> 4;
  float qo = q[o];
  float d1=0.f, a1=0.f, d2=0.f, a2=0.f;
  int r = r0;
  for(; r+1 < r1; r += 2){
    unsigned uA = KVp[(size_t)esrc_s[r]*HH + o];
    unsigned uB = KVp[(size_t)esrc_s[r+1]*HH + o];
    float eA = EW2[ew_s[r]*HH+o];
    float eB = EW2[ew_s[r+1]*HH+o];
    float kA = __uint_as_float(uA<<16), vA = __uint_as_float(uA & 0xffff0000u);
    float kB = __uint_as_float(uB<<16), vB = __uint_as_float(uB & 0xffff0000u);
    float pA = qo*(kA + eA);
    float pB = qo*(kB + eB);
    pA += __shfl_xor(pA, 1, 64);  pB += __shfl_xor(pB, 1, 64);
    pA += __shfl_xor(pA, 2, 64);  pB += __shfl_xor(pB, 2, 64);
    pA += __shfl_xor(pA, 4, 64);  pB += __shfl_xor(pB, 4, 64);
    pA += __shfl_xor(pA, 8, 64);  pB += __shfl_xor(pB, 8, 64);
    float sA = pA * mu[ety_s[r]*NH+h] * 0.25f;
    float sB = pB * mu[ety_s[r+1]*NH+h] * 0.25f;
    float e1 = __expf(sA), e2 = __expf(sB);
    d1 += e1; a1 += e1*vA;
    d2 += e2; a2 += e2*vB;
  }
  if(r < r1){
    unsigned uA = KVp[(size_t)esrc_s[r]*HH + o];
    float kA = __uint_as_float(uA<<16), vA = __uint_as_float(uA & 0xffff0000u);
    float pA = qo*(kA + EW2[ew_s[r]*HH+o]);
    pA += __shfl_xor(pA, 1, 64);
    pA += __shfl_xor(pA, 2, 64);
    pA += __shfl_xor(pA, 4, 64);
    pA += __shfl_xor(pA, 8, 64);
    float sA = pA * mu[ety_s[r]*NH+h] * 0.25f;
    float e1 = __expf(sA);
    d1 += e1; a1 += e1*vA;
  }
  float dd = d1 + d2, acc = a1 + a2;
  Abuf[(size_t)d*HH + o] = acc / fmaxf(dd, 1e-9f);
}

// ---------------- stage D: token pooling ----------------
__global__ void k_seq2(const float* x2, float* xout){
  int bl = blockIdx.x; int o = threadIdx.x;
  int b = bl / LL, l = bl % LL;
  xout[bl*HH+o] = x2[(l*BB+b)*HH+o];
}

__global__ void k_zero_hist(float* hist2, float* cnt, unsigned* amax, float* aden){
  int i = blockIdx.x*blockDim.x + threadIdx.x;
  if(i < CHILDN*HH) hist2[i] = 0.f;
  if(i < CHILDN){ cnt[i] = 0.f; aden[i] = 0.f; amax[i] = 0x007FFFFFu; }
}

__global__ void k_tokatt(const float* h2f, const int* toknt, const float* ipW, const float* iaW,
                         float* abuf, unsigned* amax, const int* tokid){
  int t = blockIdx.x; int o = threadIdx.x;
  __shared__ float es[HH];
  __shared__ float red[HH];
  int b = t % BB, l = t / BB;
  es[o] = h2f[(b*LL+l)*HH+o];
  __syncthreads();
  int nt = toknt[t];
  const float* w = ipW + (size_t)nt*HH*HH;
  float acc = 0.f;
  for(int j=0;j<HH;j++) acc += es[j]*w[j*HH+o];
  float u = tanhf(acc);
  red[o] = u * iaW[nt*HH+o];
  __syncthreads();
  for(int s=64;s>0;s>>=1){ if(o<s) red[o]+=red[o+s]; __syncthreads(); }
  if(o==0){
    float a = red[0];
    abuf[t] = a;
    atomicMax(&amax[tokid[t]], fenc(a));
  }
}

__global__ void k_tokexp(const int* tokid, float* abuf, const unsigned* amax, float* aden, float* cnt){
  int t = blockIdx.x*blockDim.x + threadIdx.x;
  if(t >= TT) return;
  int c = tokid[t];
  float ex = expf(abuf[t]-fdec(amax[c]));
  abuf[t] = ex;
  atomicAdd(&aden[c], ex);
  atomicAdd(&cnt[c], 1.f);
}

__global__ void k_tokagg(const int* tokid, const float* abuf, const float* aden,
                         const float* h2f, float* hist2){
  int t = blockIdx.x; int o = threadIdx.x;
  int c = tokid[t];
  float w = abuf[t]/fmaxf(aden[c],1e-9f);
  int b = t % BB, l = t / BB;
  atomicAdd(&hist2[c*HH+o], w*h2f[(b*LL+l)*HH+o]);
}

__global__ void k_histfix(const float* cnt, const float* hist_emb, float* hist2){
  int c = blockIdx.x; int o = threadIdx.x;
  if(cnt[c] == 0.f) hist2[c*HH+o] = hist_emb[c*HH+o];
}

// ---------------- parent pooling ----------------
__global__ void k_zero_parent(float* psum, float* pcnt){
  int i = blockIdx.x*blockDim.x + threadIdx.x;
  if(i < PARENTN*HH) psum[i] = 0.f;
  if(i < PARENTN) pcnt[i] = 0.f;
}

__global__ void k_peagg(const int* pe_p, const int* pe_c, const float* cef, float* psum, float* pcnt){
  int i = blockIdx.x; int o = threadIdx.x;
  int p = pe_p[i], c = pe_c[i];
  atomicAdd(&psum[p*HH+o], cef[c*HH+o]);
  if(o==0) atomicAdd(&pcnt[p], 1.f);
}

__global__ void k_parent(const float* psum, const float* pcnt, float* out){
  int i = blockIdx.x; int o = threadIdx.x;
  out[i*HH+o] = psum[i*HH+o]/fmaxf(pcnt[i],1.f);
}

extern "C" void kernel_launch(void* const* d_in, const int* in_sizes, int n_in,
                              void* d_out, int out_size, void* d_ws, size_t ws_size,
                              hipStream_t stream){
  const int* seq     = (const int*)d_in[0];
  const int* seq_nt  = (const int*)d_in[1];
  const int* dur     = (const int*)d_in[2];
  const int* stime   = (const int*)d_in[3];
  const int* etime   = (const int*)d_in[4];
  const int* g1_nid  = (const int*)d_in[5];
  const int* g1_nt   = (const int*)d_in[6];
  const int* g1_esrc = (const int*)d_in[7];
  const int* g1_edst = (const int*)d_in[8];
  const int* g1_ety  = (const int*)d_in[9];
  const int* g1_ew   = (const int*)d_in[10];
  const int* g2_sel  = (const int*)d_in[11];
  const int* g2_esrc = (const int*)d_in[12];
  const int* g2_edst = (const int*)d_in[13];
  const int* g2_ety  = (const int*)d_in[14];
  const int* g2_ew   = (const int*)d_in[15];
  const int* tok_sel = (const int*)d_in[16];
  const int* g4_esrc = (const int*)d_in[17];
  const int* g4_edst = (const int*)d_in[18];
  const int* g4_ety  = (const int*)d_in[19];
  const int* g4_ew   = (const int*)d_in[20];
  const int* pe_p    = (const int*)d_in[21];
  const int* pe_c    = (const int*)d_in[22];
  const float* emb     = (const float*)d_in[23];
  const float* hist_emb= (const float*)d_in[24];
  const float* edge_emb= (const float*)d_in[25];
  const float* dia_w   = (const float*)d_in[26];
  const float* dia_b   = (const float*)d_in[27];
  const float* t2v_w   = (const float*)d_in[28];
  const float* t2v_b   = (const float*)d_in[29];
  const float* exp_W   = (const float*)d_in[30];
  const float* exp_b   = (const float*)d_in[31];
  const float* l1Wi    = (const float*)d_in[32];
  const float* l1Wh    = (const float*)d_in[33];
  const float* l1b     = (const float*)d_in[34];
  const float* l2Wi    = (const float*)d_in[35];
  const float* l2Wh    = (const float*)d_in[36];
  const float* l2b     = (const float*)d_in[37];
  const float* convK   = (const float*)d_in[38];
  const float* convQ   = (const float*)d_in[39];
  const float* convV   = (const float*)d_in[40];
  const float* convO   = (const float*)d_in[41];
  const float* convE   = (const float*)d_in[42];
  const float* convMu  = (const float*)d_in[43];
  const float* ipW     = (const float*)d_in[44];
  const float* iaW     = (const float*)d_in[45];
  const float* skip    = (const float*)d_in[46];
  float* outp = (float*)d_out;

  // workspace arena
  char* wsp = (char*)d_ws;
  size_t off = 0;
  auto A = [&](size_t nbytes)->char*{ char* p = wsp+off; off += (nbytes+255)&~(size_t)255; return p; };
  float*    srcbuf = (float*)   A((size_t)N1SN*HH*4);
  unsigned* KVp    = (unsigned*)A((size_t)N1SN*HH*4);    // packed bf16 [V|K]
  float*    Qbuf   = (float*)   A((size_t)N1DN*HH*4);
  float*    Abuf   = (float*)   A((size_t)N1DN*HH*4);
  float*    xbuf   = (float*)   A((size_t)TT*HH*4);
  float*    gpre   = (float*)   A((size_t)TT*512*4);
  float*    h1     = (float*)   A((size_t)TT*HH*4);
  float*    dst2   = (float*)   A((size_t)TT*HH*4);
  float*    xg     = (float*)   A((size_t)N1DN*HH*4);
  float*    x2     = (float*)   A((size_t)TT*HH*4);
  float*    h2f    = (float*)   A((size_t)TT*HH*4);
  float*    hist2  = (float*)   A((size_t)CHILDN*HH*4);
  float*    cnt    = (float*)   A((size_t)CHILDN*4);
  float*    abuf   = (float*)   A((size_t)TT*4);
  unsigned* amax   = (unsigned*)A((size_t)CHILDN*4);
  float*    aden   = (float*)   A((size_t)CHILDN*4);
  float*    x3     = (float*)   A((size_t)N1DN*HH*4);
  float*    cef    = (float*)   A((size_t)N4DN*HH*4);
  float*    psum   = (float*)   A((size_t)PARENTN*HH*4);
  float*    pcnt   = (float*)   A((size_t)PARENTN*4);
  int*      tokid  = (int*)     A((size_t)TT*4);
  int*      toknt  = (int*)     A((size_t)TT*4);
  int*      gnid2  = (int*)     A((size_t)N2N*4);
  int*      tsrc2  = (int*)     A((size_t)N2N*4);
  int*      idxS1  = (int*)     A((size_t)NTY*N1SN*4);
  int*      idxS2  = (int*)     A((size_t)NTY*N1DN*4);
  int*      idxS3  = (int*)     A((size_t)NTY*N2N*4);
  int*      idxS4  = (int*)     A((size_t)NTY*TT*4);
  int*      idxS5  = (int*)     A((size_t)NTY*N4DN*4);
  int*      cntall = (int*)     A((size_t)5*NTY*4);
  float*    EW2all = (float*)   A((size_t)4*50*HH*4);
  float*    hstate = (float*)   A((size_t)BB*HH*4);
  float*    cstate = (float*)   A((size_t)BB*HH*4);
  short*    Wsw    = (short*)   A((size_t)64*16384*2);   // bf16-swizzled weights
  int*      g1row  = (int*)     A((size_t)(N1DN+1)*4);
  int*      g1eid  = (int*)     A((size_t)E1N*4);
  int*      g1src_s= (int*)     A((size_t)E1N*4);
  int*      g1ew_s = (int*)     A((size_t)E1N*4);
  int*      g1ety_s= (int*)     A((size_t)E1N*4);
  int*      g2row  = (int*)     A((size_t)(TT+1)*4);
  int*      g2eid  = (int*)     A((size_t)E2N*4);
  int*      g2src_s= (int*)     A((size_t)E2N*4);
  int*      g2ew_s = (int*)     A((size_t)E2N*4);
  int*      g2ety_s= (int*)     A((size_t)E2N*4);
  int*      g4row  = (int*)     A((size_t)(N4DN+1)*4);
  int*      g4eid  = (int*)     A((size_t)E4N*4);
  int*      g4src_s= (int*)     A((size_t)E4N*4);
  int*      g4ew_s = (int*)     A((size_t)E4N*4);
  int*      g4ety_s= (int*)     A((size_t)E4N*4);
  int*      icnt   = (int*)     A((size_t)(N1DN+1)*4);
  int*      icur   = (int*)     A((size_t)(N1DN+1)*4);
  if(off > ws_size) return;  // insufficient scratch: output stays zero

  auto build_csr = [&](const int* edst, const int* esrc, const int* ew, const int* ety,
                       int E, int ndst, int* rowp, int* eid, int* src_s, int* ew_s, int* ety_s){
    k_zero_intk<<<(ndst+255)/256, 256, 0, stream>>>(icnt, ndst);
    k_hist_dst<<<(E+255)/256, 256, 0, stream>>>(edst, E, icnt);
    k_scan<<<1, 1024, 0, stream>>>(icnt, ndst, rowp, icur);
    k_fill_csr<<<(E+255)/256, 256, 0, stream>>>(edst, E, icur, eid);
    k_permute_edges<<<(E+255)/256, 256, 0, stream>>>(eid, esrc, ew, ety, E, src_s, ew_s, ety_s);
  };

  auto run_conv = [&](const float* src_h, const int* src_nid, int nsrc,
                      const int* idx_src, int* cnt_src, int stride_src,
                      const float* dst_h, int ndst,
                      const int* idx_dst, int* cnt_dst, int stride_dst,
                      const int* rowp, const int* src_s, const int* ew_s, const int* ety_s,
                      int layer, float* outbuf, float* out2, int relu){
    const bfrag* WB = (const bfrag*)Wsw;
    const bfrag* WK = WB + (size_t)( 0 + layer*4)*2048;
    const bfrag* WV = WB + (size_t)(16 + layer*4)*2048;
    const bfrag* WQ = WB + (size_t)(32 + layer*4)*2048;
    const bfrag* WO = WB + (size_t)(48 + layer*4)*2048;
    const float* MU  = convMu + (size_t)layer*NRL*NH;
    const float* EW2 = EW2all + (size_t)layer*50*HH;
    dim3 gkv((nsrc+31)/32, NTY);
    k_gemm_kv5<<<gkv, 256, 0, stream>>>(src_h, src_nid, dia_w, dia_b,
                                        idx_src, cnt_src, stride_src, WK, WV, KVp);
    dim3 gq((ndst+31)/32, NTY);
    k_gemm_t5<<<gq, 256, 0, stream>>>(dst_h, idx_dst, cnt_dst, stride_dst, WQ,
                                      (const float*)nullptr, Qbuf, (float*)nullptr, 0, 1);
    k_attn_fused4<<<ndst, HH, 0, stream>>>(rowp, src_s, ew_s, ety_s, KVp, Qbuf, EW2, MU, Abuf);
    k_gemm_t5<<<gq, 256, 0, stream>>>(Abuf, idx_dst, cnt_dst, stride_dst, WO,
                                      dst_h, outbuf, out2, relu, 0);
  };

  // ---- stage A: features + LSTM1 ----
  k_featx<<<TT, HH, 0, stream>>>(seq, dur, stime, etime, emb, dia_w, dia_b, t2v_w, t2v_b, exp_W, exp_b, xbuf);
  k_xwi2<<<(TT+15)/16, 256, 0, stream>>>(xbuf, l1Wi, l1b, gpre, TT);
  k_zero_state<<<(BB*HH+255)/256, 256, 0, stream>>>(hstate, cstate);
  for(int l=0;l<LL;l++)
    k_lstm_step<<<BB, 512, 0, stream>>>(gpre, l1Wh, hstate, cstate, h1, (float*)nullptr, l);
  k_tok<<<(TT+255)/256, 256, 0, stream>>>(seq, seq_nt, tokid, toknt);

  // ---- upfront: weight prepack, edge tables, type scatters, g1 CSR ----
  k_prepack<<<64, 256, 0, stream>>>(convK, convV, convQ, convO, Wsw);
  k_edge_tab4<<<dim3(50,4), HH, 0, stream>>>(edge_emb, convE, EW2all);
  k_zero_intk<<<1, 64, 0, stream>>>(cntall, 5*NTY);
  k_scatter_type<<<(N1SN+255)/256, 256, 0, stream>>>(g1_nt, N1SN, cntall+0*NTY, idxS1);
  k_scatter_type<<<(N1DN+255)/256, 256, 0, stream>>>(g1_nt, N1DN, cntall+1*NTY, idxS2);
  k_scatter_type<<<(TT+255)/256, 256, 0, stream>>>(toknt, TT, cntall+3*NTY, idxS4);
  k_scatter_type<<<(N4DN+255)/256, 256, 0, stream>>>(g1_nt, N4DN, cntall+4*NTY, idxS5);
  build_csr(g1_edst, g1_esrc, g1_ew, g1_ety, E1N, N1DN, g1row, g1eid, g1src_s, g1ew_s, g1ety_s);

  // ---- conv1 on g1 ----
  k_gather_emb<<<N1SN, HH, 0, stream>>>(g1_nid, emb, srcbuf);
  run_conv(srcbuf, g1_nid, N1SN, idxS1, cntall+0*NTY, N1SN,
           srcbuf, N1DN, idxS2, cntall+1*NTY, N1DN,
           g1row, g1src_s, g1ew_s, g1ety_s, 0, xg, (float*)nullptr, 1);

  // ---- conv2 on g2 ----
  build_csr(g2_edst, g2_esrc, g2_ew, g2_ety, E2N, TT, g2row, g2eid, g2src_s, g2ew_s, g2ety_s);
  k_prep2<<<N2N, HH, 0, stream>>>(g2_sel, xg, g1_nid, g1_nt, srcbuf, gnid2, tsrc2);
  k_scatter_type<<<(N2N+255)/256, 256, 0, stream>>>(tsrc2, N2N, cntall+2*NTY, idxS3);
  k_dst2<<<TT, HH, 0, stream>>>(tok_sel, xg, h1, dst2);
  run_conv(srcbuf, gnid2, N2N, idxS3, cntall+2*NTY, N2N,
           dst2, TT, idxS4, cntall+3*NTY, TT,
           g2row, g2src_s, g2ew_s, g2ety_s, 1, x2, (float*)nullptr, 1);

  // ---- LSTM2 (h2 is output 0) ----
  k_seq2<<<TT, HH, 0, stream>>>(x2, xbuf);
  k_xwi2<<<(TT+15)/16, 256, 0, stream>>>(xbuf, l2Wi, l2b, gpre, TT);
  k_zero_state<<<(BB*HH+255)/256, 256, 0, stream>>>(hstate, cstate);
  for(int l=0;l<LL;l++)
    k_lstm_step<<<BB, 512, 0, stream>>>(gpre, l2Wh, hstate, cstate, h2f, outp, l);

  // ---- stage D: token attention pooling -> hist2 ----
  k_zero_hist<<<(CHILDN*HH+255)/256, 256, 0, stream>>>(hist2, cnt, amax, aden);
  k_tokatt<<<TT, HH, 0, stream>>>(h2f, toknt, ipW, iaW, abuf, amax, tokid);
  k_tokexp<<<(TT+255)/256, 256, 0, stream>>>(tokid, abuf, amax, aden, cnt);
  k_tokagg<<<TT, HH, 0, stream>>>(tokid, abuf, aden, h2f, hist2);
  k_histfix<<<CHILDN, HH, 0, stream>>>(cnt, hist_emb, hist2);

  // ---- conv3 on g1 with skip-mixed input (g1 CSR + scatters reused) ----
  k_x0<<<N1SN, HH, 0, stream>>>(g1_nid, g1_nt, emb, hist2, skip, srcbuf);
  run_conv(srcbuf, g1_nid, N1SN, idxS1, cntall+0*NTY, N1SN,
           srcbuf, N1DN, idxS2, cntall+1*NTY, N1DN,
           g1row, g1src_s, g1ew_s, g1ety_s, 2, x3, (float*)nullptr, 1);

  // ---- conv4 on g4 (child_embed = output 1, no relu) ----
  build_csr(g4_edst, g4_esrc, g4_ew, g4_ety, E4N, N4DN, g4row, g4eid, g4src_s, g4ew_s, g4ety_s);
  run_conv(x3, g1_nid, N1DN, idxS2, cntall+1*NTY, N1DN,
           x3, N4DN, idxS5, cntall+4*NTY, N4DN,
           g4row, g4src_s, g4ew_s, g4ety_s, 3, cef, outp + (size_t)TT*HH, 0);

  // ---- parent pooling (output 2) ----
  k_zero_parent<<<(PARENTN*HH+255)/256, 256, 0, stream>>>(psum, pcnt);
  k_peagg<<<EC2PN, HH, 0, stream>>>(pe_p, pe_c, cef, psum, pcnt);
  k_parent<<<PARENTN, HH, 0, stream>>>(psum, pcnt, outp + (size_t)TT*HH + (size_t)N4DN*HH);
}